// Round 1
// baseline (4426.565 us; speedup 1.0000x reference)
//
#include <hip/hip_runtime.h>
#include <cstdint>
#include <cstddef>

#define NNODES 50000
#define NEDGES 800000
#define E2 (NEDGES + NNODES)
#define HC 256

// ---------------- CSR build ----------------

__global__ void zero_int(int* __restrict__ p, int n) {
    int i = blockIdx.x * 256 + threadIdx.x;
    if (i < n) p[i] = 0;
}

__global__ void count_deg(const int* __restrict__ ei, int* __restrict__ deg) {
    int i = blockIdx.x * 256 + threadIdx.x;
    if (i >= E2) return;
    int d = (i < NEDGES) ? ei[NEDGES + i] : (i - NEDGES);
    atomicAdd(&deg[d], 1);
}

__global__ void scan1(const int* __restrict__ deg, int* __restrict__ rp, int* __restrict__ bs) {
    __shared__ int s[256];
    int t = threadIdx.x, i = blockIdx.x * 256 + t;
    int v = (i < NNODES) ? deg[i] : 0;
    s[t] = v;
    __syncthreads();
    for (int o = 1; o < 256; o <<= 1) {
        int add = (t >= o) ? s[t - o] : 0;
        __syncthreads();
        s[t] += add;
        __syncthreads();
    }
    if (i < NNODES) rp[i] = s[t] - v;   // exclusive within block
    if (t == 255) bs[blockIdx.x] = s[255];
}

__global__ void scan2(int* __restrict__ bs, int nb) {
    __shared__ int s[256];
    int t = threadIdx.x;
    int v = (t < nb) ? bs[t] : 0;
    s[t] = v;
    __syncthreads();
    for (int o = 1; o < 256; o <<= 1) {
        int add = (t >= o) ? s[t - o] : 0;
        __syncthreads();
        s[t] += add;
        __syncthreads();
    }
    bs[t] = s[t] - v;   // exclusive block offsets
}

__global__ void scan3(int* __restrict__ rp, const int* __restrict__ bs, int* __restrict__ cnt) {
    int i = blockIdx.x * 256 + threadIdx.x;
    if (i < NNODES) {
        int v = rp[i] + bs[blockIdx.x];
        rp[i] = v;
        cnt[i] = v;
    }
    if (i == 0) rp[NNODES] = E2;
}

__global__ void fill_csr(const int* __restrict__ ei, int* __restrict__ cnt, int* __restrict__ csr) {
    int i = blockIdx.x * 256 + threadIdx.x;
    if (i >= E2) return;
    int s, d;
    if (i < NEDGES) { s = ei[i]; d = ei[NEDGES + i]; }
    else            { s = d = i - NEDGES; }
    int pos = atomicAdd(&cnt[d], 1);
    csr[pos] = s;
}

// ---------------- fp32 GEMM: out[M,256] = A[M,256] @ W[256,256]^T ----------------
// 128x128 block tile, BK=32, 256 threads, 8x8 micro-tile per thread.

__global__ __launch_bounds__(256, 2) void gemm256(const float* __restrict__ A,
                                                  const float* __restrict__ W,
                                                  float* __restrict__ out, int M) {
    __shared__ float sA[128][36];
    __shared__ float sW[128][36];
    const int t = threadIdx.x;
    const int m0 = blockIdx.x * 128, n0 = blockIdx.y * 128;
    const int tx = t & 15, ty = t >> 4;
    const int lr = t >> 3;   // 0..31 (staging row base)
    const int lq = t & 7;    // 0..7  (float4 slot)

    float acc[8][8];
#pragma unroll
    for (int r = 0; r < 8; r++)
#pragma unroll
        for (int c = 0; c < 8; c++) acc[r][c] = 0.f;

    for (int kc = 0; kc < 256; kc += 32) {
#pragma unroll
        for (int i = 0; i < 4; i++) {
            int row = lr + 32 * i;
            int gr = m0 + row;
            gr = gr < M ? gr : M - 1;
            float4 av = *(const float4*)(A + (size_t)gr * HC + kc + lq * 4);
            *(float4*)(&sA[row][lq * 4]) = av;
            float4 wv = *(const float4*)(W + (size_t)(n0 + row) * HC + kc + lq * 4);
            *(float4*)(&sW[row][lq * 4]) = wv;
        }
        __syncthreads();
#pragma unroll
        for (int kv = 0; kv < 8; kv++) {
            float4 a4[8], w4[8];
#pragma unroll
            for (int r = 0; r < 8; r++) a4[r] = *(const float4*)(&sA[ty + 16 * r][kv * 4]);
#pragma unroll
            for (int c = 0; c < 8; c++) w4[c] = *(const float4*)(&sW[tx + 16 * c][kv * 4]);
#pragma unroll
            for (int r = 0; r < 8; r++)
#pragma unroll
                for (int c = 0; c < 8; c++) {
                    acc[r][c] += a4[r].x * w4[c].x + a4[r].y * w4[c].y
                               + a4[r].z * w4[c].z + a4[r].w * w4[c].w;
                }
        }
        __syncthreads();
    }
#pragma unroll
    for (int r = 0; r < 8; r++) {
        int gr = m0 + ty + 16 * r;
        if (gr < M) {
#pragma unroll
            for (int c = 0; c < 8; c++) {
                out[(size_t)gr * HC + n0 + tx + 16 * c] = acc[r][c];
            }
        }
    }
}

// ---------------- per-(node,head) attention logits: asrc/adst ----------------
// one block per node; wave w == head w; shuffle-reduce over C=64.

__global__ void alpha_hc(const float* __restrict__ h, const float* __restrict__ a_s,
                         const float* __restrict__ a_d, float* __restrict__ asrc,
                         float* __restrict__ adst) {
    int n = blockIdx.x;
    int t = threadIdx.x;
    float v = h[(size_t)n * HC + t];
    float ps = v * a_s[t];
    float pd = v * a_d[t];
    for (int o = 32; o > 0; o >>= 1) {
        ps += __shfl_xor(ps, o);
        pd += __shfl_xor(pd, o);
    }
    if ((t & 63) == 0) {
        int w = t >> 6;
        asrc[n * 4 + w] = ps;
        adst[n * 4 + w] = pd;
    }
}

// ---------------- fused segment softmax + aggregation (layers 1,2) ----------------
// one block per dst node; wave w == head w; lane l == channel l.
// pass 1: max over neighbors; pass 2: exp-sum + weighted gather, then bias + ELU.

__global__ void aggregate_hc(const float* __restrict__ h, const float* __restrict__ asrc,
                             const float* __restrict__ adst, const int* __restrict__ rp,
                             const int* __restrict__ csr, const float* __restrict__ bias,
                             float* __restrict__ y) {
    int n = blockIdx.x;
    int t = threadIdx.x;
    int w = t >> 6, l = t & 63;
    int r0 = rp[n], deg = rp[n + 1] - r0;
    float ad = adst[n * 4 + w];

    float m = -1e30f;
    for (int j = l; j < deg; j += 64) {
        int s = csr[r0 + j];
        float e = asrc[s * 4 + w] + ad;
        e = e > 0.f ? e : 0.2f * e;
        m = fmaxf(m, e);
    }
    for (int o = 32; o > 0; o >>= 1) m = fmaxf(m, __shfl_xor(m, o));

    float acc = 0.f;
    float ssum = 0.f;
    for (int j = 0; j < deg; j++) {
        int s = csr[r0 + j];
        float e = asrc[s * 4 + w] + ad;
        e = e > 0.f ? e : 0.2f * e;
        float a = expf(e - m);
        ssum += a;   // uniform across lanes of this wave
        acc += a * h[(size_t)s * HC + (w << 6) + l];
    }
    float outv = acc / ssum + bias[(w << 6) + l];
    outv = outv > 0.f ? outv : expm1f(outv);
    y[(size_t)n * HC + (w << 6) + l] = outv;
}

// ---------------- layer 3: small GEMM [N,256] @ [12,256]^T ----------------

__global__ void gemm_small(const float* __restrict__ Y, const float* __restrict__ W3,
                           float* __restrict__ h3) {
    int idx = blockIdx.x * 256 + threadIdx.x;
    if (idx >= NNODES * 12) return;
    int n = idx / 12, o = idx - n * 12;
    const float4* xr = (const float4*)(Y + (size_t)n * HC);
    const float4* wr = (const float4*)(W3 + o * HC);
    float acc = 0.f;
#pragma unroll 8
    for (int k = 0; k < 64; k++) {
        float4 a = xr[k], b = wr[k];
        acc += a.x * b.x + a.y * b.y + a.z * b.z + a.w * b.w;
    }
    h3[idx] = acc;
}

__global__ void alpha3(const float* __restrict__ h3, const float* __restrict__ a_s,
                       const float* __restrict__ a_d, float* __restrict__ asrc,
                       float* __restrict__ adst) {
    int n = blockIdx.x * 256 + threadIdx.x;
    if (n >= NNODES) return;
    const float* hr = h3 + (size_t)n * 12;
    float s[4], d[4];
#pragma unroll
    for (int hh = 0; hh < 4; hh++) {
        s[hh] = hr[hh * 3] * a_s[hh * 3] + hr[hh * 3 + 1] * a_s[hh * 3 + 1] + hr[hh * 3 + 2] * a_s[hh * 3 + 2];
        d[hh] = hr[hh * 3] * a_d[hh * 3] + hr[hh * 3 + 1] * a_d[hh * 3 + 1] + hr[hh * 3 + 2] * a_d[hh * 3 + 2];
    }
    *(float4*)(asrc + n * 4) = make_float4(s[0], s[1], s[2], s[3]);
    *(float4*)(adst + n * 4) = make_float4(d[0], d[1], d[2], d[3]);
}

// layer-3 aggregate: one wave per node (4 nodes/block), heads averaged, +b3, ELU.
__global__ void aggregate3(const float* __restrict__ h3, const float* __restrict__ asrc,
                           const float* __restrict__ adst, const int* __restrict__ rp,
                           const int* __restrict__ csr, const float* __restrict__ b3,
                           float* __restrict__ out) {
    int n = blockIdx.x * 4 + (threadIdx.x >> 6);
    int l = threadIdx.x & 63;
    if (n >= NNODES) return;
    int r0 = rp[n], deg = rp[n + 1] - r0;
    float4 ad = *(const float4*)(adst + n * 4);

    float m0 = -1e30f, m1 = -1e30f, m2 = -1e30f, m3 = -1e30f;
    for (int j = l; j < deg; j += 64) {
        int s = csr[r0 + j];
        float4 a4 = *(const float4*)(asrc + s * 4);
        float e0 = a4.x + ad.x, e1 = a4.y + ad.y, e2 = a4.z + ad.z, e3 = a4.w + ad.w;
        e0 = e0 > 0.f ? e0 : 0.2f * e0;
        e1 = e1 > 0.f ? e1 : 0.2f * e1;
        e2 = e2 > 0.f ? e2 : 0.2f * e2;
        e3 = e3 > 0.f ? e3 : 0.2f * e3;
        m0 = fmaxf(m0, e0); m1 = fmaxf(m1, e1); m2 = fmaxf(m2, e2); m3 = fmaxf(m3, e3);
    }
    for (int o = 32; o > 0; o >>= 1) {
        m0 = fmaxf(m0, __shfl_xor(m0, o));
        m1 = fmaxf(m1, __shfl_xor(m1, o));
        m2 = fmaxf(m2, __shfl_xor(m2, o));
        m3 = fmaxf(m3, __shfl_xor(m3, o));
    }

    float acc[12];
#pragma unroll
    for (int k = 0; k < 12; k++) acc[k] = 0.f;
    float s0 = 0.f, s1 = 0.f, s2 = 0.f, s3 = 0.f;
    for (int j = l; j < deg; j += 64) {
        int s = csr[r0 + j];
        float4 a4 = *(const float4*)(asrc + s * 4);
        float e0 = a4.x + ad.x, e1 = a4.y + ad.y, e2 = a4.z + ad.z, e3 = a4.w + ad.w;
        e0 = e0 > 0.f ? e0 : 0.2f * e0;
        e1 = e1 > 0.f ? e1 : 0.2f * e1;
        e2 = e2 > 0.f ? e2 : 0.2f * e2;
        e3 = e3 > 0.f ? e3 : 0.2f * e3;
        float w0 = expf(e0 - m0), w1 = expf(e1 - m1), w2 = expf(e2 - m2), w3 = expf(e3 - m3);
        s0 += w0; s1 += w1; s2 += w2; s3 += w3;
        const float* hr = h3 + (size_t)s * 12;
#pragma unroll
        for (int c = 0; c < 3; c++) {
            acc[c]     += w0 * hr[c];
            acc[3 + c] += w1 * hr[3 + c];
            acc[6 + c] += w2 * hr[6 + c];
            acc[9 + c] += w3 * hr[9 + c];
        }
    }
    for (int o = 32; o > 0; o >>= 1) {
#pragma unroll
        for (int k = 0; k < 12; k++) acc[k] += __shfl_xor(acc[k], o);
        s0 += __shfl_xor(s0, o);
        s1 += __shfl_xor(s1, o);
        s2 += __shfl_xor(s2, o);
        s3 += __shfl_xor(s3, o);
    }
    if (l < 3) {
        float v = 0.25f * (acc[l] / s0 + acc[3 + l] / s1 + acc[6 + l] / s2 + acc[9 + l] / s3) + b3[l];
        v = v > 0.f ? v : expm1f(v);
        out[(size_t)n * 3 + l] = v;
    }
}

// ---------------- launch ----------------

extern "C" void kernel_launch(void* const* d_in, const int* in_sizes, int n_in,
                              void* d_out, int out_size, void* d_ws, size_t ws_size,
                              hipStream_t stream) {
    (void)in_sizes; (void)n_in; (void)out_size; (void)ws_size;
    const float* x   = (const float*)d_in[0];
    const int*   ei  = (const int*)d_in[1];
    const float* W1  = (const float*)d_in[2];
    const float* as1 = (const float*)d_in[3];
    const float* ad1 = (const float*)d_in[4];
    const float* b1  = (const float*)d_in[5];
    const float* W2  = (const float*)d_in[6];
    const float* as2 = (const float*)d_in[7];
    const float* ad2 = (const float*)d_in[8];
    const float* b2  = (const float*)d_in[9];
    const float* W3  = (const float*)d_in[10];
    const float* as3 = (const float*)d_in[11];
    const float* ad3 = (const float*)d_in[12];
    const float* b3  = (const float*)d_in[13];
    float* out = (float*)d_out;

    uint8_t* p = (uint8_t*)d_ws;
    auto alloc = [&](size_t bytes) -> void* {
        void* r = (void*)p;
        p += (bytes + 255) & ~(size_t)255;
        return r;
    };
    float* bufH = (float*)alloc((size_t)NNODES * HC * 4);
    float* bufY = (float*)alloc((size_t)NNODES * HC * 4);
    float* h3   = (float*)alloc((size_t)NNODES * 12 * 4);
    float* asrc = (float*)alloc((size_t)NNODES * 4 * 4);
    float* adst = (float*)alloc((size_t)NNODES * 4 * 4);
    int* deg    = (int*)alloc((size_t)NNODES * 4);
    int* rp     = (int*)alloc((size_t)(NNODES + 1) * 4);
    int* cnt    = (int*)alloc((size_t)NNODES * 4);
    int* csr    = (int*)alloc((size_t)E2 * 4);
    int* bsums  = (int*)alloc(256 * 4);

    const int NB_N = (NNODES + 255) / 256;     // 196
    const int NB_E = (E2 + 255) / 256;         // 3321

    // CSR build (counting sort by dst, self-loops appended)
    zero_int<<<NB_N, 256, 0, stream>>>(deg, NNODES);
    count_deg<<<NB_E, 256, 0, stream>>>(ei, deg);
    scan1<<<NB_N, 256, 0, stream>>>(deg, rp, bsums);
    scan2<<<1, 256, 0, stream>>>(bsums, NB_N);
    scan3<<<NB_N, 256, 0, stream>>>(rp, bsums, cnt);
    fill_csr<<<NB_E, 256, 0, stream>>>(ei, cnt, csr);

    // Layer 1
    gemm256<<<dim3((NNODES + 127) / 128, 2), 256, 0, stream>>>(x, W1, bufH, NNODES);
    alpha_hc<<<NNODES, 256, 0, stream>>>(bufH, as1, ad1, asrc, adst);
    aggregate_hc<<<NNODES, 256, 0, stream>>>(bufH, asrc, adst, rp, csr, b1, bufY);

    // Layer 2
    gemm256<<<dim3((NNODES + 127) / 128, 2), 256, 0, stream>>>(bufY, W2, bufH, NNODES);
    alpha_hc<<<NNODES, 256, 0, stream>>>(bufH, as2, ad2, asrc, adst);
    aggregate_hc<<<NNODES, 256, 0, stream>>>(bufH, asrc, adst, rp, csr, b2, bufY);

    // Layer 3
    gemm_small<<<(NNODES * 12 + 255) / 256, 256, 0, stream>>>(bufY, W3, h3);
    alpha3<<<NB_N, 256, 0, stream>>>(h3, as3, ad3, asrc, adst);
    aggregate3<<<(NNODES + 3) / 4, 256, 0, stream>>>(h3, asrc, adst, rp, csr, b3, out);
}

// Round 2
// 1088.870 us; speedup vs baseline: 4.0653x; 4.0653x over previous
//
#include <hip/hip_runtime.h>
#include <cstdint>
#include <cstddef>

#define NNODES 50000
#define NEDGES 800000
#define E2 (NEDGES + NNODES)
#define HC 256

// ---------------- CSR build ----------------

__global__ void zero_int(int* __restrict__ p, int n) {
    int i = blockIdx.x * 256 + threadIdx.x;
    if (i < n) p[i] = 0;
}

__global__ void count_deg(const int* __restrict__ ei, int* __restrict__ deg) {
    int i = blockIdx.x * 256 + threadIdx.x;
    if (i >= E2) return;
    int d = (i < NEDGES) ? ei[NEDGES + i] : (i - NEDGES);
    atomicAdd(&deg[d], 1);
}

__global__ void scan1(const int* __restrict__ deg, int* __restrict__ rp, int* __restrict__ bs) {
    __shared__ int s[256];
    int t = threadIdx.x, i = blockIdx.x * 256 + t;
    int v = (i < NNODES) ? deg[i] : 0;
    s[t] = v;
    __syncthreads();
    for (int o = 1; o < 256; o <<= 1) {
        int add = (t >= o) ? s[t - o] : 0;
        __syncthreads();
        s[t] += add;
        __syncthreads();
    }
    if (i < NNODES) rp[i] = s[t] - v;   // exclusive within block
    if (t == 255) bs[blockIdx.x] = s[255];
}

__global__ void scan2(int* __restrict__ bs, int nb) {
    __shared__ int s[256];
    int t = threadIdx.x;
    int v = (t < nb) ? bs[t] : 0;
    s[t] = v;
    __syncthreads();
    for (int o = 1; o < 256; o <<= 1) {
        int add = (t >= o) ? s[t - o] : 0;
        __syncthreads();
        s[t] += add;
        __syncthreads();
    }
    bs[t] = s[t] - v;   // exclusive block offsets
}

__global__ void scan3(int* __restrict__ rp, const int* __restrict__ bs, int* __restrict__ cnt) {
    int i = blockIdx.x * 256 + threadIdx.x;
    if (i < NNODES) {
        int v = rp[i] + bs[blockIdx.x];
        rp[i] = v;
        cnt[i] = v;
    }
    if (i == 0) rp[NNODES] = E2;
}

__global__ void fill_csr(const int* __restrict__ ei, int* __restrict__ cnt, int* __restrict__ csr) {
    int i = blockIdx.x * 256 + threadIdx.x;
    if (i >= E2) return;
    int s, d;
    if (i < NEDGES) { s = ei[i]; d = ei[NEDGES + i]; }
    else            { s = d = i - NEDGES; }
    int pos = atomicAdd(&cnt[d], 1);
    csr[pos] = s;
}

// ---------------- fp32 GEMM: out[M,256] = A[M,256] @ W[256,256]^T ----------------
// 128x128 block tile, BK=32, 256 threads, 8x8 micro-tile per thread.
// Scalar LDS operand reads (a[8], w[8] = 16 regs) so acc[8][8] stays in VGPRs.
// Pad 33 (odd): a-reads 4 addrs x 16-lane broadcast, w-reads 16 distinct banks,
// stage-writes <=2-way aliasing (free).

__global__ __launch_bounds__(256, 2) void gemm256(const float* __restrict__ A,
                                                  const float* __restrict__ W,
                                                  float* __restrict__ out, int M) {
    __shared__ float sA[128][33];
    __shared__ float sW[128][33];
    const int t = threadIdx.x;
    const int m0 = blockIdx.x * 128, n0 = blockIdx.y * 128;
    const int tx = t & 15, ty = t >> 4;
    const int lr = t >> 3;   // 0..31 (staging row base)
    const int lq = t & 7;    // 0..7  (float4 slot)

    float acc[8][8];
#pragma unroll
    for (int r = 0; r < 8; r++)
#pragma unroll
        for (int c = 0; c < 8; c++) acc[r][c] = 0.f;

    for (int kc = 0; kc < 256; kc += 32) {
#pragma unroll
        for (int i = 0; i < 4; i++) {
            int row = lr + 32 * i;
            int gr = m0 + row;
            gr = gr < M ? gr : M - 1;
            float4 av = *(const float4*)(A + (size_t)gr * HC + kc + lq * 4);
            sA[row][lq * 4 + 0] = av.x;
            sA[row][lq * 4 + 1] = av.y;
            sA[row][lq * 4 + 2] = av.z;
            sA[row][lq * 4 + 3] = av.w;
            float4 wv = *(const float4*)(W + (size_t)(n0 + row) * HC + kc + lq * 4);
            sW[row][lq * 4 + 0] = wv.x;
            sW[row][lq * 4 + 1] = wv.y;
            sW[row][lq * 4 + 2] = wv.z;
            sW[row][lq * 4 + 3] = wv.w;
        }
        __syncthreads();
#pragma unroll 2
        for (int k = 0; k < 32; k++) {
            float a[8], w[8];
#pragma unroll
            for (int r = 0; r < 8; r++) a[r] = sA[ty + 16 * r][k];
#pragma unroll
            for (int c = 0; c < 8; c++) w[c] = sW[tx + 16 * c][k];
#pragma unroll
            for (int r = 0; r < 8; r++)
#pragma unroll
                for (int c = 0; c < 8; c++) acc[r][c] = fmaf(a[r], w[c], acc[r][c]);
        }
        __syncthreads();
    }
#pragma unroll
    for (int r = 0; r < 8; r++) {
        int gr = m0 + ty + 16 * r;
        if (gr < M) {
#pragma unroll
            for (int c = 0; c < 8; c++) {
                out[(size_t)gr * HC + n0 + tx + 16 * c] = acc[r][c];
            }
        }
    }
}

// ---------------- per-(node,head) attention logits: asrc/adst ----------------

__global__ void alpha_hc(const float* __restrict__ h, const float* __restrict__ a_s,
                         const float* __restrict__ a_d, float* __restrict__ asrc,
                         float* __restrict__ adst) {
    int n = blockIdx.x;
    int t = threadIdx.x;
    float v = h[(size_t)n * HC + t];
    float ps = v * a_s[t];
    float pd = v * a_d[t];
    for (int o = 32; o > 0; o >>= 1) {
        ps += __shfl_xor(ps, o);
        pd += __shfl_xor(pd, o);
    }
    if ((t & 63) == 0) {
        int w = t >> 6;
        asrc[n * 4 + w] = ps;
        adst[n * 4 + w] = pd;
    }
}

// ---------------- fused segment softmax + aggregation (layers 1,2) ----------------

__global__ void aggregate_hc(const float* __restrict__ h, const float* __restrict__ asrc,
                             const float* __restrict__ adst, const int* __restrict__ rp,
                             const int* __restrict__ csr, const float* __restrict__ bias,
                             float* __restrict__ y) {
    int n = blockIdx.x;
    int t = threadIdx.x;
    int w = t >> 6, l = t & 63;
    int r0 = rp[n], deg = rp[n + 1] - r0;
    float ad = adst[n * 4 + w];

    float m = -1e30f;
    for (int j = l; j < deg; j += 64) {
        int s = csr[r0 + j];
        float e = asrc[s * 4 + w] + ad;
        e = e > 0.f ? e : 0.2f * e;
        m = fmaxf(m, e);
    }
    for (int o = 32; o > 0; o >>= 1) m = fmaxf(m, __shfl_xor(m, o));

    float acc = 0.f;
    float ssum = 0.f;
    for (int j = 0; j < deg; j++) {
        int s = csr[r0 + j];
        float e = asrc[s * 4 + w] + ad;
        e = e > 0.f ? e : 0.2f * e;
        float a = expf(e - m);
        ssum += a;   // uniform across lanes of this wave
        acc += a * h[(size_t)s * HC + (w << 6) + l];
    }
    float outv = acc / ssum + bias[(w << 6) + l];
    outv = outv > 0.f ? outv : expm1f(outv);
    y[(size_t)n * HC + (w << 6) + l] = outv;
}

// ---------------- layer 3: small GEMM [N,256] @ [12,256]^T ----------------

__global__ void gemm_small(const float* __restrict__ Y, const float* __restrict__ W3,
                           float* __restrict__ h3) {
    int idx = blockIdx.x * 256 + threadIdx.x;
    if (idx >= NNODES * 12) return;
    int n = idx / 12, o = idx - n * 12;
    const float4* xr = (const float4*)(Y + (size_t)n * HC);
    const float4* wr = (const float4*)(W3 + o * HC);
    float acc = 0.f;
#pragma unroll 8
    for (int k = 0; k < 64; k++) {
        float4 a = xr[k], b = wr[k];
        acc += a.x * b.x + a.y * b.y + a.z * b.z + a.w * b.w;
    }
    h3[idx] = acc;
}

__global__ void alpha3(const float* __restrict__ h3, const float* __restrict__ a_s,
                       const float* __restrict__ a_d, float* __restrict__ asrc,
                       float* __restrict__ adst) {
    int n = blockIdx.x * 256 + threadIdx.x;
    if (n >= NNODES) return;
    const float* hr = h3 + (size_t)n * 12;
    float s[4], d[4];
#pragma unroll
    for (int hh = 0; hh < 4; hh++) {
        s[hh] = hr[hh * 3] * a_s[hh * 3] + hr[hh * 3 + 1] * a_s[hh * 3 + 1] + hr[hh * 3 + 2] * a_s[hh * 3 + 2];
        d[hh] = hr[hh * 3] * a_d[hh * 3] + hr[hh * 3 + 1] * a_d[hh * 3 + 1] + hr[hh * 3 + 2] * a_d[hh * 3 + 2];
    }
    *(float4*)(asrc + n * 4) = make_float4(s[0], s[1], s[2], s[3]);
    *(float4*)(adst + n * 4) = make_float4(d[0], d[1], d[2], d[3]);
}

// layer-3 aggregate: one wave per node (4 nodes/block), heads averaged, +b3, ELU.
__global__ void aggregate3(const float* __restrict__ h3, const float* __restrict__ asrc,
                           const float* __restrict__ adst, const int* __restrict__ rp,
                           const int* __restrict__ csr, const float* __restrict__ b3,
                           float* __restrict__ out) {
    int n = blockIdx.x * 4 + (threadIdx.x >> 6);
    int l = threadIdx.x & 63;
    if (n >= NNODES) return;
    int r0 = rp[n], deg = rp[n + 1] - r0;
    float4 ad = *(const float4*)(adst + n * 4);

    float m0 = -1e30f, m1 = -1e30f, m2 = -1e30f, m3 = -1e30f;
    for (int j = l; j < deg; j += 64) {
        int s = csr[r0 + j];
        float4 a4 = *(const float4*)(asrc + s * 4);
        float e0 = a4.x + ad.x, e1 = a4.y + ad.y, e2 = a4.z + ad.z, e3 = a4.w + ad.w;
        e0 = e0 > 0.f ? e0 : 0.2f * e0;
        e1 = e1 > 0.f ? e1 : 0.2f * e1;
        e2 = e2 > 0.f ? e2 : 0.2f * e2;
        e3 = e3 > 0.f ? e3 : 0.2f * e3;
        m0 = fmaxf(m0, e0); m1 = fmaxf(m1, e1); m2 = fmaxf(m2, e2); m3 = fmaxf(m3, e3);
    }
    for (int o = 32; o > 0; o >>= 1) {
        m0 = fmaxf(m0, __shfl_xor(m0, o));
        m1 = fmaxf(m1, __shfl_xor(m1, o));
        m2 = fmaxf(m2, __shfl_xor(m2, o));
        m3 = fmaxf(m3, __shfl_xor(m3, o));
    }

    float acc[12];
#pragma unroll
    for (int k = 0; k < 12; k++) acc[k] = 0.f;
    float s0 = 0.f, s1 = 0.f, s2 = 0.f, s3 = 0.f;
    for (int j = l; j < deg; j += 64) {
        int s = csr[r0 + j];
        float4 a4 = *(const float4*)(asrc + s * 4);
        float e0 = a4.x + ad.x, e1 = a4.y + ad.y, e2 = a4.z + ad.z, e3 = a4.w + ad.w;
        e0 = e0 > 0.f ? e0 : 0.2f * e0;
        e1 = e1 > 0.f ? e1 : 0.2f * e1;
        e2 = e2 > 0.f ? e2 : 0.2f * e2;
        e3 = e3 > 0.f ? e3 : 0.2f * e3;
        float w0 = expf(e0 - m0), w1 = expf(e1 - m1), w2 = expf(e2 - m2), w3 = expf(e3 - m3);
        s0 += w0; s1 += w1; s2 += w2; s3 += w3;
        const float* hr = h3 + (size_t)s * 12;
#pragma unroll
        for (int c = 0; c < 3; c++) {
            acc[c]     += w0 * hr[c];
            acc[3 + c] += w1 * hr[3 + c];
            acc[6 + c] += w2 * hr[6 + c];
            acc[9 + c] += w3 * hr[9 + c];
        }
    }
    for (int o = 32; o > 0; o >>= 1) {
#pragma unroll
        for (int k = 0; k < 12; k++) acc[k] += __shfl_xor(acc[k], o);
        s0 += __shfl_xor(s0, o);
        s1 += __shfl_xor(s1, o);
        s2 += __shfl_xor(s2, o);
        s3 += __shfl_xor(s3, o);
    }
    if (l < 3) {
        float v = 0.25f * (acc[l] / s0 + acc[3 + l] / s1 + acc[6 + l] / s2 + acc[9 + l] / s3) + b3[l];
        v = v > 0.f ? v : expm1f(v);
        out[(size_t)n * 3 + l] = v;
    }
}

// ---------------- launch ----------------

extern "C" void kernel_launch(void* const* d_in, const int* in_sizes, int n_in,
                              void* d_out, int out_size, void* d_ws, size_t ws_size,
                              hipStream_t stream) {
    (void)in_sizes; (void)n_in; (void)out_size; (void)ws_size;
    const float* x   = (const float*)d_in[0];
    const int*   ei  = (const int*)d_in[1];
    const float* W1  = (const float*)d_in[2];
    const float* as1 = (const float*)d_in[3];
    const float* ad1 = (const float*)d_in[4];
    const float* b1  = (const float*)d_in[5];
    const float* W2  = (const float*)d_in[6];
    const float* as2 = (const float*)d_in[7];
    const float* ad2 = (const float*)d_in[8];
    const float* b2  = (const float*)d_in[9];
    const float* W3  = (const float*)d_in[10];
    const float* as3 = (const float*)d_in[11];
    const float* ad3 = (const float*)d_in[12];
    const float* b3  = (const float*)d_in[13];
    float* out = (float*)d_out;

    uint8_t* p = (uint8_t*)d_ws;
    auto alloc = [&](size_t bytes) -> void* {
        void* r = (void*)p;
        p += (bytes + 255) & ~(size_t)255;
        return r;
    };
    float* bufH = (float*)alloc((size_t)NNODES * HC * 4);
    float* bufY = (float*)alloc((size_t)NNODES * HC * 4);
    float* h3   = (float*)alloc((size_t)NNODES * 12 * 4);
    float* asrc = (float*)alloc((size_t)NNODES * 4 * 4);
    float* adst = (float*)alloc((size_t)NNODES * 4 * 4);
    int* deg    = (int*)alloc((size_t)NNODES * 4);
    int* rp     = (int*)alloc((size_t)(NNODES + 1) * 4);
    int* cnt    = (int*)alloc((size_t)NNODES * 4);
    int* csr    = (int*)alloc((size_t)E2 * 4);
    int* bsums  = (int*)alloc(256 * 4);

    const int NB_N = (NNODES + 255) / 256;     // 196
    const int NB_E = (E2 + 255) / 256;         // 3321

    // CSR build (counting sort by dst, self-loops appended)
    zero_int<<<NB_N, 256, 0, stream>>>(deg, NNODES);
    count_deg<<<NB_E, 256, 0, stream>>>(ei, deg);
    scan1<<<NB_N, 256, 0, stream>>>(deg, rp, bsums);
    scan2<<<1, 256, 0, stream>>>(bsums, NB_N);
    scan3<<<NB_N, 256, 0, stream>>>(rp, bsums, cnt);
    fill_csr<<<NB_E, 256, 0, stream>>>(ei, cnt, csr);

    // Layer 1
    gemm256<<<dim3((NNODES + 127) / 128, 2), 256, 0, stream>>>(x, W1, bufH, NNODES);
    alpha_hc<<<NNODES, 256, 0, stream>>>(bufH, as1, ad1, asrc, adst);
    aggregate_hc<<<NNODES, 256, 0, stream>>>(bufH, asrc, adst, rp, csr, b1, bufY);

    // Layer 2
    gemm256<<<dim3((NNODES + 127) / 128, 2), 256, 0, stream>>>(bufY, W2, bufH, NNODES);
    alpha_hc<<<NNODES, 256, 0, stream>>>(bufH, as2, ad2, asrc, adst);
    aggregate_hc<<<NNODES, 256, 0, stream>>>(bufH, asrc, adst, rp, csr, b2, bufY);

    // Layer 3
    gemm_small<<<(NNODES * 12 + 255) / 256, 256, 0, stream>>>(bufY, W3, h3);
    alpha3<<<NB_N, 256, 0, stream>>>(h3, as3, ad3, asrc, adst);
    aggregate3<<<(NNODES + 3) / 4, 256, 0, stream>>>(h3, asrc, adst, rp, csr, b3, out);
}

// Round 3
// 930.662 us; speedup vs baseline: 4.7564x; 1.1700x over previous
//
#include <hip/hip_runtime.h>
#include <cstdint>
#include <cstddef>

#define NNODES 50000
#define NEDGES 800000
#define E2 (NEDGES + NNODES)
#define HC 256

// ---------------- CSR build ----------------

__global__ void zero_int(int* __restrict__ p, int n) {
    int i = blockIdx.x * 256 + threadIdx.x;
    if (i < n) p[i] = 0;
}

__global__ void count_deg(const int* __restrict__ ei, int* __restrict__ deg) {
    int i = blockIdx.x * 256 + threadIdx.x;
    if (i >= E2) return;
    int d = (i < NEDGES) ? ei[NEDGES + i] : (i - NEDGES);
    atomicAdd(&deg[d], 1);
}

__global__ void scan1(const int* __restrict__ deg, int* __restrict__ rp, int* __restrict__ bs) {
    __shared__ int s[256];
    int t = threadIdx.x, i = blockIdx.x * 256 + t;
    int v = (i < NNODES) ? deg[i] : 0;
    s[t] = v;
    __syncthreads();
    for (int o = 1; o < 256; o <<= 1) {
        int add = (t >= o) ? s[t - o] : 0;
        __syncthreads();
        s[t] += add;
        __syncthreads();
    }
    if (i < NNODES) rp[i] = s[t] - v;   // exclusive within block
    if (t == 255) bs[blockIdx.x] = s[255];
}

__global__ void scan2(int* __restrict__ bs, int nb) {
    __shared__ int s[256];
    int t = threadIdx.x;
    int v = (t < nb) ? bs[t] : 0;
    s[t] = v;
    __syncthreads();
    for (int o = 1; o < 256; o <<= 1) {
        int add = (t >= o) ? s[t - o] : 0;
        __syncthreads();
        s[t] += add;
        __syncthreads();
    }
    bs[t] = s[t] - v;   // exclusive block offsets
}

__global__ void scan3(int* __restrict__ rp, const int* __restrict__ bs, int* __restrict__ cnt) {
    int i = blockIdx.x * 256 + threadIdx.x;
    if (i < NNODES) {
        int v = rp[i] + bs[blockIdx.x];
        rp[i] = v;
        cnt[i] = v;
    }
    if (i == 0) rp[NNODES] = E2;
}

__global__ void fill_csr(const int* __restrict__ ei, int* __restrict__ cnt, int* __restrict__ csr) {
    int i = blockIdx.x * 256 + threadIdx.x;
    if (i >= E2) return;
    int s, d;
    if (i < NEDGES) { s = ei[i]; d = ei[NEDGES + i]; }
    else            { s = d = i - NEDGES; }
    int pos = atomicAdd(&cnt[d], 1);
    csr[pos] = s;
}

// ---------------- fp32 GEMM: out[M,256] = A[M,256] @ W[256,256]^T ----------------

__global__ __launch_bounds__(256, 2) void gemm256(const float* __restrict__ A,
                                                  const float* __restrict__ W,
                                                  float* __restrict__ out, int M) {
    __shared__ float sA[128][33];
    __shared__ float sW[128][33];
    const int t = threadIdx.x;
    const int m0 = blockIdx.x * 128, n0 = blockIdx.y * 128;
    const int tx = t & 15, ty = t >> 4;
    const int lr = t >> 3;   // 0..31 (staging row base)
    const int lq = t & 7;    // 0..7  (float4 slot)

    float acc[8][8];
#pragma unroll
    for (int r = 0; r < 8; r++)
#pragma unroll
        for (int c = 0; c < 8; c++) acc[r][c] = 0.f;

    for (int kc = 0; kc < 256; kc += 32) {
#pragma unroll
        for (int i = 0; i < 4; i++) {
            int row = lr + 32 * i;
            int gr = m0 + row;
            gr = gr < M ? gr : M - 1;
            float4 av = *(const float4*)(A + (size_t)gr * HC + kc + lq * 4);
            sA[row][lq * 4 + 0] = av.x;
            sA[row][lq * 4 + 1] = av.y;
            sA[row][lq * 4 + 2] = av.z;
            sA[row][lq * 4 + 3] = av.w;
            float4 wv = *(const float4*)(W + (size_t)(n0 + row) * HC + kc + lq * 4);
            sW[row][lq * 4 + 0] = wv.x;
            sW[row][lq * 4 + 1] = wv.y;
            sW[row][lq * 4 + 2] = wv.z;
            sW[row][lq * 4 + 3] = wv.w;
        }
        __syncthreads();
#pragma unroll 2
        for (int k = 0; k < 32; k++) {
            float a[8], w[8];
#pragma unroll
            for (int r = 0; r < 8; r++) a[r] = sA[ty + 16 * r][k];
#pragma unroll
            for (int c = 0; c < 8; c++) w[c] = sW[tx + 16 * c][k];
#pragma unroll
            for (int r = 0; r < 8; r++)
#pragma unroll
                for (int c = 0; c < 8; c++) acc[r][c] = fmaf(a[r], w[c], acc[r][c]);
        }
        __syncthreads();
    }
#pragma unroll
    for (int r = 0; r < 8; r++) {
        int gr = m0 + ty + 16 * r;
        if (gr < M) {
#pragma unroll
            for (int c = 0; c < 8; c++) {
                out[(size_t)gr * HC + n0 + tx + 16 * c] = acc[r][c];
            }
        }
    }
}

// ---------------- per-(node,head) attention logits: asrc/adst ----------------

__global__ void alpha_hc(const float* __restrict__ h, const float* __restrict__ a_s,
                         const float* __restrict__ a_d, float* __restrict__ asrc,
                         float* __restrict__ adst) {
    int n = blockIdx.x;
    int t = threadIdx.x;
    float v = h[(size_t)n * HC + t];
    float ps = v * a_s[t];
    float pd = v * a_d[t];
    for (int o = 32; o > 0; o >>= 1) {
        ps += __shfl_xor(ps, o);
        pd += __shfl_xor(pd, o);
    }
    if ((t & 63) == 0) {
        int w = t >> 6;
        asrc[n * 4 + w] = ps;
        adst[n * 4 + w] = pd;
    }
}

// ---------------- fused segment softmax + aggregation (layers 1,2) ----------------
// one block per dst node; wave w == head w; lane l == channel l.
// neighbor ids staged in LDS; softmax weights computed lane-parallel into LDS
// (once per edge-head, not 64x); gather loop unrolled x4 to batch h-row loads.

#define CHUNK 512

__global__ void aggregate_hc(const float* __restrict__ h, const float* __restrict__ asrc,
                             const float* __restrict__ adst, const int* __restrict__ rp,
                             const int* __restrict__ csr, const float* __restrict__ bias,
                             float* __restrict__ y) {
    __shared__ int   sIdx[CHUNK];
    __shared__ float sE[CHUNK * 4];
    int n = blockIdx.x;
    int t = threadIdx.x;
    int w = t >> 6, l = t & 63;
    int r0 = rp[n], deg = rp[n + 1] - r0;
    float ad = adst[n * 4 + w];
    int hoff = (w << 6) + l;

    if (deg <= CHUNK) {
        // stage neighbor ids (coalesced, all 256 threads)
        for (int j = t; j < deg; j += 256) sIdx[j] = csr[r0 + j];
        __syncthreads();

        // lane-parallel logits -> LDS, running max
        float m = -1e30f;
        for (int j = l; j < deg; j += 64) {
            int s = sIdx[j];
            float e = asrc[s * 4 + w] + ad;
            e = e > 0.f ? e : 0.2f * e;
            sE[j * 4 + w] = e;
            m = fmaxf(m, e);
        }
#pragma unroll
        for (int o = 32; o > 0; o >>= 1) m = fmaxf(m, __shfl_xor(m, o));

        // lane-parallel exp + sum (in place)
        float ssum = 0.f;
        for (int j = l; j < deg; j += 64) {
            float ex = __expf(sE[j * 4 + w] - m);
            sE[j * 4 + w] = ex;
            ssum += ex;
        }
#pragma unroll
        for (int o = 32; o > 0; o >>= 1) ssum += __shfl_xor(ssum, o);

        // gather: unroll 4, batch the h-row loads
        float acc = 0.f;
        int j = 0;
        for (; j + 4 <= deg; j += 4) {
            int s0 = sIdx[j], s1 = sIdx[j + 1], s2 = sIdx[j + 2], s3 = sIdx[j + 3];
            float a0 = sE[(j) * 4 + w], a1 = sE[(j + 1) * 4 + w];
            float a2 = sE[(j + 2) * 4 + w], a3 = sE[(j + 3) * 4 + w];
            float h0 = h[(size_t)s0 * HC + hoff];
            float h1 = h[(size_t)s1 * HC + hoff];
            float h2 = h[(size_t)s2 * HC + hoff];
            float h3v = h[(size_t)s3 * HC + hoff];
            acc = fmaf(a0, h0, acc);
            acc = fmaf(a1, h1, acc);
            acc = fmaf(a2, h2, acc);
            acc = fmaf(a3, h3v, acc);
        }
        for (; j < deg; j++) {
            acc = fmaf(sE[j * 4 + w], h[(size_t)sIdx[j] * HC + hoff], acc);
        }

        float outv = acc / ssum + bias[hoff];
        outv = outv > 0.f ? outv : expm1f(outv);
        y[(size_t)n * HC + hoff] = outv;
    } else {
        // fallback (unreachable for this graph size, kept for correctness)
        float m = -1e30f;
        for (int j = l; j < deg; j += 64) {
            int s = csr[r0 + j];
            float e = asrc[s * 4 + w] + ad;
            e = e > 0.f ? e : 0.2f * e;
            m = fmaxf(m, e);
        }
#pragma unroll
        for (int o = 32; o > 0; o >>= 1) m = fmaxf(m, __shfl_xor(m, o));

        float acc = 0.f, ssum = 0.f;
        for (int j = 0; j < deg; j++) {
            int s = csr[r0 + j];
            float e = asrc[s * 4 + w] + ad;
            e = e > 0.f ? e : 0.2f * e;
            float a = __expf(e - m);
            ssum += a;
            acc = fmaf(a, h[(size_t)s * HC + hoff], acc);
        }
        float outv = acc / ssum + bias[hoff];
        outv = outv > 0.f ? outv : expm1f(outv);
        y[(size_t)n * HC + hoff] = outv;
    }
}

// ---------------- layer 3: small GEMM [N,256] @ [12,256]^T ----------------

__global__ void gemm_small(const float* __restrict__ Y, const float* __restrict__ W3,
                           float* __restrict__ h3) {
    int idx = blockIdx.x * 256 + threadIdx.x;
    if (idx >= NNODES * 12) return;
    int n = idx / 12, o = idx - n * 12;
    const float4* xr = (const float4*)(Y + (size_t)n * HC);
    const float4* wr = (const float4*)(W3 + o * HC);
    float acc = 0.f;
#pragma unroll 8
    for (int k = 0; k < 64; k++) {
        float4 a = xr[k], b = wr[k];
        acc += a.x * b.x + a.y * b.y + a.z * b.z + a.w * b.w;
    }
    h3[idx] = acc;
}

__global__ void alpha3(const float* __restrict__ h3, const float* __restrict__ a_s,
                       const float* __restrict__ a_d, float* __restrict__ asrc,
                       float* __restrict__ adst) {
    int n = blockIdx.x * 256 + threadIdx.x;
    if (n >= NNODES) return;
    const float* hr = h3 + (size_t)n * 12;
    float s[4], d[4];
#pragma unroll
    for (int hh = 0; hh < 4; hh++) {
        s[hh] = hr[hh * 3] * a_s[hh * 3] + hr[hh * 3 + 1] * a_s[hh * 3 + 1] + hr[hh * 3 + 2] * a_s[hh * 3 + 2];
        d[hh] = hr[hh * 3] * a_d[hh * 3] + hr[hh * 3 + 1] * a_d[hh * 3 + 1] + hr[hh * 3 + 2] * a_d[hh * 3 + 2];
    }
    *(float4*)(asrc + n * 4) = make_float4(s[0], s[1], s[2], s[3]);
    *(float4*)(adst + n * 4) = make_float4(d[0], d[1], d[2], d[3]);
}

// layer-3 aggregate: one wave per node (4 nodes/block), heads averaged, +b3, ELU.
__global__ void aggregate3(const float* __restrict__ h3, const float* __restrict__ asrc,
                           const float* __restrict__ adst, const int* __restrict__ rp,
                           const int* __restrict__ csr, const float* __restrict__ b3,
                           float* __restrict__ out) {
    int n = blockIdx.x * 4 + (threadIdx.x >> 6);
    int l = threadIdx.x & 63;
    if (n >= NNODES) return;
    int r0 = rp[n], deg = rp[n + 1] - r0;
    float4 ad = *(const float4*)(adst + n * 4);

    float m0 = -1e30f, m1 = -1e30f, m2 = -1e30f, m3 = -1e30f;
    for (int j = l; j < deg; j += 64) {
        int s = csr[r0 + j];
        float4 a4 = *(const float4*)(asrc + s * 4);
        float e0 = a4.x + ad.x, e1 = a4.y + ad.y, e2 = a4.z + ad.z, e3 = a4.w + ad.w;
        e0 = e0 > 0.f ? e0 : 0.2f * e0;
        e1 = e1 > 0.f ? e1 : 0.2f * e1;
        e2 = e2 > 0.f ? e2 : 0.2f * e2;
        e3 = e3 > 0.f ? e3 : 0.2f * e3;
        m0 = fmaxf(m0, e0); m1 = fmaxf(m1, e1); m2 = fmaxf(m2, e2); m3 = fmaxf(m3, e3);
    }
    for (int o = 32; o > 0; o >>= 1) {
        m0 = fmaxf(m0, __shfl_xor(m0, o));
        m1 = fmaxf(m1, __shfl_xor(m1, o));
        m2 = fmaxf(m2, __shfl_xor(m2, o));
        m3 = fmaxf(m3, __shfl_xor(m3, o));
    }

    float acc[12];
#pragma unroll
    for (int k = 0; k < 12; k++) acc[k] = 0.f;
    float s0 = 0.f, s1 = 0.f, s2 = 0.f, s3 = 0.f;
    for (int j = l; j < deg; j += 64) {
        int s = csr[r0 + j];
        float4 a4 = *(const float4*)(asrc + s * 4);
        float e0 = a4.x + ad.x, e1 = a4.y + ad.y, e2 = a4.z + ad.z, e3 = a4.w + ad.w;
        e0 = e0 > 0.f ? e0 : 0.2f * e0;
        e1 = e1 > 0.f ? e1 : 0.2f * e1;
        e2 = e2 > 0.f ? e2 : 0.2f * e2;
        e3 = e3 > 0.f ? e3 : 0.2f * e3;
        float w0 = __expf(e0 - m0), w1 = __expf(e1 - m1), w2 = __expf(e2 - m2), w3 = __expf(e3 - m3);
        s0 += w0; s1 += w1; s2 += w2; s3 += w3;
        const float* hr = h3 + (size_t)s * 12;
#pragma unroll
        for (int c = 0; c < 3; c++) {
            acc[c]     += w0 * hr[c];
            acc[3 + c] += w1 * hr[3 + c];
            acc[6 + c] += w2 * hr[6 + c];
            acc[9 + c] += w3 * hr[9 + c];
        }
    }
    for (int o = 32; o > 0; o >>= 1) {
#pragma unroll
        for (int k = 0; k < 12; k++) acc[k] += __shfl_xor(acc[k], o);
        s0 += __shfl_xor(s0, o);
        s1 += __shfl_xor(s1, o);
        s2 += __shfl_xor(s2, o);
        s3 += __shfl_xor(s3, o);
    }
    if (l < 3) {
        float v = 0.25f * (acc[l] / s0 + acc[3 + l] / s1 + acc[6 + l] / s2 + acc[9 + l] / s3) + b3[l];
        v = v > 0.f ? v : expm1f(v);
        out[(size_t)n * 3 + l] = v;
    }
}

// ---------------- launch ----------------

extern "C" void kernel_launch(void* const* d_in, const int* in_sizes, int n_in,
                              void* d_out, int out_size, void* d_ws, size_t ws_size,
                              hipStream_t stream) {
    (void)in_sizes; (void)n_in; (void)out_size; (void)ws_size;
    const float* x   = (const float*)d_in[0];
    const int*   ei  = (const int*)d_in[1];
    const float* W1  = (const float*)d_in[2];
    const float* as1 = (const float*)d_in[3];
    const float* ad1 = (const float*)d_in[4];
    const float* b1  = (const float*)d_in[5];
    const float* W2  = (const float*)d_in[6];
    const float* as2 = (const float*)d_in[7];
    const float* ad2 = (const float*)d_in[8];
    const float* b2  = (const float*)d_in[9];
    const float* W3  = (const float*)d_in[10];
    const float* as3 = (const float*)d_in[11];
    const float* ad3 = (const float*)d_in[12];
    const float* b3  = (const float*)d_in[13];
    float* out = (float*)d_out;

    uint8_t* p = (uint8_t*)d_ws;
    auto alloc = [&](size_t bytes) -> void* {
        void* r = (void*)p;
        p += (bytes + 255) & ~(size_t)255;
        return r;
    };
    float* bufH = (float*)alloc((size_t)NNODES * HC * 4);
    float* bufY = (float*)alloc((size_t)NNODES * HC * 4);
    float* h3   = (float*)alloc((size_t)NNODES * 12 * 4);
    float* asrc = (float*)alloc((size_t)NNODES * 4 * 4);
    float* adst = (float*)alloc((size_t)NNODES * 4 * 4);
    int* deg    = (int*)alloc((size_t)NNODES * 4);
    int* rp     = (int*)alloc((size_t)(NNODES + 1) * 4);
    int* cnt    = (int*)alloc((size_t)NNODES * 4);
    int* csr    = (int*)alloc((size_t)E2 * 4);
    int* bsums  = (int*)alloc(256 * 4);

    const int NB_N = (NNODES + 255) / 256;     // 196
    const int NB_E = (E2 + 255) / 256;         // 3321

    // CSR build (counting sort by dst, self-loops appended)
    zero_int<<<NB_N, 256, 0, stream>>>(deg, NNODES);
    count_deg<<<NB_E, 256, 0, stream>>>(ei, deg);
    scan1<<<NB_N, 256, 0, stream>>>(deg, rp, bsums);
    scan2<<<1, 256, 0, stream>>>(bsums, NB_N);
    scan3<<<NB_N, 256, 0, stream>>>(rp, bsums, cnt);
    fill_csr<<<NB_E, 256, 0, stream>>>(ei, cnt, csr);

    // Layer 1
    gemm256<<<dim3((NNODES + 127) / 128, 2), 256, 0, stream>>>(x, W1, bufH, NNODES);
    alpha_hc<<<NNODES, 256, 0, stream>>>(bufH, as1, ad1, asrc, adst);
    aggregate_hc<<<NNODES, 256, 0, stream>>>(bufH, asrc, adst, rp, csr, b1, bufY);

    // Layer 2
    gemm256<<<dim3((NNODES + 127) / 128, 2), 256, 0, stream>>>(bufY, W2, bufH, NNODES);
    alpha_hc<<<NNODES, 256, 0, stream>>>(bufH, as2, ad2, asrc, adst);
    aggregate_hc<<<NNODES, 256, 0, stream>>>(bufH, asrc, adst, rp, csr, b2, bufY);

    // Layer 3
    gemm_small<<<(NNODES * 12 + 255) / 256, 256, 0, stream>>>(bufY, W3, h3);
    alpha3<<<NB_N, 256, 0, stream>>>(h3, as3, ad3, asrc, adst);
    aggregate3<<<(NNODES + 3) / 4, 256, 0, stream>>>(h3, asrc, adst, rp, csr, b3, out);
}

// Round 4
// 793.611 us; speedup vs baseline: 5.5777x; 1.1727x over previous
//
#include <hip/hip_runtime.h>
#include <cstdint>
#include <cstddef>

#define NNODES 50000
#define NEDGES 800000
#define E2 (NEDGES + NNODES)
#define HC 256

typedef __attribute__((ext_vector_type(8))) short short8v;  // 8 bf16 = 4 VGPR (MFMA A/B frag)
typedef __attribute__((ext_vector_type(4))) float f32x4;    // MFMA C/D frag

// ---------------- CSR build ----------------

__global__ void zero_int(int* __restrict__ p, int n) {
    int i = blockIdx.x * 256 + threadIdx.x;
    if (i < n) p[i] = 0;
}

__global__ void count_deg(const int* __restrict__ ei, int* __restrict__ deg) {
    int i = blockIdx.x * 256 + threadIdx.x;
    if (i >= E2) return;
    int d = (i < NEDGES) ? ei[NEDGES + i] : (i - NEDGES);
    atomicAdd(&deg[d], 1);
}

__global__ void scan1(const int* __restrict__ deg, int* __restrict__ rp, int* __restrict__ bs) {
    __shared__ int s[256];
    int t = threadIdx.x, i = blockIdx.x * 256 + t;
    int v = (i < NNODES) ? deg[i] : 0;
    s[t] = v;
    __syncthreads();
    for (int o = 1; o < 256; o <<= 1) {
        int add = (t >= o) ? s[t - o] : 0;
        __syncthreads();
        s[t] += add;
        __syncthreads();
    }
    if (i < NNODES) rp[i] = s[t] - v;
    if (t == 255) bs[blockIdx.x] = s[255];
}

__global__ void scan2(int* __restrict__ bs, int nb) {
    __shared__ int s[256];
    int t = threadIdx.x;
    int v = (t < nb) ? bs[t] : 0;
    s[t] = v;
    __syncthreads();
    for (int o = 1; o < 256; o <<= 1) {
        int add = (t >= o) ? s[t - o] : 0;
        __syncthreads();
        s[t] += add;
        __syncthreads();
    }
    bs[t] = s[t] - v;
}

__global__ void scan3(int* __restrict__ rp, const int* __restrict__ bs, int* __restrict__ cnt) {
    int i = blockIdx.x * 256 + threadIdx.x;
    if (i < NNODES) {
        int v = rp[i] + bs[blockIdx.x];
        rp[i] = v;
        cnt[i] = v;
    }
    if (i == 0) rp[NNODES] = E2;
}

__global__ void fill_csr(const int* __restrict__ ei, int* __restrict__ cnt, int* __restrict__ csr) {
    int i = blockIdx.x * 256 + threadIdx.x;
    if (i >= E2) return;
    int s, d;
    if (i < NEDGES) { s = ei[i]; d = ei[NEDGES + i]; }
    else            { s = d = i - NEDGES; }
    int pos = atomicAdd(&cnt[d], 1);
    csr[pos] = s;
}

// ---------------- fp32 -> split bf16 (hi + residual-lo), RNE ----------------

__device__ __forceinline__ unsigned short f2bf(float f) {
    uint32_t u = __float_as_uint(f);
    uint32_t r = (u + 0x7FFFu + ((u >> 16) & 1u)) >> 16;
    return (unsigned short)r;
}
__device__ __forceinline__ float bf2f(unsigned short h) {
    return __uint_as_float(((uint32_t)h) << 16);
}

__global__ void split_bf16(const float* __restrict__ in, unsigned short* __restrict__ hi,
                           unsigned short* __restrict__ lo, int n4) {
    int i = blockIdx.x * 256 + threadIdx.x;
    if (i >= n4) return;
    float4 v = ((const float4*)in)[i];
    unsigned short h0 = f2bf(v.x), h1 = f2bf(v.y), h2 = f2bf(v.z), h3 = f2bf(v.w);
    unsigned short l0 = f2bf(v.x - bf2f(h0));
    unsigned short l1 = f2bf(v.y - bf2f(h1));
    unsigned short l2 = f2bf(v.z - bf2f(h2));
    unsigned short l3 = f2bf(v.w - bf2f(h3));
    uint2 hp, lp;
    hp.x = (uint32_t)h0 | ((uint32_t)h1 << 16);
    hp.y = (uint32_t)h2 | ((uint32_t)h3 << 16);
    lp.x = (uint32_t)l0 | ((uint32_t)l1 << 16);
    lp.y = (uint32_t)l2 | ((uint32_t)l3 << 16);
    *(uint2*)(hi + 4 * (size_t)i) = hp;
    *(uint2*)(lo + 4 * (size_t)i) = lp;
}

// ---------------- MFMA split-bf16 GEMM: out[M,256] = A[M,256] @ W[256,256]^T ----------------
// 128x128 tile, 4 waves (2x2 of 64x64), K-step 32, 16x16x32 bf16 MFMA.
// out = Ah*Wh + Ah*Wl + Al*Wh (fp32 accumulate); error ~2^-18 relative.
// A/B frag: lane holds 8 k-contiguous bf16 at row/col (lane&15), k-group (lane>>4).
// C/D frag: col = lane&15, row = (lane>>4)*4 + reg  [m89/m91-verified].

__global__ __launch_bounds__(256, 2) void gemm_mfma(
    const unsigned short* __restrict__ Ah, const unsigned short* __restrict__ Al,
    const unsigned short* __restrict__ Wh, const unsigned short* __restrict__ Wl,
    float* __restrict__ out, int M) {
    __shared__ unsigned short sAh[128][32], sAl[128][32], sWh[128][32], sWl[128][32];
    const int t = threadIdx.x;
    const int m0 = blockIdx.x * 128, n0 = blockIdx.y * 128;
    const int lane = t & 63, w = t >> 6;
    const int wr = w >> 1, wc = w & 1;         // wave's 64x64 quadrant
    const int fr = lane & 15, fg = lane >> 4;  // frag row/col, k-group

    f32x4 acc[4][4];
#pragma unroll
    for (int mi = 0; mi < 4; mi++)
#pragma unroll
        for (int ni = 0; ni < 4; ni++) acc[mi][ni] = (f32x4){0.f, 0.f, 0.f, 0.f};

    for (int kc = 0; kc < 256; kc += 32) {
        // stage 4 x 8KB tiles; thread t handles 16B units t and t+256 (contiguous LDS)
#pragma unroll
        for (int i = 0; i < 2; i++) {
            int u = t + 256 * i;           // 0..511
            int row = u >> 2;              // 0..127
            int cb = (u & 3) * 8;          // bf16 col offset 0/8/16/24
            int gra = m0 + row; gra = gra < M ? gra : M - 1;
            int grw = n0 + row;
            *(short8v*)&sAh[row][cb] = *(const short8v*)(Ah + (size_t)gra * HC + kc + cb);
            *(short8v*)&sAl[row][cb] = *(const short8v*)(Al + (size_t)gra * HC + kc + cb);
            *(short8v*)&sWh[row][cb] = *(const short8v*)(Wh + (size_t)grw * HC + kc + cb);
            *(short8v*)&sWl[row][cb] = *(const short8v*)(Wl + (size_t)grw * HC + kc + cb);
        }
        __syncthreads();

        short8v ah[4], al[4], bh[4], bl[4];
#pragma unroll
        for (int i = 0; i < 4; i++) {
            ah[i] = *(const short8v*)&sAh[wr * 64 + i * 16 + fr][fg * 8];
            al[i] = *(const short8v*)&sAl[wr * 64 + i * 16 + fr][fg * 8];
            bh[i] = *(const short8v*)&sWh[wc * 64 + i * 16 + fr][fg * 8];
            bl[i] = *(const short8v*)&sWl[wc * 64 + i * 16 + fr][fg * 8];
        }
#pragma unroll
        for (int mi = 0; mi < 4; mi++)
#pragma unroll
            for (int ni = 0; ni < 4; ni++) {
                acc[mi][ni] = __builtin_amdgcn_mfma_f32_16x16x32_bf16(ah[mi], bh[ni], acc[mi][ni], 0, 0, 0);
                acc[mi][ni] = __builtin_amdgcn_mfma_f32_16x16x32_bf16(ah[mi], bl[ni], acc[mi][ni], 0, 0, 0);
                acc[mi][ni] = __builtin_amdgcn_mfma_f32_16x16x32_bf16(al[mi], bh[ni], acc[mi][ni], 0, 0, 0);
            }
        __syncthreads();
    }

#pragma unroll
    for (int mi = 0; mi < 4; mi++) {
#pragma unroll
        for (int r = 0; r < 4; r++) {
            int gr = m0 + wr * 64 + mi * 16 + fg * 4 + r;
            if (gr < M) {
#pragma unroll
                for (int ni = 0; ni < 4; ni++) {
                    out[(size_t)gr * HC + n0 + wc * 64 + ni * 16 + fr] = acc[mi][ni][r];
                }
            }
        }
    }
}

// ---------------- per-(node,head) attention logits ----------------

__global__ void alpha_hc(const float* __restrict__ h, const float* __restrict__ a_s,
                         const float* __restrict__ a_d, float* __restrict__ asrc,
                         float* __restrict__ adst) {
    int n = blockIdx.x;
    int t = threadIdx.x;
    float v = h[(size_t)n * HC + t];
    float ps = v * a_s[t];
    float pd = v * a_d[t];
    for (int o = 32; o > 0; o >>= 1) {
        ps += __shfl_xor(ps, o);
        pd += __shfl_xor(pd, o);
    }
    if ((t & 63) == 0) {
        int w = t >> 6;
        asrc[n * 4 + w] = ps;
        adst[n * 4 + w] = pd;
    }
}

// ---------------- fused segment softmax + aggregation (layers 1,2) ----------------

#define CHUNK 512

__global__ void aggregate_hc(const float* __restrict__ h, const float* __restrict__ asrc,
                             const float* __restrict__ adst, const int* __restrict__ rp,
                             const int* __restrict__ csr, const float* __restrict__ bias,
                             float* __restrict__ y) {
    __shared__ int   sIdx[CHUNK];
    __shared__ float sE[4][CHUNK];   // [head][edge]: lane-parallel stride-1, conflict-free
    int n = blockIdx.x;
    int t = threadIdx.x;
    int w = t >> 6, l = t & 63;
    int r0 = rp[n], deg = rp[n + 1] - r0;
    float ad = adst[n * 4 + w];
    int hoff = (w << 6) + l;

    if (deg <= CHUNK) {
        for (int j = t; j < deg; j += 256) sIdx[j] = csr[r0 + j];
        __syncthreads();

        float m = -1e30f;
        for (int j = l; j < deg; j += 64) {
            int s = sIdx[j];
            float e = asrc[s * 4 + w] + ad;
            e = e > 0.f ? e : 0.2f * e;
            sE[w][j] = e;
            m = fmaxf(m, e);
        }
#pragma unroll
        for (int o = 32; o > 0; o >>= 1) m = fmaxf(m, __shfl_xor(m, o));

        float ssum = 0.f;
        for (int j = l; j < deg; j += 64) {
            float ex = __expf(sE[w][j] - m);
            sE[w][j] = ex;
            ssum += ex;
        }
#pragma unroll
        for (int o = 32; o > 0; o >>= 1) ssum += __shfl_xor(ssum, o);

        float acc = 0.f;
        int j = 0;
        for (; j + 4 <= deg; j += 4) {
            int s0 = sIdx[j], s1 = sIdx[j + 1], s2 = sIdx[j + 2], s3 = sIdx[j + 3];
            float a0 = sE[w][j], a1 = sE[w][j + 1], a2 = sE[w][j + 2], a3 = sE[w][j + 3];
            float h0 = h[(size_t)s0 * HC + hoff];
            float h1 = h[(size_t)s1 * HC + hoff];
            float h2 = h[(size_t)s2 * HC + hoff];
            float h3v = h[(size_t)s3 * HC + hoff];
            acc = fmaf(a0, h0, acc);
            acc = fmaf(a1, h1, acc);
            acc = fmaf(a2, h2, acc);
            acc = fmaf(a3, h3v, acc);
        }
        for (; j < deg; j++) {
            acc = fmaf(sE[w][j], h[(size_t)sIdx[j] * HC + hoff], acc);
        }

        float outv = acc / ssum + bias[hoff];
        outv = outv > 0.f ? outv : expm1f(outv);
        y[(size_t)n * HC + hoff] = outv;
    } else {
        float m = -1e30f;
        for (int j = l; j < deg; j += 64) {
            int s = csr[r0 + j];
            float e = asrc[s * 4 + w] + ad;
            e = e > 0.f ? e : 0.2f * e;
            m = fmaxf(m, e);
        }
#pragma unroll
        for (int o = 32; o > 0; o >>= 1) m = fmaxf(m, __shfl_xor(m, o));

        float acc = 0.f, ssum = 0.f;
        for (int j = 0; j < deg; j++) {
            int s = csr[r0 + j];
            float e = asrc[s * 4 + w] + ad;
            e = e > 0.f ? e : 0.2f * e;
            float a = __expf(e - m);
            ssum += a;
            acc = fmaf(a, h[(size_t)s * HC + hoff], acc);
        }
        float outv = acc / ssum + bias[hoff];
        outv = outv > 0.f ? outv : expm1f(outv);
        y[(size_t)n * HC + hoff] = outv;
    }
}

// ---------------- layer 3 ----------------

__global__ void gemm_small(const float* __restrict__ Y, const float* __restrict__ W3,
                           float* __restrict__ h3) {
    int idx = blockIdx.x * 256 + threadIdx.x;
    if (idx >= NNODES * 12) return;
    int n = idx / 12, o = idx - n * 12;
    const float4* xr = (const float4*)(Y + (size_t)n * HC);
    const float4* wr = (const float4*)(W3 + o * HC);
    float acc = 0.f;
#pragma unroll 8
    for (int k = 0; k < 64; k++) {
        float4 a = xr[k], b = wr[k];
        acc += a.x * b.x + a.y * b.y + a.z * b.z + a.w * b.w;
    }
    h3[idx] = acc;
}

__global__ void alpha3(const float* __restrict__ h3, const float* __restrict__ a_s,
                       const float* __restrict__ a_d, float* __restrict__ asrc,
                       float* __restrict__ adst) {
    int n = blockIdx.x * 256 + threadIdx.x;
    if (n >= NNODES) return;
    const float* hr = h3 + (size_t)n * 12;
    float s[4], d[4];
#pragma unroll
    for (int hh = 0; hh < 4; hh++) {
        s[hh] = hr[hh * 3] * a_s[hh * 3] + hr[hh * 3 + 1] * a_s[hh * 3 + 1] + hr[hh * 3 + 2] * a_s[hh * 3 + 2];
        d[hh] = hr[hh * 3] * a_d[hh * 3] + hr[hh * 3 + 1] * a_d[hh * 3 + 1] + hr[hh * 3 + 2] * a_d[hh * 3 + 2];
    }
    *(float4*)(asrc + n * 4) = make_float4(s[0], s[1], s[2], s[3]);
    *(float4*)(adst + n * 4) = make_float4(d[0], d[1], d[2], d[3]);
}

__global__ void aggregate3(const float* __restrict__ h3, const float* __restrict__ asrc,
                           const float* __restrict__ adst, const int* __restrict__ rp,
                           const int* __restrict__ csr, const float* __restrict__ b3,
                           float* __restrict__ out) {
    int n = blockIdx.x * 4 + (threadIdx.x >> 6);
    int l = threadIdx.x & 63;
    if (n >= NNODES) return;
    int r0 = rp[n], deg = rp[n + 1] - r0;
    float4 ad = *(const float4*)(adst + n * 4);

    float m0 = -1e30f, m1 = -1e30f, m2 = -1e30f, m3 = -1e30f;
    for (int j = l; j < deg; j += 64) {
        int s = csr[r0 + j];
        float4 a4 = *(const float4*)(asrc + s * 4);
        float e0 = a4.x + ad.x, e1 = a4.y + ad.y, e2 = a4.z + ad.z, e3 = a4.w + ad.w;
        e0 = e0 > 0.f ? e0 : 0.2f * e0;
        e1 = e1 > 0.f ? e1 : 0.2f * e1;
        e2 = e2 > 0.f ? e2 : 0.2f * e2;
        e3 = e3 > 0.f ? e3 : 0.2f * e3;
        m0 = fmaxf(m0, e0); m1 = fmaxf(m1, e1); m2 = fmaxf(m2, e2); m3 = fmaxf(m3, e3);
    }
    for (int o = 32; o > 0; o >>= 1) {
        m0 = fmaxf(m0, __shfl_xor(m0, o));
        m1 = fmaxf(m1, __shfl_xor(m1, o));
        m2 = fmaxf(m2, __shfl_xor(m2, o));
        m3 = fmaxf(m3, __shfl_xor(m3, o));
    }

    float acc[12];
#pragma unroll
    for (int k = 0; k < 12; k++) acc[k] = 0.f;
    float s0 = 0.f, s1 = 0.f, s2 = 0.f, s3 = 0.f;
    for (int j = l; j < deg; j += 64) {
        int s = csr[r0 + j];
        float4 a4 = *(const float4*)(asrc + s * 4);
        float e0 = a4.x + ad.x, e1 = a4.y + ad.y, e2 = a4.z + ad.z, e3 = a4.w + ad.w;
        e0 = e0 > 0.f ? e0 : 0.2f * e0;
        e1 = e1 > 0.f ? e1 : 0.2f * e1;
        e2 = e2 > 0.f ? e2 : 0.2f * e2;
        e3 = e3 > 0.f ? e3 : 0.2f * e3;
        float w0 = __expf(e0 - m0), w1 = __expf(e1 - m1), w2 = __expf(e2 - m2), w3 = __expf(e3 - m3);
        s0 += w0; s1 += w1; s2 += w2; s3 += w3;
        const float* hr = h3 + (size_t)s * 12;
#pragma unroll
        for (int c = 0; c < 3; c++) {
            acc[c]     += w0 * hr[c];
            acc[3 + c] += w1 * hr[3 + c];
            acc[6 + c] += w2 * hr[6 + c];
            acc[9 + c] += w3 * hr[9 + c];
        }
    }
    for (int o = 32; o > 0; o >>= 1) {
#pragma unroll
        for (int k = 0; k < 12; k++) acc[k] += __shfl_xor(acc[k], o);
        s0 += __shfl_xor(s0, o);
        s1 += __shfl_xor(s1, o);
        s2 += __shfl_xor(s2, o);
        s3 += __shfl_xor(s3, o);
    }
    if (l < 3) {
        float v = 0.25f * (acc[l] / s0 + acc[3 + l] / s1 + acc[6 + l] / s2 + acc[9 + l] / s3) + b3[l];
        v = v > 0.f ? v : expm1f(v);
        out[(size_t)n * 3 + l] = v;
    }
}

// ---------------- launch ----------------

extern "C" void kernel_launch(void* const* d_in, const int* in_sizes, int n_in,
                              void* d_out, int out_size, void* d_ws, size_t ws_size,
                              hipStream_t stream) {
    (void)in_sizes; (void)n_in; (void)out_size; (void)ws_size;
    const float* x   = (const float*)d_in[0];
    const int*   ei  = (const int*)d_in[1];
    const float* W1  = (const float*)d_in[2];
    const float* as1 = (const float*)d_in[3];
    const float* ad1 = (const float*)d_in[4];
    const float* b1  = (const float*)d_in[5];
    const float* W2  = (const float*)d_in[6];
    const float* as2 = (const float*)d_in[7];
    const float* ad2 = (const float*)d_in[8];
    const float* b2  = (const float*)d_in[9];
    const float* W3  = (const float*)d_in[10];
    const float* as3 = (const float*)d_in[11];
    const float* ad3 = (const float*)d_in[12];
    const float* b3  = (const float*)d_in[13];
    float* out = (float*)d_out;

    uint8_t* p = (uint8_t*)d_ws;
    auto alloc = [&](size_t bytes) -> void* {
        void* r = (void*)p;
        p += (bytes + 255) & ~(size_t)255;
        return r;
    };
    float* bufH = (float*)alloc((size_t)NNODES * HC * 4);
    float* bufY = (float*)alloc((size_t)NNODES * HC * 4);
    float* h3   = (float*)alloc((size_t)NNODES * 12 * 4);
    float* asrc = (float*)alloc((size_t)NNODES * 4 * 4);
    float* adst = (float*)alloc((size_t)NNODES * 4 * 4);
    int* deg    = (int*)alloc((size_t)NNODES * 4);
    int* rp     = (int*)alloc((size_t)(NNODES + 1) * 4);
    int* cnt    = (int*)alloc((size_t)NNODES * 4);
    int* csr    = (int*)alloc((size_t)E2 * 4);
    int* bsums  = (int*)alloc(256 * 4);
    unsigned short* xh  = (unsigned short*)alloc((size_t)NNODES * HC * 2);
    unsigned short* xl  = (unsigned short*)alloc((size_t)NNODES * HC * 2);
    unsigned short* w1h = (unsigned short*)alloc((size_t)HC * HC * 2);
    unsigned short* w1l = (unsigned short*)alloc((size_t)HC * HC * 2);
    unsigned short* w2h = (unsigned short*)alloc((size_t)HC * HC * 2);
    unsigned short* w2l = (unsigned short*)alloc((size_t)HC * HC * 2);

    const int NB_N = (NNODES + 255) / 256;
    const int NB_E = (E2 + 255) / 256;
    const int N4_A = NNODES * HC / 4;   // float4 count for node features
    const int N4_W = HC * HC / 4;

    // CSR build
    zero_int<<<NB_N, 256, 0, stream>>>(deg, NNODES);
    count_deg<<<NB_E, 256, 0, stream>>>(ei, deg);
    scan1<<<NB_N, 256, 0, stream>>>(deg, rp, bsums);
    scan2<<<1, 256, 0, stream>>>(bsums, NB_N);
    scan3<<<NB_N, 256, 0, stream>>>(rp, bsums, cnt);
    fill_csr<<<NB_E, 256, 0, stream>>>(ei, cnt, csr);

    dim3 ggrid((NNODES + 127) / 128, 2);

    // Layer 1
    split_bf16<<<(N4_W + 255) / 256, 256, 0, stream>>>(W1, w1h, w1l, N4_W);
    split_bf16<<<(N4_A + 255) / 256, 256, 0, stream>>>(x, xh, xl, N4_A);
    gemm_mfma<<<ggrid, 256, 0, stream>>>(xh, xl, w1h, w1l, bufH, NNODES);
    alpha_hc<<<NNODES, 256, 0, stream>>>(bufH, as1, ad1, asrc, adst);
    aggregate_hc<<<NNODES, 256, 0, stream>>>(bufH, asrc, adst, rp, csr, b1, bufY);

    // Layer 2
    split_bf16<<<(N4_W + 255) / 256, 256, 0, stream>>>(W2, w2h, w2l, N4_W);
    split_bf16<<<(N4_A + 255) / 256, 256, 0, stream>>>(bufY, xh, xl, N4_A);
    gemm_mfma<<<ggrid, 256, 0, stream>>>(xh, xl, w2h, w2l, bufH, NNODES);
    alpha_hc<<<NNODES, 256, 0, stream>>>(bufH, as2, ad2, asrc, adst);
    aggregate_hc<<<NNODES, 256, 0, stream>>>(bufH, asrc, adst, rp, csr, b2, bufY);

    // Layer 3
    gemm_small<<<(NNODES * 12 + 255) / 256, 256, 0, stream>>>(bufY, W3, h3);
    alpha3<<<NB_N, 256, 0, stream>>>(h3, as3, ad3, asrc, adst);
    aggregate3<<<(NNODES + 3) / 4, 256, 0, stream>>>(h3, asrc, adst, rp, csr, b3, out);
}

// Round 5
// 749.215 us; speedup vs baseline: 5.9083x; 1.0593x over previous
//
#include <hip/hip_runtime.h>
#include <hip/hip_fp16.h>
#include <cstdint>
#include <cstddef>

#define NNODES 50000
#define NEDGES 800000
#define E2 (NEDGES + NNODES)
#define HC 256

typedef __attribute__((ext_vector_type(8))) short short8v;  // 8 bf16 = 4 VGPR (MFMA A/B frag)
typedef __attribute__((ext_vector_type(4))) float f32x4;    // MFMA C/D frag

// ---------------- CSR build ----------------

__global__ void zero_int(int* __restrict__ p, int n) {
    int i = blockIdx.x * 256 + threadIdx.x;
    if (i < n) p[i] = 0;
}

__global__ void count_deg(const int* __restrict__ ei, int* __restrict__ deg) {
    int i = blockIdx.x * 256 + threadIdx.x;
    if (i >= E2) return;
    int d = (i < NEDGES) ? ei[NEDGES + i] : (i - NEDGES);
    atomicAdd(&deg[d], 1);
}

__global__ void scan1(const int* __restrict__ deg, int* __restrict__ rp, int* __restrict__ bs) {
    __shared__ int s[256];
    int t = threadIdx.x, i = blockIdx.x * 256 + t;
    int v = (i < NNODES) ? deg[i] : 0;
    s[t] = v;
    __syncthreads();
    for (int o = 1; o < 256; o <<= 1) {
        int add = (t >= o) ? s[t - o] : 0;
        __syncthreads();
        s[t] += add;
        __syncthreads();
    }
    if (i < NNODES) rp[i] = s[t] - v;
    if (t == 255) bs[blockIdx.x] = s[255];
}

__global__ void scan2(int* __restrict__ bs, int nb) {
    __shared__ int s[256];
    int t = threadIdx.x;
    int v = (t < nb) ? bs[t] : 0;
    s[t] = v;
    __syncthreads();
    for (int o = 1; o < 256; o <<= 1) {
        int add = (t >= o) ? s[t - o] : 0;
        __syncthreads();
        s[t] += add;
        __syncthreads();
    }
    bs[t] = s[t] - v;
}

__global__ void scan3(int* __restrict__ rp, const int* __restrict__ bs, int* __restrict__ cnt) {
    int i = blockIdx.x * 256 + threadIdx.x;
    if (i < NNODES) {
        int v = rp[i] + bs[blockIdx.x];
        rp[i] = v;
        cnt[i] = v;
    }
    if (i == 0) rp[NNODES] = E2;
}

__global__ void fill_csr(const int* __restrict__ ei, int* __restrict__ cnt, int* __restrict__ csr) {
    int i = blockIdx.x * 256 + threadIdx.x;
    if (i >= E2) return;
    int s, d;
    if (i < NEDGES) { s = ei[i]; d = ei[NEDGES + i]; }
    else            { s = d = i - NEDGES; }
    int pos = atomicAdd(&cnt[d], 1);
    csr[pos] = s;
}

// ---------------- fp32 -> split bf16 (hi + residual-lo), RNE ----------------

__device__ __forceinline__ unsigned short f2bf(float f) {
    uint32_t u = __float_as_uint(f);
    uint32_t r = (u + 0x7FFFu + ((u >> 16) & 1u)) >> 16;
    return (unsigned short)r;
}
__device__ __forceinline__ float bf2f(unsigned short h) {
    return __uint_as_float(((uint32_t)h) << 16);
}

__global__ void split_bf16(const float* __restrict__ in, unsigned short* __restrict__ hi,
                           unsigned short* __restrict__ lo, int n4) {
    int i = blockIdx.x * 256 + threadIdx.x;
    if (i >= n4) return;
    float4 v = ((const float4*)in)[i];
    unsigned short h0 = f2bf(v.x), h1 = f2bf(v.y), h2 = f2bf(v.z), h3 = f2bf(v.w);
    unsigned short l0 = f2bf(v.x - bf2f(h0));
    unsigned short l1 = f2bf(v.y - bf2f(h1));
    unsigned short l2 = f2bf(v.z - bf2f(h2));
    unsigned short l3 = f2bf(v.w - bf2f(h3));
    uint2 hp, lp;
    hp.x = (uint32_t)h0 | ((uint32_t)h1 << 16);
    hp.y = (uint32_t)h2 | ((uint32_t)h3 << 16);
    lp.x = (uint32_t)l0 | ((uint32_t)l1 << 16);
    lp.y = (uint32_t)l2 | ((uint32_t)l3 << 16);
    *(uint2*)(hi + 4 * (size_t)i) = hp;
    *(uint2*)(lo + 4 * (size_t)i) = lp;
}

// ---------------- MFMA split-bf16 GEMM: out[M,256] = A[M,256] @ W[256,256]^T ----------------
// Also emits an fp16 copy of the output (gather-optimized feed for aggregate_hc).

__global__ __launch_bounds__(256, 2) void gemm_mfma(
    const unsigned short* __restrict__ Ah, const unsigned short* __restrict__ Al,
    const unsigned short* __restrict__ Wh, const unsigned short* __restrict__ Wl,
    float* __restrict__ out, _Float16* __restrict__ out16, int M) {
    __shared__ unsigned short sAh[128][32], sAl[128][32], sWh[128][32], sWl[128][32];
    const int t = threadIdx.x;
    const int m0 = blockIdx.x * 128, n0 = blockIdx.y * 128;
    const int lane = t & 63, w = t >> 6;
    const int wr = w >> 1, wc = w & 1;         // wave's 64x64 quadrant
    const int fr = lane & 15, fg = lane >> 4;  // frag row/col, k-group

    f32x4 acc[4][4];
#pragma unroll
    for (int mi = 0; mi < 4; mi++)
#pragma unroll
        for (int ni = 0; ni < 4; ni++) acc[mi][ni] = (f32x4){0.f, 0.f, 0.f, 0.f};

    for (int kc = 0; kc < 256; kc += 32) {
#pragma unroll
        for (int i = 0; i < 2; i++) {
            int u = t + 256 * i;           // 0..511
            int row = u >> 2;              // 0..127
            int cb = (u & 3) * 8;          // bf16 col offset 0/8/16/24
            int gra = m0 + row; gra = gra < M ? gra : M - 1;
            int grw = n0 + row;
            *(short8v*)&sAh[row][cb] = *(const short8v*)(Ah + (size_t)gra * HC + kc + cb);
            *(short8v*)&sAl[row][cb] = *(const short8v*)(Al + (size_t)gra * HC + kc + cb);
            *(short8v*)&sWh[row][cb] = *(const short8v*)(Wh + (size_t)grw * HC + kc + cb);
            *(short8v*)&sWl[row][cb] = *(const short8v*)(Wl + (size_t)grw * HC + kc + cb);
        }
        __syncthreads();

        short8v ah[4], al[4], bh[4], bl[4];
#pragma unroll
        for (int i = 0; i < 4; i++) {
            ah[i] = *(const short8v*)&sAh[wr * 64 + i * 16 + fr][fg * 8];
            al[i] = *(const short8v*)&sAl[wr * 64 + i * 16 + fr][fg * 8];
            bh[i] = *(const short8v*)&sWh[wc * 64 + i * 16 + fr][fg * 8];
            bl[i] = *(const short8v*)&sWl[wc * 64 + i * 16 + fr][fg * 8];
        }
#pragma unroll
        for (int mi = 0; mi < 4; mi++)
#pragma unroll
            for (int ni = 0; ni < 4; ni++) {
                acc[mi][ni] = __builtin_amdgcn_mfma_f32_16x16x32_bf16(ah[mi], bh[ni], acc[mi][ni], 0, 0, 0);
                acc[mi][ni] = __builtin_amdgcn_mfma_f32_16x16x32_bf16(ah[mi], bl[ni], acc[mi][ni], 0, 0, 0);
                acc[mi][ni] = __builtin_amdgcn_mfma_f32_16x16x32_bf16(al[mi], bh[ni], acc[mi][ni], 0, 0, 0);
            }
        __syncthreads();
    }

#pragma unroll
    for (int mi = 0; mi < 4; mi++) {
#pragma unroll
        for (int r = 0; r < 4; r++) {
            int gr = m0 + wr * 64 + mi * 16 + fg * 4 + r;
            if (gr < M) {
#pragma unroll
                for (int ni = 0; ni < 4; ni++) {
                    float v = acc[mi][ni][r];
                    size_t off = (size_t)gr * HC + n0 + wc * 64 + ni * 16 + fr;
                    out[off] = v;
                    out16[off] = (_Float16)v;
                }
            }
        }
    }
}

// ---------------- per-(node,head) attention logits ----------------

__global__ void alpha_hc(const float* __restrict__ h, const float* __restrict__ a_s,
                         const float* __restrict__ a_d, float* __restrict__ asrc,
                         float* __restrict__ adst) {
    int n = blockIdx.x;
    int t = threadIdx.x;
    float v = h[(size_t)n * HC + t];
    float ps = v * a_s[t];
    float pd = v * a_d[t];
    for (int o = 32; o > 0; o >>= 1) {
        ps += __shfl_xor(ps, o);
        pd += __shfl_xor(pd, o);
    }
    if ((t & 63) == 0) {
        int w = t >> 6;
        asrc[n * 4 + w] = ps;
        adst[n * 4 + w] = pd;
    }
}

// ---------------- fused segment softmax + aggregation (layers 1,2) ----------------
// gather reads fp16 h (128B/wave per edge-head): halves the dominant traffic.

#define CHUNK 512

__global__ void aggregate_hc(const _Float16* __restrict__ h16, const float* __restrict__ asrc,
                             const float* __restrict__ adst, const int* __restrict__ rp,
                             const int* __restrict__ csr, const float* __restrict__ bias,
                             float* __restrict__ y) {
    __shared__ int   sIdx[CHUNK];
    __shared__ float sE[4][CHUNK];
    int n = blockIdx.x;
    int t = threadIdx.x;
    int w = t >> 6, l = t & 63;
    int r0 = rp[n], deg = rp[n + 1] - r0;
    float ad = adst[n * 4 + w];
    int hoff = (w << 6) + l;
    const _Float16* hp = h16 + hoff;

    if (deg <= CHUNK) {
        for (int j = t; j < deg; j += 256) sIdx[j] = csr[r0 + j];
        __syncthreads();

        float m = -1e30f;
        for (int j = l; j < deg; j += 64) {
            int s = sIdx[j];
            float e = asrc[s * 4 + w] + ad;
            e = e > 0.f ? e : 0.2f * e;
            sE[w][j] = e;
            m = fmaxf(m, e);
        }
#pragma unroll
        for (int o = 32; o > 0; o >>= 1) m = fmaxf(m, __shfl_xor(m, o));

        float ssum = 0.f;
        for (int j = l; j < deg; j += 64) {
            float ex = __expf(sE[w][j] - m);
            sE[w][j] = ex;
            ssum += ex;
        }
#pragma unroll
        for (int o = 32; o > 0; o >>= 1) ssum += __shfl_xor(ssum, o);

        float acc = 0.f;
        int j = 0;
        for (; j + 4 <= deg; j += 4) {
            int s0 = sIdx[j], s1 = sIdx[j + 1], s2 = sIdx[j + 2], s3 = sIdx[j + 3];
            float a0 = sE[w][j], a1 = sE[w][j + 1], a2 = sE[w][j + 2], a3 = sE[w][j + 3];
            float h0 = (float)hp[(size_t)s0 * HC];
            float h1 = (float)hp[(size_t)s1 * HC];
            float h2 = (float)hp[(size_t)s2 * HC];
            float h3v = (float)hp[(size_t)s3 * HC];
            acc = fmaf(a0, h0, acc);
            acc = fmaf(a1, h1, acc);
            acc = fmaf(a2, h2, acc);
            acc = fmaf(a3, h3v, acc);
        }
        for (; j < deg; j++) {
            acc = fmaf(sE[w][j], (float)hp[(size_t)sIdx[j] * HC], acc);
        }

        float outv = acc / ssum + bias[hoff];
        outv = outv > 0.f ? outv : expm1f(outv);
        y[(size_t)n * HC + hoff] = outv;
    } else {
        float m = -1e30f;
        for (int j = l; j < deg; j += 64) {
            int s = csr[r0 + j];
            float e = asrc[s * 4 + w] + ad;
            e = e > 0.f ? e : 0.2f * e;
            m = fmaxf(m, e);
        }
#pragma unroll
        for (int o = 32; o > 0; o >>= 1) m = fmaxf(m, __shfl_xor(m, o));

        float acc = 0.f, ssum = 0.f;
        for (int j = 0; j < deg; j++) {
            int s = csr[r0 + j];
            float e = asrc[s * 4 + w] + ad;
            e = e > 0.f ? e : 0.2f * e;
            float a = __expf(e - m);
            ssum += a;
            acc = fmaf(a, (float)hp[(size_t)s * HC], acc);
        }
        float outv = acc / ssum + bias[hoff];
        outv = outv > 0.f ? outv : expm1f(outv);
        y[(size_t)n * HC + hoff] = outv;
    }
}

// ---------------- layer 3 ----------------

__global__ void gemm_small(const float* __restrict__ Y, const float* __restrict__ W3,
                           float* __restrict__ h3) {
    int idx = blockIdx.x * 256 + threadIdx.x;
    if (idx >= NNODES * 12) return;
    int n = idx / 12, o = idx - n * 12;
    const float4* xr = (const float4*)(Y + (size_t)n * HC);
    const float4* wr = (const float4*)(W3 + o * HC);
    float acc = 0.f;
#pragma unroll 8
    for (int k = 0; k < 64; k++) {
        float4 a = xr[k], b = wr[k];
        acc += a.x * b.x + a.y * b.y + a.z * b.z + a.w * b.w;
    }
    h3[idx] = acc;
}

__global__ void alpha3(const float* __restrict__ h3, const float* __restrict__ a_s,
                       const float* __restrict__ a_d, float* __restrict__ asrc,
                       float* __restrict__ adst) {
    int n = blockIdx.x * 256 + threadIdx.x;
    if (n >= NNODES) return;
    const float* hr = h3 + (size_t)n * 12;
    float s[4], d[4];
#pragma unroll
    for (int hh = 0; hh < 4; hh++) {
        s[hh] = hr[hh * 3] * a_s[hh * 3] + hr[hh * 3 + 1] * a_s[hh * 3 + 1] + hr[hh * 3 + 2] * a_s[hh * 3 + 2];
        d[hh] = hr[hh * 3] * a_d[hh * 3] + hr[hh * 3 + 1] * a_d[hh * 3 + 1] + hr[hh * 3 + 2] * a_d[hh * 3 + 2];
    }
    *(float4*)(asrc + n * 4) = make_float4(s[0], s[1], s[2], s[3]);
    *(float4*)(adst + n * 4) = make_float4(d[0], d[1], d[2], d[3]);
}

__global__ void aggregate3(const float* __restrict__ h3, const float* __restrict__ asrc,
                           const float* __restrict__ adst, const int* __restrict__ rp,
                           const int* __restrict__ csr, const float* __restrict__ b3,
                           float* __restrict__ out) {
    int n = blockIdx.x * 4 + (threadIdx.x >> 6);
    int l = threadIdx.x & 63;
    if (n >= NNODES) return;
    int r0 = rp[n], deg = rp[n + 1] - r0;
    float4 ad = *(const float4*)(adst + n * 4);

    float m0 = -1e30f, m1 = -1e30f, m2 = -1e30f, m3 = -1e30f;
    for (int j = l; j < deg; j += 64) {
        int s = csr[r0 + j];
        float4 a4 = *(const float4*)(asrc + s * 4);
        float e0 = a4.x + ad.x, e1 = a4.y + ad.y, e2 = a4.z + ad.z, e3 = a4.w + ad.w;
        e0 = e0 > 0.f ? e0 : 0.2f * e0;
        e1 = e1 > 0.f ? e1 : 0.2f * e1;
        e2 = e2 > 0.f ? e2 : 0.2f * e2;
        e3 = e3 > 0.f ? e3 : 0.2f * e3;
        m0 = fmaxf(m0, e0); m1 = fmaxf(m1, e1); m2 = fmaxf(m2, e2); m3 = fmaxf(m3, e3);
    }
    for (int o = 32; o > 0; o >>= 1) {
        m0 = fmaxf(m0, __shfl_xor(m0, o));
        m1 = fmaxf(m1, __shfl_xor(m1, o));
        m2 = fmaxf(m2, __shfl_xor(m2, o));
        m3 = fmaxf(m3, __shfl_xor(m3, o));
    }

    float acc[12];
#pragma unroll
    for (int k = 0; k < 12; k++) acc[k] = 0.f;
    float s0 = 0.f, s1 = 0.f, s2 = 0.f, s3 = 0.f;
    for (int j = l; j < deg; j += 64) {
        int s = csr[r0 + j];
        float4 a4 = *(const float4*)(asrc + s * 4);
        float e0 = a4.x + ad.x, e1 = a4.y + ad.y, e2 = a4.z + ad.z, e3 = a4.w + ad.w;
        e0 = e0 > 0.f ? e0 : 0.2f * e0;
        e1 = e1 > 0.f ? e1 : 0.2f * e1;
        e2 = e2 > 0.f ? e2 : 0.2f * e2;
        e3 = e3 > 0.f ? e3 : 0.2f * e3;
        float w0 = __expf(e0 - m0), w1 = __expf(e1 - m1), w2 = __expf(e2 - m2), w3 = __expf(e3 - m3);
        s0 += w0; s1 += w1; s2 += w2; s3 += w3;
        const float* hr = h3 + (size_t)s * 12;
#pragma unroll
        for (int c = 0; c < 3; c++) {
            acc[c]     += w0 * hr[c];
            acc[3 + c] += w1 * hr[3 + c];
            acc[6 + c] += w2 * hr[6 + c];
            acc[9 + c] += w3 * hr[9 + c];
        }
    }
    for (int o = 32; o > 0; o >>= 1) {
#pragma unroll
        for (int k = 0; k < 12; k++) acc[k] += __shfl_xor(acc[k], o);
        s0 += __shfl_xor(s0, o);
        s1 += __shfl_xor(s1, o);
        s2 += __shfl_xor(s2, o);
        s3 += __shfl_xor(s3, o);
    }
    if (l < 3) {
        float v = 0.25f * (acc[l] / s0 + acc[3 + l] / s1 + acc[6 + l] / s2 + acc[9 + l] / s3) + b3[l];
        v = v > 0.f ? v : expm1f(v);
        out[(size_t)n * 3 + l] = v;
    }
}

// ---------------- launch ----------------

extern "C" void kernel_launch(void* const* d_in, const int* in_sizes, int n_in,
                              void* d_out, int out_size, void* d_ws, size_t ws_size,
                              hipStream_t stream) {
    (void)in_sizes; (void)n_in; (void)out_size; (void)ws_size;
    const float* x   = (const float*)d_in[0];
    const int*   ei  = (const int*)d_in[1];
    const float* W1  = (const float*)d_in[2];
    const float* as1 = (const float*)d_in[3];
    const float* ad1 = (const float*)d_in[4];
    const float* b1  = (const float*)d_in[5];
    const float* W2  = (const float*)d_in[6];
    const float* as2 = (const float*)d_in[7];
    const float* ad2 = (const float*)d_in[8];
    const float* b2  = (const float*)d_in[9];
    const float* W3  = (const float*)d_in[10];
    const float* as3 = (const float*)d_in[11];
    const float* ad3 = (const float*)d_in[12];
    const float* b3  = (const float*)d_in[13];
    float* out = (float*)d_out;

    uint8_t* p = (uint8_t*)d_ws;
    auto alloc = [&](size_t bytes) -> void* {
        void* r = (void*)p;
        p += (bytes + 255) & ~(size_t)255;
        return r;
    };
    float* bufH = (float*)alloc((size_t)NNODES * HC * 4);
    float* bufY = (float*)alloc((size_t)NNODES * HC * 4);
    float* h3   = (float*)alloc((size_t)NNODES * 12 * 4);
    float* asrc = (float*)alloc((size_t)NNODES * 4 * 4);
    float* adst = (float*)alloc((size_t)NNODES * 4 * 4);
    int* deg    = (int*)alloc((size_t)NNODES * 4);
    int* rp     = (int*)alloc((size_t)(NNODES + 1) * 4);
    int* cnt    = (int*)alloc((size_t)NNODES * 4);
    int* csr    = (int*)alloc((size_t)E2 * 4);
    int* bsums  = (int*)alloc(256 * 4);
    unsigned short* xh  = (unsigned short*)alloc((size_t)NNODES * HC * 2);
    unsigned short* xl  = (unsigned short*)alloc((size_t)NNODES * HC * 2);
    unsigned short* w1h = (unsigned short*)alloc((size_t)HC * HC * 2);
    unsigned short* w1l = (unsigned short*)alloc((size_t)HC * HC * 2);
    unsigned short* w2h = (unsigned short*)alloc((size_t)HC * HC * 2);
    unsigned short* w2l = (unsigned short*)alloc((size_t)HC * HC * 2);
    _Float16* h16 = (_Float16*)alloc((size_t)NNODES * HC * 2);

    const int NB_N = (NNODES + 255) / 256;
    const int NB_E = (E2 + 255) / 256;
    const int N4_A = NNODES * HC / 4;
    const int N4_W = HC * HC / 4;

    // CSR build
    zero_int<<<NB_N, 256, 0, stream>>>(deg, NNODES);
    count_deg<<<NB_E, 256, 0, stream>>>(ei, deg);
    scan1<<<NB_N, 256, 0, stream>>>(deg, rp, bsums);
    scan2<<<1, 256, 0, stream>>>(bsums, NB_N);
    scan3<<<NB_N, 256, 0, stream>>>(rp, bsums, cnt);
    fill_csr<<<NB_E, 256, 0, stream>>>(ei, cnt, csr);

    dim3 ggrid((NNODES + 127) / 128, 2);

    // Layer 1
    split_bf16<<<(N4_W + 255) / 256, 256, 0, stream>>>(W1, w1h, w1l, N4_W);
    split_bf16<<<(N4_A + 255) / 256, 256, 0, stream>>>(x, xh, xl, N4_A);
    gemm_mfma<<<ggrid, 256, 0, stream>>>(xh, xl, w1h, w1l, bufH, h16, NNODES);
    alpha_hc<<<NNODES, 256, 0, stream>>>(bufH, as1, ad1, asrc, adst);
    aggregate_hc<<<NNODES, 256, 0, stream>>>(h16, asrc, adst, rp, csr, b1, bufY);

    // Layer 2
    split_bf16<<<(N4_W + 255) / 256, 256, 0, stream>>>(W2, w2h, w2l, N4_W);
    split_bf16<<<(N4_A + 255) / 256, 256, 0, stream>>>(bufY, xh, xl, N4_A);
    gemm_mfma<<<ggrid, 256, 0, stream>>>(xh, xl, w2h, w2l, bufH, h16, NNODES);
    alpha_hc<<<NNODES, 256, 0, stream>>>(bufH, as2, ad2, asrc, adst);
    aggregate_hc<<<NNODES, 256, 0, stream>>>(h16, asrc, adst, rp, csr, b2, bufY);

    // Layer 3
    gemm_small<<<(NNODES * 12 + 255) / 256, 256, 0, stream>>>(bufY, W3, h3);
    alpha3<<<NB_N, 256, 0, stream>>>(h3, as3, ad3, asrc, adst);
    aggregate3<<<(NNODES + 3) / 4, 256, 0, stream>>>(h3, asrc, adst, rp, csr, b3, out);
}

// Round 6
// 715.374 us; speedup vs baseline: 6.1878x; 1.0473x over previous
//
#include <hip/hip_runtime.h>
#include <hip/hip_fp16.h>
#include <cstdint>
#include <cstddef>

#define NNODES 50000
#define NEDGES 800000
#define E2 (NEDGES + NNODES)
#define HC 256

typedef __attribute__((ext_vector_type(8))) short short8v;  // 8 bf16 = 4 VGPR (MFMA A/B frag)
typedef __attribute__((ext_vector_type(4))) float f32x4;    // MFMA C/D frag

// ---------------- CSR build ----------------

__global__ void zero_int(int* __restrict__ p, int n) {
    int i = blockIdx.x * 256 + threadIdx.x;
    if (i < n) p[i] = 0;
}

__global__ void count_deg(const int* __restrict__ ei, int* __restrict__ deg) {
    int i = blockIdx.x * 256 + threadIdx.x;
    if (i >= E2) return;
    int d = (i < NEDGES) ? ei[NEDGES + i] : (i - NEDGES);
    atomicAdd(&deg[d], 1);
}

__global__ void scan1(const int* __restrict__ deg, int* __restrict__ rp, int* __restrict__ bs) {
    __shared__ int s[256];
    int t = threadIdx.x, i = blockIdx.x * 256 + t;
    int v = (i < NNODES) ? deg[i] : 0;
    s[t] = v;
    __syncthreads();
    for (int o = 1; o < 256; o <<= 1) {
        int add = (t >= o) ? s[t - o] : 0;
        __syncthreads();
        s[t] += add;
        __syncthreads();
    }
    if (i < NNODES) rp[i] = s[t] - v;
    if (t == 255) bs[blockIdx.x] = s[255];
}

__global__ void scan2(int* __restrict__ bs, int nb) {
    __shared__ int s[256];
    int t = threadIdx.x;
    int v = (t < nb) ? bs[t] : 0;
    s[t] = v;
    __syncthreads();
    for (int o = 1; o < 256; o <<= 1) {
        int add = (t >= o) ? s[t - o] : 0;
        __syncthreads();
        s[t] += add;
        __syncthreads();
    }
    bs[t] = s[t] - v;
}

__global__ void scan3(int* __restrict__ rp, const int* __restrict__ bs, int* __restrict__ cnt) {
    int i = blockIdx.x * 256 + threadIdx.x;
    if (i < NNODES) {
        int v = rp[i] + bs[blockIdx.x];
        rp[i] = v;
        cnt[i] = v;
    }
    if (i == 0) rp[NNODES] = E2;
}

__global__ void fill_csr(const int* __restrict__ ei, int* __restrict__ cnt, int* __restrict__ csr) {
    int i = blockIdx.x * 256 + threadIdx.x;
    if (i >= E2) return;
    int s, d;
    if (i < NEDGES) { s = ei[i]; d = ei[NEDGES + i]; }
    else            { s = d = i - NEDGES; }
    int pos = atomicAdd(&cnt[d], 1);
    csr[pos] = s;
}

// ---------------- fp32 -> split bf16 (hi + residual-lo), RNE ----------------

__device__ __forceinline__ unsigned short f2bf(float f) {
    uint32_t u = __float_as_uint(f);
    uint32_t r = (u + 0x7FFFu + ((u >> 16) & 1u)) >> 16;
    return (unsigned short)r;
}
__device__ __forceinline__ float bf2f(unsigned short h) {
    return __uint_as_float(((uint32_t)h) << 16);
}

__global__ void split_bf16(const float* __restrict__ in, unsigned short* __restrict__ hi,
                           unsigned short* __restrict__ lo, int n4) {
    int i = blockIdx.x * 256 + threadIdx.x;
    if (i >= n4) return;
    float4 v = ((const float4*)in)[i];
    unsigned short h0 = f2bf(v.x), h1 = f2bf(v.y), h2 = f2bf(v.z), h3 = f2bf(v.w);
    unsigned short l0 = f2bf(v.x - bf2f(h0));
    unsigned short l1 = f2bf(v.y - bf2f(h1));
    unsigned short l2 = f2bf(v.z - bf2f(h2));
    unsigned short l3 = f2bf(v.w - bf2f(h3));
    uint2 hp, lp;
    hp.x = (uint32_t)h0 | ((uint32_t)h1 << 16);
    hp.y = (uint32_t)h2 | ((uint32_t)h3 << 16);
    lp.x = (uint32_t)l0 | ((uint32_t)l1 << 16);
    lp.y = (uint32_t)l2 | ((uint32_t)l3 << 16);
    *(uint2*)(hi + 4 * (size_t)i) = hp;
    *(uint2*)(lo + 4 * (size_t)i) = lp;
}

// ---------------- MFMA split-bf16 GEMM: out[M,256] = A[M,256] @ W[256,256]^T ----------------

__global__ __launch_bounds__(256, 2) void gemm_mfma(
    const unsigned short* __restrict__ Ah, const unsigned short* __restrict__ Al,
    const unsigned short* __restrict__ Wh, const unsigned short* __restrict__ Wl,
    float* __restrict__ out, _Float16* __restrict__ out16, int M) {
    __shared__ unsigned short sAh[128][32], sAl[128][32], sWh[128][32], sWl[128][32];
    const int t = threadIdx.x;
    const int m0 = blockIdx.x * 128, n0 = blockIdx.y * 128;
    const int lane = t & 63, w = t >> 6;
    const int wr = w >> 1, wc = w & 1;
    const int fr = lane & 15, fg = lane >> 4;

    f32x4 acc[4][4];
#pragma unroll
    for (int mi = 0; mi < 4; mi++)
#pragma unroll
        for (int ni = 0; ni < 4; ni++) acc[mi][ni] = (f32x4){0.f, 0.f, 0.f, 0.f};

    for (int kc = 0; kc < 256; kc += 32) {
#pragma unroll
        for (int i = 0; i < 2; i++) {
            int u = t + 256 * i;
            int row = u >> 2;
            int cb = (u & 3) * 8;
            int gra = m0 + row; gra = gra < M ? gra : M - 1;
            int grw = n0 + row;
            *(short8v*)&sAh[row][cb] = *(const short8v*)(Ah + (size_t)gra * HC + kc + cb);
            *(short8v*)&sAl[row][cb] = *(const short8v*)(Al + (size_t)gra * HC + kc + cb);
            *(short8v*)&sWh[row][cb] = *(const short8v*)(Wh + (size_t)grw * HC + kc + cb);
            *(short8v*)&sWl[row][cb] = *(const short8v*)(Wl + (size_t)grw * HC + kc + cb);
        }
        __syncthreads();

        short8v ah[4], al[4], bh[4], bl[4];
#pragma unroll
        for (int i = 0; i < 4; i++) {
            ah[i] = *(const short8v*)&sAh[wr * 64 + i * 16 + fr][fg * 8];
            al[i] = *(const short8v*)&sAl[wr * 64 + i * 16 + fr][fg * 8];
            bh[i] = *(const short8v*)&sWh[wc * 64 + i * 16 + fr][fg * 8];
            bl[i] = *(const short8v*)&sWl[wc * 64 + i * 16 + fr][fg * 8];
        }
#pragma unroll
        for (int mi = 0; mi < 4; mi++)
#pragma unroll
            for (int ni = 0; ni < 4; ni++) {
                acc[mi][ni] = __builtin_amdgcn_mfma_f32_16x16x32_bf16(ah[mi], bh[ni], acc[mi][ni], 0, 0, 0);
                acc[mi][ni] = __builtin_amdgcn_mfma_f32_16x16x32_bf16(ah[mi], bl[ni], acc[mi][ni], 0, 0, 0);
                acc[mi][ni] = __builtin_amdgcn_mfma_f32_16x16x32_bf16(al[mi], bh[ni], acc[mi][ni], 0, 0, 0);
            }
        __syncthreads();
    }

#pragma unroll
    for (int mi = 0; mi < 4; mi++) {
#pragma unroll
        for (int r = 0; r < 4; r++) {
            int gr = m0 + wr * 64 + mi * 16 + fg * 4 + r;
            if (gr < M) {
#pragma unroll
                for (int ni = 0; ni < 4; ni++) {
                    float v = acc[mi][ni][r];
                    size_t off = (size_t)gr * HC + n0 + wc * 64 + ni * 16 + fr;
                    out[off] = v;
                    out16[off] = (_Float16)v;
                }
            }
        }
    }
}

// ---------------- per-(node,head) attention logits ----------------

__global__ void alpha_hc(const float* __restrict__ h, const float* __restrict__ a_s,
                         const float* __restrict__ a_d, float* __restrict__ asrc,
                         float* __restrict__ adst) {
    int n = blockIdx.x;
    int t = threadIdx.x;
    float v = h[(size_t)n * HC + t];
    float ps = v * a_s[t];
    float pd = v * a_d[t];
    for (int o = 32; o > 0; o >>= 1) {
        ps += __shfl_xor(ps, o);
        pd += __shfl_xor(pd, o);
    }
    if ((t & 63) == 0) {
        int w = t >> 6;
        asrc[n * 4 + w] = ps;
        adst[n * 4 + w] = pd;
    }
}

// ---------------- fused segment softmax + aggregation (layers 1,2) ----------------
// One block per dst node. Softmax phases: 256-thread parallel, thread t handles
// (edge-slot t>>2, head t&3). Gather: wave wv handles edges j=wv,wv+4,...; lane l
// loads 8B = 4 fp16 channels [4l..4l+3] -> one 512B coalesced row read per edge.
// Cross-wave 4KB LDS reduction. Epilogue optionally writes fp32 y and/or a
// split-bf16 (hi/lo) copy for the next MFMA layer (fuses split_bf16).

#define CHUNK 512

__global__ void aggregate_hc(const _Float16* __restrict__ h16, const float* __restrict__ asrc,
                             const float* __restrict__ adst, const int* __restrict__ rp,
                             const int* __restrict__ csr, const float* __restrict__ bias,
                             float* __restrict__ y, unsigned short* __restrict__ yh,
                             unsigned short* __restrict__ yl, int flags) {
    __shared__ int   sIdx[CHUNK];
    __shared__ float sE4[CHUNK][4];
    __shared__ float sRed[4][64][4];
    __shared__ float sM[4][4], sS[4][4];
    int n = blockIdx.x;
    int t = threadIdx.x;
    int r0 = rp[n], deg = rp[n + 1] - r0;

    if (deg <= CHUNK) {
        for (int j = t; j < deg; j += 256) sIdx[j] = csr[r0 + j];
        __syncthreads();

        // phase A: logits + per-head max (thread t -> head t&3, edge-slot t>>2)
        int hA = t & 3, jj = t >> 2;
        float adh = adst[n * 4 + hA];
        float pm = -1e30f;
        for (int j = jj; j < deg; j += 64) {
            int s = sIdx[j];
            float e = asrc[s * 4 + hA] + adh;
            e = e > 0.f ? e : 0.2f * e;
            sE4[j][hA] = e;
            pm = fmaxf(pm, e);
        }
#pragma unroll
        for (int o = 4; o <= 32; o <<= 1) pm = fmaxf(pm, __shfl_xor(pm, o));
        if ((t & 63) < 4) sM[t >> 6][t & 3] = pm;
        __syncthreads();

        // phase B: exp + per-head sum
        float mh = fmaxf(fmaxf(sM[0][hA], sM[1][hA]), fmaxf(sM[2][hA], sM[3][hA]));
        float ps = 0.f;
        for (int j = jj; j < deg; j += 64) {
            float ex = __expf(sE4[j][hA] - mh);
            sE4[j][hA] = ex;
            ps += ex;
        }
#pragma unroll
        for (int o = 4; o <= 32; o <<= 1) ps += __shfl_xor(ps, o);
        if ((t & 63) < 4) sS[t >> 6][t & 3] = ps;
        __syncthreads();

        // gather: wave wv -> edges wv, wv+4, ...; lane l -> channels 4l..4l+3
        int wv = t >> 6, l = t & 63;
        int hh = l >> 4;
        float a0 = 0.f, a1 = 0.f, a2 = 0.f, a3 = 0.f;
        for (int j = wv; j < deg; j += 4) {
            int s = sIdx[j];
            float aw = sE4[j][hh];
            uint2 raw = *(const uint2*)(h16 + (size_t)s * HC + 4 * l);
            __half2 p0 = *(__half2*)&raw.x;
            __half2 p1 = *(__half2*)&raw.y;
            a0 = fmaf(aw, __low2float(p0), a0);
            a1 = fmaf(aw, __high2float(p0), a1);
            a2 = fmaf(aw, __low2float(p1), a2);
            a3 = fmaf(aw, __high2float(p1), a3);
        }
        sRed[wv][l][0] = a0;
        sRed[wv][l][1] = a1;
        sRed[wv][l][2] = a2;
        sRed[wv][l][3] = a3;
        __syncthreads();

        // epilogue: thread t -> channel t
        int c = t;
        float val = sRed[0][c >> 2][c & 3] + sRed[1][c >> 2][c & 3]
                  + sRed[2][c >> 2][c & 3] + sRed[3][c >> 2][c & 3];
        int ch = c >> 6;
        float ssum = sS[0][ch] + sS[1][ch] + sS[2][ch] + sS[3][ch];
        float outv = val / ssum + bias[c];
        outv = outv > 0.f ? outv : expm1f(outv);
        size_t off = (size_t)n * HC + c;
        if (flags & 1) y[off] = outv;
        if (flags & 2) {
            unsigned short hi = f2bf(outv);
            yh[off] = hi;
            yl[off] = f2bf(outv - bf2f(hi));
        }
    } else {
        // fallback (unreachable for this graph size)
        int w = t >> 6, l = t & 63;
        float ad = adst[n * 4 + w];
        int hoff = (w << 6) + l;
        const _Float16* hp = h16 + hoff;
        float m = -1e30f;
        for (int j = l; j < deg; j += 64) {
            int s = csr[r0 + j];
            float e = asrc[s * 4 + w] + ad;
            e = e > 0.f ? e : 0.2f * e;
            m = fmaxf(m, e);
        }
#pragma unroll
        for (int o = 32; o > 0; o >>= 1) m = fmaxf(m, __shfl_xor(m, o));
        float acc = 0.f, ssum = 0.f;
        for (int j = 0; j < deg; j++) {
            int s = csr[r0 + j];
            float e = asrc[s * 4 + w] + ad;
            e = e > 0.f ? e : 0.2f * e;
            float a = __expf(e - m);
            ssum += a;
            acc = fmaf(a, (float)hp[(size_t)s * HC], acc);
        }
        float outv = acc / ssum + bias[hoff];
        outv = outv > 0.f ? outv : expm1f(outv);
        size_t off = (size_t)n * HC + hoff;
        if (flags & 1) y[off] = outv;
        if (flags & 2) {
            unsigned short hi = f2bf(outv);
            yh[off] = hi;
            yl[off] = f2bf(outv - bf2f(hi));
        }
    }
}

// ---------------- layer 3 ----------------

__global__ void gemm_small(const float* __restrict__ Y, const float* __restrict__ W3,
                           float* __restrict__ h3) {
    int idx = blockIdx.x * 256 + threadIdx.x;
    if (idx >= NNODES * 12) return;
    int n = idx / 12, o = idx - n * 12;
    const float4* xr = (const float4*)(Y + (size_t)n * HC);
    const float4* wr = (const float4*)(W3 + o * HC);
    float acc = 0.f;
#pragma unroll 8
    for (int k = 0; k < 64; k++) {
        float4 a = xr[k], b = wr[k];
        acc += a.x * b.x + a.y * b.y + a.z * b.z + a.w * b.w;
    }
    h3[idx] = acc;
}

__global__ void alpha3(const float* __restrict__ h3, const float* __restrict__ a_s,
                       const float* __restrict__ a_d, float* __restrict__ asrc,
                       float* __restrict__ adst) {
    int n = blockIdx.x * 256 + threadIdx.x;
    if (n >= NNODES) return;
    const float* hr = h3 + (size_t)n * 12;
    float s[4], d[4];
#pragma unroll
    for (int hh = 0; hh < 4; hh++) {
        s[hh] = hr[hh * 3] * a_s[hh * 3] + hr[hh * 3 + 1] * a_s[hh * 3 + 1] + hr[hh * 3 + 2] * a_s[hh * 3 + 2];
        d[hh] = hr[hh * 3] * a_d[hh * 3] + hr[hh * 3 + 1] * a_d[hh * 3 + 1] + hr[hh * 3 + 2] * a_d[hh * 3 + 2];
    }
    *(float4*)(asrc + n * 4) = make_float4(s[0], s[1], s[2], s[3]);
    *(float4*)(adst + n * 4) = make_float4(d[0], d[1], d[2], d[3]);
}

__global__ void aggregate3(const float* __restrict__ h3, const float* __restrict__ asrc,
                           const float* __restrict__ adst, const int* __restrict__ rp,
                           const int* __restrict__ csr, const float* __restrict__ b3,
                           float* __restrict__ out) {
    int n = blockIdx.x * 4 + (threadIdx.x >> 6);
    int l = threadIdx.x & 63;
    if (n >= NNODES) return;
    int r0 = rp[n], deg = rp[n + 1] - r0;
    float4 ad = *(const float4*)(adst + n * 4);

    float m0 = -1e30f, m1 = -1e30f, m2 = -1e30f, m3 = -1e30f;
    for (int j = l; j < deg; j += 64) {
        int s = csr[r0 + j];
        float4 a4 = *(const float4*)(asrc + s * 4);
        float e0 = a4.x + ad.x, e1 = a4.y + ad.y, e2 = a4.z + ad.z, e3 = a4.w + ad.w;
        e0 = e0 > 0.f ? e0 : 0.2f * e0;
        e1 = e1 > 0.f ? e1 : 0.2f * e1;
        e2 = e2 > 0.f ? e2 : 0.2f * e2;
        e3 = e3 > 0.f ? e3 : 0.2f * e3;
        m0 = fmaxf(m0, e0); m1 = fmaxf(m1, e1); m2 = fmaxf(m2, e2); m3 = fmaxf(m3, e3);
    }
    for (int o = 32; o > 0; o >>= 1) {
        m0 = fmaxf(m0, __shfl_xor(m0, o));
        m1 = fmaxf(m1, __shfl_xor(m1, o));
        m2 = fmaxf(m2, __shfl_xor(m2, o));
        m3 = fmaxf(m3, __shfl_xor(m3, o));
    }

    float acc[12];
#pragma unroll
    for (int k = 0; k < 12; k++) acc[k] = 0.f;
    float s0 = 0.f, s1 = 0.f, s2 = 0.f, s3 = 0.f;
    for (int j = l; j < deg; j += 64) {
        int s = csr[r0 + j];
        float4 a4 = *(const float4*)(asrc + s * 4);
        float e0 = a4.x + ad.x, e1 = a4.y + ad.y, e2 = a4.z + ad.z, e3 = a4.w + ad.w;
        e0 = e0 > 0.f ? e0 : 0.2f * e0;
        e1 = e1 > 0.f ? e1 : 0.2f * e1;
        e2 = e2 > 0.f ? e2 : 0.2f * e2;
        e3 = e3 > 0.f ? e3 : 0.2f * e3;
        float w0 = __expf(e0 - m0), w1 = __expf(e1 - m1), w2 = __expf(e2 - m2), w3 = __expf(e3 - m3);
        s0 += w0; s1 += w1; s2 += w2; s3 += w3;
        const float* hr = h3 + (size_t)s * 12;
#pragma unroll
        for (int c = 0; c < 3; c++) {
            acc[c]     += w0 * hr[c];
            acc[3 + c] += w1 * hr[3 + c];
            acc[6 + c] += w2 * hr[6 + c];
            acc[9 + c] += w3 * hr[9 + c];
        }
    }
    for (int o = 32; o > 0; o >>= 1) {
#pragma unroll
        for (int k = 0; k < 12; k++) acc[k] += __shfl_xor(acc[k], o);
        s0 += __shfl_xor(s0, o);
        s1 += __shfl_xor(s1, o);
        s2 += __shfl_xor(s2, o);
        s3 += __shfl_xor(s3, o);
    }
    if (l < 3) {
        float v = 0.25f * (acc[l] / s0 + acc[3 + l] / s1 + acc[6 + l] / s2 + acc[9 + l] / s3) + b3[l];
        v = v > 0.f ? v : expm1f(v);
        out[(size_t)n * 3 + l] = v;
    }
}

// ---------------- launch ----------------

extern "C" void kernel_launch(void* const* d_in, const int* in_sizes, int n_in,
                              void* d_out, int out_size, void* d_ws, size_t ws_size,
                              hipStream_t stream) {
    (void)in_sizes; (void)n_in; (void)out_size; (void)ws_size;
    const float* x   = (const float*)d_in[0];
    const int*   ei  = (const int*)d_in[1];
    const float* W1  = (const float*)d_in[2];
    const float* as1 = (const float*)d_in[3];
    const float* ad1 = (const float*)d_in[4];
    const float* b1  = (const float*)d_in[5];
    const float* W2  = (const float*)d_in[6];
    const float* as2 = (const float*)d_in[7];
    const float* ad2 = (const float*)d_in[8];
    const float* b2  = (const float*)d_in[9];
    const float* W3  = (const float*)d_in[10];
    const float* as3 = (const float*)d_in[11];
    const float* ad3 = (const float*)d_in[12];
    const float* b3  = (const float*)d_in[13];
    float* out = (float*)d_out;

    uint8_t* p = (uint8_t*)d_ws;
    auto alloc = [&](size_t bytes) -> void* {
        void* r = (void*)p;
        p += (bytes + 255) & ~(size_t)255;
        return r;
    };
    float* bufH = (float*)alloc((size_t)NNODES * HC * 4);
    float* bufY = (float*)alloc((size_t)NNODES * HC * 4);
    float* h3   = (float*)alloc((size_t)NNODES * 12 * 4);
    float* asrc = (float*)alloc((size_t)NNODES * 4 * 4);
    float* adst = (float*)alloc((size_t)NNODES * 4 * 4);
    int* deg    = (int*)alloc((size_t)NNODES * 4);
    int* rp     = (int*)alloc((size_t)(NNODES + 1) * 4);
    int* cnt    = (int*)alloc((size_t)NNODES * 4);
    int* csr    = (int*)alloc((size_t)E2 * 4);
    int* bsums  = (int*)alloc(256 * 4);
    unsigned short* xh  = (unsigned short*)alloc((size_t)NNODES * HC * 2);
    unsigned short* xl  = (unsigned short*)alloc((size_t)NNODES * HC * 2);
    unsigned short* w1h = (unsigned short*)alloc((size_t)HC * HC * 2);
    unsigned short* w1l = (unsigned short*)alloc((size_t)HC * HC * 2);
    unsigned short* w2h = (unsigned short*)alloc((size_t)HC * HC * 2);
    unsigned short* w2l = (unsigned short*)alloc((size_t)HC * HC * 2);
    _Float16* h16 = (_Float16*)alloc((size_t)NNODES * HC * 2);

    const int NB_N = (NNODES + 255) / 256;
    const int NB_E = (E2 + 255) / 256;
    const int N4_A = NNODES * HC / 4;
    const int N4_W = HC * HC / 4;

    // CSR build
    zero_int<<<NB_N, 256, 0, stream>>>(deg, NNODES);
    count_deg<<<NB_E, 256, 0, stream>>>(ei, deg);
    scan1<<<NB_N, 256, 0, stream>>>(deg, rp, bsums);
    scan2<<<1, 256, 0, stream>>>(bsums, NB_N);
    scan3<<<NB_N, 256, 0, stream>>>(rp, bsums, cnt);
    fill_csr<<<NB_E, 256, 0, stream>>>(ei, cnt, csr);

    dim3 ggrid((NNODES + 127) / 128, 2);

    // Layer 1
    split_bf16<<<(N4_W + 255) / 256, 256, 0, stream>>>(W1, w1h, w1l, N4_W);
    split_bf16<<<(N4_A + 255) / 256, 256, 0, stream>>>(x, xh, xl, N4_A);
    gemm_mfma<<<ggrid, 256, 0, stream>>>(xh, xl, w1h, w1l, bufH, h16, NNODES);
    alpha_hc<<<NNODES, 256, 0, stream>>>(bufH, as1, ad1, asrc, adst);
    // writes split-bf16 (xh/xl) directly for layer-2 GEMM; no fp32 y needed
    aggregate_hc<<<NNODES, 256, 0, stream>>>(h16, asrc, adst, rp, csr, b1, bufY, xh, xl, 2);

    // Layer 2
    split_bf16<<<(N4_W + 255) / 256, 256, 0, stream>>>(W2, w2h, w2l, N4_W);
    gemm_mfma<<<ggrid, 256, 0, stream>>>(xh, xl, w2h, w2l, bufH, h16, NNODES);
    alpha_hc<<<NNODES, 256, 0, stream>>>(bufH, as2, ad2, asrc, adst);
    // writes fp32 y (consumed by layer-3 gemm_small)
    aggregate_hc<<<NNODES, 256, 0, stream>>>(h16, asrc, adst, rp, csr, b2, bufY, xh, xl, 1);

    // Layer 3
    gemm_small<<<(NNODES * 12 + 255) / 256, 256, 0, stream>>>(bufY, W3, h3);
    alpha3<<<NB_N, 256, 0, stream>>>(h3, as3, ad3, asrc, adst);
    aggregate3<<<(NNODES + 3) / 4, 256, 0, stream>>>(h3, asrc, adst, rp, csr, b3, out);
}

// Round 7
// 664.413 us; speedup vs baseline: 6.6624x; 1.0767x over previous
//
#include <hip/hip_runtime.h>
#include <hip/hip_fp16.h>
#include <cstdint>
#include <cstddef>

#define NNODES 50000
#define NEDGES 800000
#define E2 (NEDGES + NNODES)
#define HC 256

typedef __attribute__((ext_vector_type(8))) short short8v;  // 8 bf16 = 4 VGPR (MFMA A/B frag)
typedef __attribute__((ext_vector_type(4))) float f32x4;    // MFMA C/D frag
typedef const __attribute__((address_space(1))) void* gas_t;
typedef __attribute__((address_space(3))) void* las_t;

// ---------------- CSR build ----------------

__global__ void zero_int(int* __restrict__ p, int n) {
    int i = blockIdx.x * 256 + threadIdx.x;
    if (i < n) p[i] = 0;
}

__global__ void count_deg(const int* __restrict__ ei, int* __restrict__ deg) {
    int i = blockIdx.x * 256 + threadIdx.x;
    if (i >= E2) return;
    int d = (i < NEDGES) ? ei[NEDGES + i] : (i - NEDGES);
    atomicAdd(&deg[d], 1);
}

__global__ void scan1(const int* __restrict__ deg, int* __restrict__ rp, int* __restrict__ bs) {
    __shared__ int s[256];
    int t = threadIdx.x, i = blockIdx.x * 256 + t;
    int v = (i < NNODES) ? deg[i] : 0;
    s[t] = v;
    __syncthreads();
    for (int o = 1; o < 256; o <<= 1) {
        int add = (t >= o) ? s[t - o] : 0;
        __syncthreads();
        s[t] += add;
        __syncthreads();
    }
    if (i < NNODES) rp[i] = s[t] - v;
    if (t == 255) bs[blockIdx.x] = s[255];
}

__global__ void scan2(int* __restrict__ bs, int nb) {
    __shared__ int s[256];
    int t = threadIdx.x;
    int v = (t < nb) ? bs[t] : 0;
    s[t] = v;
    __syncthreads();
    for (int o = 1; o < 256; o <<= 1) {
        int add = (t >= o) ? s[t - o] : 0;
        __syncthreads();
        s[t] += add;
        __syncthreads();
    }
    bs[t] = s[t] - v;
}

__global__ void scan3(int* __restrict__ rp, const int* __restrict__ bs, int* __restrict__ cnt) {
    int i = blockIdx.x * 256 + threadIdx.x;
    if (i < NNODES) {
        int v = rp[i] + bs[blockIdx.x];
        rp[i] = v;
        cnt[i] = v;
    }
    if (i == 0) rp[NNODES] = E2;
}

__global__ void fill_csr(const int* __restrict__ ei, int* __restrict__ cnt, int* __restrict__ csr) {
    int i = blockIdx.x * 256 + threadIdx.x;
    if (i >= E2) return;
    int s, d;
    if (i < NEDGES) { s = ei[i]; d = ei[NEDGES + i]; }
    else            { s = d = i - NEDGES; }
    int pos = atomicAdd(&cnt[d], 1);
    csr[pos] = s;
}

// ---------------- fp32 -> split bf16 (hi + residual-lo), RNE ----------------

__device__ __forceinline__ unsigned short f2bf(float f) {
    uint32_t u = __float_as_uint(f);
    uint32_t r = (u + 0x7FFFu + ((u >> 16) & 1u)) >> 16;
    return (unsigned short)r;
}
__device__ __forceinline__ float bf2f(unsigned short h) {
    return __uint_as_float(((uint32_t)h) << 16);
}

__global__ void split_bf16(const float* __restrict__ in, unsigned short* __restrict__ hi,
                           unsigned short* __restrict__ lo, int n4) {
    int i = blockIdx.x * 256 + threadIdx.x;
    if (i >= n4) return;
    float4 v = ((const float4*)in)[i];
    unsigned short h0 = f2bf(v.x), h1 = f2bf(v.y), h2 = f2bf(v.z), h3 = f2bf(v.w);
    unsigned short l0 = f2bf(v.x - bf2f(h0));
    unsigned short l1 = f2bf(v.y - bf2f(h1));
    unsigned short l2 = f2bf(v.z - bf2f(h2));
    unsigned short l3 = f2bf(v.w - bf2f(h3));
    uint2 hp, lp;
    hp.x = (uint32_t)h0 | ((uint32_t)h1 << 16);
    hp.y = (uint32_t)h2 | ((uint32_t)h3 << 16);
    lp.x = (uint32_t)l0 | ((uint32_t)l1 << 16);
    lp.y = (uint32_t)l2 | ((uint32_t)l3 << 16);
    *(uint2*)(hi + 4 * (size_t)i) = hp;
    *(uint2*)(lo + 4 * (size_t)i) = lp;
}

// ---------------- MFMA split-bf16 GEMM: out16[M,256] = A[M,256] @ W[256,256]^T ----------------
// global_load_lds (16B) staging, fp16-only output.

__global__ __launch_bounds__(256, 2) void gemm_mfma(
    const unsigned short* __restrict__ Ah, const unsigned short* __restrict__ Al,
    const unsigned short* __restrict__ Wh, const unsigned short* __restrict__ Wl,
    _Float16* __restrict__ out16, int M) {
    __shared__ unsigned short sAh[128][32], sAl[128][32], sWh[128][32], sWl[128][32];
    const int t = threadIdx.x;
    const int m0 = blockIdx.x * 128, n0 = blockIdx.y * 128;
    const int lane = t & 63, w = t >> 6;
    const int wr = w >> 1, wc = w & 1;
    const int fr = lane & 15, fg = lane >> 4;

    // staging geometry: wave w, sub-call i in {0,1}: unit u = (w*2+i)*64 + lane
    const int u0 = (w * 2) * 64 + lane, u1 = (w * 2 + 1) * 64 + lane;
    const int row0 = u0 >> 2, cb0 = (u0 & 3) * 8;
    const int row1 = u1 >> 2, cb1 = (u1 & 3) * 8;
    int gra0 = m0 + row0; gra0 = gra0 < M ? gra0 : M - 1;
    int gra1 = m0 + row1; gra1 = gra1 < M ? gra1 : M - 1;
    const int grw0 = n0 + row0, grw1 = n0 + row1;
    unsigned short* lA0 = &sAh[(w * 2) * 16][0];
    unsigned short* lA1 = &sAh[(w * 2 + 1) * 16][0];
    unsigned short* lB0 = &sAl[(w * 2) * 16][0];
    unsigned short* lB1 = &sAl[(w * 2 + 1) * 16][0];
    unsigned short* lC0 = &sWh[(w * 2) * 16][0];
    unsigned short* lC1 = &sWh[(w * 2 + 1) * 16][0];
    unsigned short* lD0 = &sWl[(w * 2) * 16][0];
    unsigned short* lD1 = &sWl[(w * 2 + 1) * 16][0];

    f32x4 acc[4][4];
#pragma unroll
    for (int mi = 0; mi < 4; mi++)
#pragma unroll
        for (int ni = 0; ni < 4; ni++) acc[mi][ni] = (f32x4){0.f, 0.f, 0.f, 0.f};

    for (int kc = 0; kc < 256; kc += 32) {
        __builtin_amdgcn_global_load_lds((gas_t)(Ah + (size_t)gra0 * HC + kc + cb0), (las_t)lA0, 16, 0, 0);
        __builtin_amdgcn_global_load_lds((gas_t)(Ah + (size_t)gra1 * HC + kc + cb1), (las_t)lA1, 16, 0, 0);
        __builtin_amdgcn_global_load_lds((gas_t)(Al + (size_t)gra0 * HC + kc + cb0), (las_t)lB0, 16, 0, 0);
        __builtin_amdgcn_global_load_lds((gas_t)(Al + (size_t)gra1 * HC + kc + cb1), (las_t)lB1, 16, 0, 0);
        __builtin_amdgcn_global_load_lds((gas_t)(Wh + (size_t)grw0 * HC + kc + cb0), (las_t)lC0, 16, 0, 0);
        __builtin_amdgcn_global_load_lds((gas_t)(Wh + (size_t)grw1 * HC + kc + cb1), (las_t)lC1, 16, 0, 0);
        __builtin_amdgcn_global_load_lds((gas_t)(Wl + (size_t)grw0 * HC + kc + cb0), (las_t)lD0, 16, 0, 0);
        __builtin_amdgcn_global_load_lds((gas_t)(Wl + (size_t)grw1 * HC + kc + cb1), (las_t)lD1, 16, 0, 0);
        __syncthreads();

        short8v ah[4], al[4], bh[4], bl[4];
#pragma unroll
        for (int i = 0; i < 4; i++) {
            ah[i] = *(const short8v*)&sAh[wr * 64 + i * 16 + fr][fg * 8];
            al[i] = *(const short8v*)&sAl[wr * 64 + i * 16 + fr][fg * 8];
            bh[i] = *(const short8v*)&sWh[wc * 64 + i * 16 + fr][fg * 8];
            bl[i] = *(const short8v*)&sWl[wc * 64 + i * 16 + fr][fg * 8];
        }
#pragma unroll
        for (int mi = 0; mi < 4; mi++)
#pragma unroll
            for (int ni = 0; ni < 4; ni++) {
                acc[mi][ni] = __builtin_amdgcn_mfma_f32_16x16x32_bf16(ah[mi], bh[ni], acc[mi][ni], 0, 0, 0);
                acc[mi][ni] = __builtin_amdgcn_mfma_f32_16x16x32_bf16(ah[mi], bl[ni], acc[mi][ni], 0, 0, 0);
                acc[mi][ni] = __builtin_amdgcn_mfma_f32_16x16x32_bf16(al[mi], bh[ni], acc[mi][ni], 0, 0, 0);
            }
        __syncthreads();
    }

#pragma unroll
    for (int mi = 0; mi < 4; mi++) {
#pragma unroll
        for (int r = 0; r < 4; r++) {
            int gr = m0 + wr * 64 + mi * 16 + fg * 4 + r;
            if (gr < M) {
#pragma unroll
                for (int ni = 0; ni < 4; ni++) {
                    out16[(size_t)gr * HC + n0 + wc * 64 + ni * 16 + fr] = (_Float16)acc[mi][ni][r];
                }
            }
        }
    }
}

// ---------------- per-(node,head) attention logits (reads fp16 h) ----------------

__global__ void alpha_hc(const _Float16* __restrict__ h16, const float* __restrict__ a_s,
                         const float* __restrict__ a_d, float* __restrict__ asrc,
                         float* __restrict__ adst) {
    int n = blockIdx.x;
    int t = threadIdx.x;
    float v = (float)h16[(size_t)n * HC + t];
    float ps = v * a_s[t];
    float pd = v * a_d[t];
    for (int o = 32; o > 0; o >>= 1) {
        ps += __shfl_xor(ps, o);
        pd += __shfl_xor(pd, o);
    }
    if ((t & 63) == 0) {
        int w = t >> 6;
        asrc[n * 4 + w] = ps;
        adst[n * 4 + w] = pd;
    }
}

// ---------------- fused segment softmax + aggregation (layers 1,2) ----------------
// Softmax: 256-thread parallel (head t&3, edge-slot t>>2). Gather: 8 groups of
// 32 lanes; group G owns edges j=G,G+8,...; lane q loads 16B = 8 fp16 channels
// [8q..8q+7] -> whole 512B row per edge in one wavefront-issue. fmaf((float)h,..)
// fuses to v_fma_mix_f32. Group pairs combine via shfl_xor(32); cross-wave via LDS.

#define CHUNK 512

__global__ void aggregate_hc(const _Float16* __restrict__ h16, const float* __restrict__ asrc,
                             const float* __restrict__ adst, const int* __restrict__ rp,
                             const int* __restrict__ csr, const float* __restrict__ bias,
                             float* __restrict__ y, unsigned short* __restrict__ yh,
                             unsigned short* __restrict__ yl, int flags) {
    __shared__ int   sIdx[CHUNK];
    __shared__ float sE4[CHUNK][4];
    __shared__ float sM[4][4], sS[4][4];
    __shared__ float sRed[4][32][9];   // [wave][q][ch], pad 9 vs bank conflicts
    int n = blockIdx.x;
    int t = threadIdx.x;
    int r0 = rp[n], deg = rp[n + 1] - r0;

    if (deg <= CHUNK) {
        for (int j = t; j < deg; j += 256) sIdx[j] = csr[r0 + j];
        __syncthreads();

        // phase A: logits + per-head max
        int hA = t & 3, jj = t >> 2;
        float adh = adst[n * 4 + hA];
        float pm = -1e30f;
        for (int j = jj; j < deg; j += 64) {
            int s = sIdx[j];
            float e = asrc[s * 4 + hA] + adh;
            e = e > 0.f ? e : 0.2f * e;
            sE4[j][hA] = e;
            pm = fmaxf(pm, e);
        }
#pragma unroll
        for (int o = 4; o <= 32; o <<= 1) pm = fmaxf(pm, __shfl_xor(pm, o));
        if ((t & 63) < 4) sM[t >> 6][t & 3] = pm;
        __syncthreads();

        // phase B: exp + per-head sum
        float mh = fmaxf(fmaxf(sM[0][hA], sM[1][hA]), fmaxf(sM[2][hA], sM[3][hA]));
        float ps = 0.f;
        for (int j = jj; j < deg; j += 64) {
            float ex = __expf(sE4[j][hA] - mh);
            sE4[j][hA] = ex;
            ps += ex;
        }
#pragma unroll
        for (int o = 4; o <= 32; o <<= 1) ps += __shfl_xor(ps, o);
        if ((t & 63) < 4) sS[t >> 6][t & 3] = ps;
        __syncthreads();

        // gather: group G (32 lanes) per edge; lane q -> channels 8q..8q+7
        int G = t >> 5, q = t & 31, hh = q >> 3;
        float a[8];
#pragma unroll
        for (int i = 0; i < 8; i++) a[i] = 0.f;
#pragma unroll 2
        for (int j = G; j < deg; j += 8) {
            int s = sIdx[j];
            float aw = sE4[j][hh];
            uint4 raw = *(const uint4*)(h16 + (size_t)s * HC + 8 * q);
            const _Float16* hv = reinterpret_cast<const _Float16*>(&raw);
#pragma unroll
            for (int i = 0; i < 8; i++) a[i] = fmaf((float)hv[i], aw, a[i]);
        }
        // combine paired groups (lanes l and l^32 hold same channels)
#pragma unroll
        for (int i = 0; i < 8; i++) a[i] += __shfl_xor(a[i], 32);
        int wv = t >> 6, l = t & 63;
        if (l < 32) {
#pragma unroll
            for (int i = 0; i < 8; i++) sRed[wv][l][i] = a[i];
        }
        __syncthreads();

        // epilogue: thread t -> channel t
        int c = t;
        float val = sRed[0][c >> 3][c & 7] + sRed[1][c >> 3][c & 7]
                  + sRed[2][c >> 3][c & 7] + sRed[3][c >> 3][c & 7];
        int ch = c >> 6;
        float ssum = sS[0][ch] + sS[1][ch] + sS[2][ch] + sS[3][ch];
        float outv = val / ssum + bias[c];
        outv = outv > 0.f ? outv : expm1f(outv);
        size_t off = (size_t)n * HC + c;
        if (flags & 1) y[off] = outv;
        if (flags & 2) {
            unsigned short hi = f2bf(outv);
            yh[off] = hi;
            yl[off] = f2bf(outv - bf2f(hi));
        }
    } else {
        // fallback (unreachable for this graph size)
        int w = t >> 6, l = t & 63;
        float ad = adst[n * 4 + w];
        int hoff = (w << 6) + l;
        const _Float16* hp = h16 + hoff;
        float m = -1e30f;
        for (int j = l; j < deg; j += 64) {
            int s = csr[r0 + j];
            float e = asrc[s * 4 + w] + ad;
            e = e > 0.f ? e : 0.2f * e;
            m = fmaxf(m, e);
        }
#pragma unroll
        for (int o = 32; o > 0; o >>= 1) m = fmaxf(m, __shfl_xor(m, o));
        float acc = 0.f, ssum = 0.f;
        for (int j = 0; j < deg; j++) {
            int s = csr[r0 + j];
            float e = asrc[s * 4 + w] + ad;
            e = e > 0.f ? e : 0.2f * e;
            float aa = __expf(e - m);
            ssum += aa;
            acc = fmaf(aa, (float)hp[(size_t)s * HC], acc);
        }
        float outv = acc / ssum + bias[hoff];
        outv = outv > 0.f ? outv : expm1f(outv);
        size_t off = (size_t)n * HC + hoff;
        if (flags & 1) y[off] = outv;
        if (flags & 2) {
            unsigned short hi = f2bf(outv);
            yh[off] = hi;
            yl[off] = f2bf(outv - bf2f(hi));
        }
    }
}

// ---------------- layer 3 ----------------

__global__ void gemm_small(const float* __restrict__ Y, const float* __restrict__ W3,
                           float* __restrict__ h3) {
    int idx = blockIdx.x * 256 + threadIdx.x;
    if (idx >= NNODES * 12) return;
    int n = idx / 12, o = idx - n * 12;
    const float4* xr = (const float4*)(Y + (size_t)n * HC);
    const float4* wr = (const float4*)(W3 + o * HC);
    float acc = 0.f;
#pragma unroll 8
    for (int k = 0; k < 64; k++) {
        float4 a = xr[k], b = wr[k];
        acc += a.x * b.x + a.y * b.y + a.z * b.z + a.w * b.w;
    }
    h3[idx] = acc;
}

__global__ void alpha3(const float* __restrict__ h3, const float* __restrict__ a_s,
                       const float* __restrict__ a_d, float* __restrict__ asrc,
                       float* __restrict__ adst) {
    int n = blockIdx.x * 256 + threadIdx.x;
    if (n >= NNODES) return;
    const float* hr = h3 + (size_t)n * 12;
    float s[4], d[4];
#pragma unroll
    for (int hh = 0; hh < 4; hh++) {
        s[hh] = hr[hh * 3] * a_s[hh * 3] + hr[hh * 3 + 1] * a_s[hh * 3 + 1] + hr[hh * 3 + 2] * a_s[hh * 3 + 2];
        d[hh] = hr[hh * 3] * a_d[hh * 3] + hr[hh * 3 + 1] * a_d[hh * 3 + 1] + hr[hh * 3 + 2] * a_d[hh * 3 + 2];
    }
    *(float4*)(asrc + n * 4) = make_float4(s[0], s[1], s[2], s[3]);
    *(float4*)(adst + n * 4) = make_float4(d[0], d[1], d[2], d[3]);
}

__global__ void aggregate3(const float* __restrict__ h3, const float* __restrict__ asrc,
                           const float* __restrict__ adst, const int* __restrict__ rp,
                           const int* __restrict__ csr, const float* __restrict__ b3,
                           float* __restrict__ out) {
    int n = blockIdx.x * 4 + (threadIdx.x >> 6);
    int l = threadIdx.x & 63;
    if (n >= NNODES) return;
    int r0 = rp[n], deg = rp[n + 1] - r0;
    float4 ad = *(const float4*)(adst + n * 4);

    float m0 = -1e30f, m1 = -1e30f, m2 = -1e30f, m3 = -1e30f;
    for (int j = l; j < deg; j += 64) {
        int s = csr[r0 + j];
        float4 a4 = *(const float4*)(asrc + s * 4);
        float e0 = a4.x + ad.x, e1 = a4.y + ad.y, e2 = a4.z + ad.z, e3 = a4.w + ad.w;
        e0 = e0 > 0.f ? e0 : 0.2f * e0;
        e1 = e1 > 0.f ? e1 : 0.2f * e1;
        e2 = e2 > 0.f ? e2 : 0.2f * e2;
        e3 = e3 > 0.f ? e3 : 0.2f * e3;
        m0 = fmaxf(m0, e0); m1 = fmaxf(m1, e1); m2 = fmaxf(m2, e2); m3 = fmaxf(m3, e3);
    }
    for (int o = 32; o > 0; o >>= 1) {
        m0 = fmaxf(m0, __shfl_xor(m0, o));
        m1 = fmaxf(m1, __shfl_xor(m1, o));
        m2 = fmaxf(m2, __shfl_xor(m2, o));
        m3 = fmaxf(m3, __shfl_xor(m3, o));
    }

    float acc[12];
#pragma unroll
    for (int k = 0; k < 12; k++) acc[k] = 0.f;
    float s0 = 0.f, s1 = 0.f, s2 = 0.f, s3 = 0.f;
    for (int j = l; j < deg; j += 64) {
        int s = csr[r0 + j];
        float4 a4 = *(const float4*)(asrc + s * 4);
        float e0 = a4.x + ad.x, e1 = a4.y + ad.y, e2 = a4.z + ad.z, e3 = a4.w + ad.w;
        e0 = e0 > 0.f ? e0 : 0.2f * e0;
        e1 = e1 > 0.f ? e1 : 0.2f * e1;
        e2 = e2 > 0.f ? e2 : 0.2f * e2;
        e3 = e3 > 0.f ? e3 : 0.2f * e3;
        float w0 = __expf(e0 - m0), w1 = __expf(e1 - m1), w2 = __expf(e2 - m2), w3 = __expf(e3 - m3);
        s0 += w0; s1 += w1; s2 += w2; s3 += w3;
        const float* hr = h3 + (size_t)s * 12;
#pragma unroll
        for (int c = 0; c < 3; c++) {
            acc[c]     += w0 * hr[c];
            acc[3 + c] += w1 * hr[3 + c];
            acc[6 + c] += w2 * hr[6 + c];
            acc[9 + c] += w3 * hr[9 + c];
        }
    }
    for (int o = 32; o > 0; o >>= 1) {
#pragma unroll
        for (int k = 0; k < 12; k++) acc[k] += __shfl_xor(acc[k], o);
        s0 += __shfl_xor(s0, o);
        s1 += __shfl_xor(s1, o);
        s2 += __shfl_xor(s2, o);
        s3 += __shfl_xor(s3, o);
    }
    if (l < 3) {
        float v = 0.25f * (acc[l] / s0 + acc[3 + l] / s1 + acc[6 + l] / s2 + acc[9 + l] / s3) + b3[l];
        v = v > 0.f ? v : expm1f(v);
        out[(size_t)n * 3 + l] = v;
    }
}

// ---------------- launch ----------------

extern "C" void kernel_launch(void* const* d_in, const int* in_sizes, int n_in,
                              void* d_out, int out_size, void* d_ws, size_t ws_size,
                              hipStream_t stream) {
    (void)in_sizes; (void)n_in; (void)out_size; (void)ws_size;
    const float* x   = (const float*)d_in[0];
    const int*   ei  = (const int*)d_in[1];
    const float* W1  = (const float*)d_in[2];
    const float* as1 = (const float*)d_in[3];
    const float* ad1 = (const float*)d_in[4];
    const float* b1  = (const float*)d_in[5];
    const float* W2  = (const float*)d_in[6];
    const float* as2 = (const float*)d_in[7];
    const float* ad2 = (const float*)d_in[8];
    const float* b2  = (const float*)d_in[9];
    const float* W3  = (const float*)d_in[10];
    const float* as3 = (const float*)d_in[11];
    const float* ad3 = (const float*)d_in[12];
    const float* b3  = (const float*)d_in[13];
    float* out = (float*)d_out;

    uint8_t* p = (uint8_t*)d_ws;
    auto alloc = [&](size_t bytes) -> void* {
        void* r = (void*)p;
        p += (bytes + 255) & ~(size_t)255;
        return r;
    };
    float* bufY = (float*)alloc((size_t)NNODES * HC * 4);
    float* h3   = (float*)alloc((size_t)NNODES * 12 * 4);
    float* asrc = (float*)alloc((size_t)NNODES * 4 * 4);
    float* adst = (float*)alloc((size_t)NNODES * 4 * 4);
    int* deg    = (int*)alloc((size_t)NNODES * 4);
    int* rp     = (int*)alloc((size_t)(NNODES + 1) * 4);
    int* cnt    = (int*)alloc((size_t)NNODES * 4);
    int* csr    = (int*)alloc((size_t)E2 * 4);
    int* bsums  = (int*)alloc(256 * 4);
    unsigned short* xh  = (unsigned short*)alloc((size_t)NNODES * HC * 2);
    unsigned short* xl  = (unsigned short*)alloc((size_t)NNODES * HC * 2);
    unsigned short* w1h = (unsigned short*)alloc((size_t)HC * HC * 2);
    unsigned short* w1l = (unsigned short*)alloc((size_t)HC * HC * 2);
    unsigned short* w2h = (unsigned short*)alloc((size_t)HC * HC * 2);
    unsigned short* w2l = (unsigned short*)alloc((size_t)HC * HC * 2);
    _Float16* h16 = (_Float16*)alloc((size_t)NNODES * HC * 2);

    const int NB_N = (NNODES + 255) / 256;
    const int NB_E = (E2 + 255) / 256;
    const int N4_A = NNODES * HC / 4;
    const int N4_W = HC * HC / 4;

    // CSR build
    zero_int<<<NB_N, 256, 0, stream>>>(deg, NNODES);
    count_deg<<<NB_E, 256, 0, stream>>>(ei, deg);
    scan1<<<NB_N, 256, 0, stream>>>(deg, rp, bsums);
    scan2<<<1, 256, 0, stream>>>(bsums, NB_N);
    scan3<<<NB_N, 256, 0, stream>>>(rp, bsums, cnt);
    fill_csr<<<NB_E, 256, 0, stream>>>(ei, cnt, csr);

    dim3 ggrid((NNODES + 127) / 128, 2);

    // Layer 1
    split_bf16<<<(N4_W + 255) / 256, 256, 0, stream>>>(W1, w1h, w1l, N4_W);
    split_bf16<<<(N4_A + 255) / 256, 256, 0, stream>>>(x, xh, xl, N4_A);
    gemm_mfma<<<ggrid, 256, 0, stream>>>(xh, xl, w1h, w1l, h16, NNODES);
    alpha_hc<<<NNODES, 256, 0, stream>>>(h16, as1, ad1, asrc, adst);
    aggregate_hc<<<NNODES, 256, 0, stream>>>(h16, asrc, adst, rp, csr, b1, bufY, xh, xl, 2);

    // Layer 2
    split_bf16<<<(N4_W + 255) / 256, 256, 0, stream>>>(W2, w2h, w2l, N4_W);
    gemm_mfma<<<ggrid, 256, 0, stream>>>(xh, xl, w2h, w2l, h16, NNODES);
    alpha_hc<<<NNODES, 256, 0, stream>>>(h16, as2, ad2, asrc, adst);
    aggregate_hc<<<NNODES, 256, 0, stream>>>(h16, asrc, adst, rp, csr, b2, bufY, xh, xl, 1);

    // Layer 3
    gemm_small<<<(NNODES * 12 + 255) / 256, 256, 0, stream>>>(bufY, W3, h3);
    alpha3<<<NB_N, 256, 0, stream>>>(h3, as3, ad3, asrc, adst);
    aggregate3<<<(NNODES + 3) / 4, 256, 0, stream>>>(h3, asrc, adst, rp, csr, b3, out);
}

// Round 8
// 640.196 us; speedup vs baseline: 6.9144x; 1.0378x over previous
//
#include <hip/hip_runtime.h>
#include <hip/hip_fp16.h>
#include <cstdint>
#include <cstddef>

#define NNODES 50000
#define NEDGES 800000
#define E2 (NEDGES + NNODES)
#define HC 256

typedef __attribute__((ext_vector_type(8))) short short8v;  // 8 bf16 = 4 VGPR (MFMA A/B frag)
typedef __attribute__((ext_vector_type(4))) float f32x4;    // MFMA C/D frag
typedef const __attribute__((address_space(1))) void* gas_t;
typedef __attribute__((address_space(3))) void* las_t;

// ---------------- CSR build ----------------

__global__ void zero_int(int* __restrict__ p, int n) {
    int i = blockIdx.x * 256 + threadIdx.x;
    if (i < n) p[i] = 0;
}

__global__ void count_deg(const int* __restrict__ ei, int* __restrict__ deg) {
    int i = blockIdx.x * 256 + threadIdx.x;
    if (i >= E2) return;
    int d = (i < NEDGES) ? ei[NEDGES + i] : (i - NEDGES);
    atomicAdd(&deg[d], 1);
}

__global__ void scan1(const int* __restrict__ deg, int* __restrict__ rp, int* __restrict__ bs) {
    __shared__ int s[256];
    int t = threadIdx.x, i = blockIdx.x * 256 + t;
    int v = (i < NNODES) ? deg[i] : 0;
    s[t] = v;
    __syncthreads();
    for (int o = 1; o < 256; o <<= 1) {
        int add = (t >= o) ? s[t - o] : 0;
        __syncthreads();
        s[t] += add;
        __syncthreads();
    }
    if (i < NNODES) rp[i] = s[t] - v;
    if (t == 255) bs[blockIdx.x] = s[255];
}

__global__ void scan2(int* __restrict__ bs, int nb) {
    __shared__ int s[256];
    int t = threadIdx.x;
    int v = (t < nb) ? bs[t] : 0;
    s[t] = v;
    __syncthreads();
    for (int o = 1; o < 256; o <<= 1) {
        int add = (t >= o) ? s[t - o] : 0;
        __syncthreads();
        s[t] += add;
        __syncthreads();
    }
    bs[t] = s[t] - v;
}

__global__ void scan3(int* __restrict__ rp, const int* __restrict__ bs, int* __restrict__ cnt) {
    int i = blockIdx.x * 256 + threadIdx.x;
    if (i < NNODES) {
        int v = rp[i] + bs[blockIdx.x];
        rp[i] = v;
        cnt[i] = v;
    }
    if (i == 0) rp[NNODES] = E2;
}

__global__ void fill_csr(const int* __restrict__ ei, int* __restrict__ cnt, int* __restrict__ csr) {
    int i = blockIdx.x * 256 + threadIdx.x;
    if (i >= E2) return;
    int s, d;
    if (i < NEDGES) { s = ei[i]; d = ei[NEDGES + i]; }
    else            { s = d = i - NEDGES; }
    int pos = atomicAdd(&cnt[d], 1);
    csr[pos] = s;
}

// ---------------- fp32 -> split bf16 (hi + residual-lo), RNE ----------------

__device__ __forceinline__ unsigned short f2bf(float f) {
    uint32_t u = __float_as_uint(f);
    uint32_t r = (u + 0x7FFFu + ((u >> 16) & 1u)) >> 16;
    return (unsigned short)r;
}
__device__ __forceinline__ float bf2f(unsigned short h) {
    return __uint_as_float(((uint32_t)h) << 16);
}

__global__ void split_bf16(const float* __restrict__ in, unsigned short* __restrict__ hi,
                           unsigned short* __restrict__ lo, int n4) {
    int i = blockIdx.x * 256 + threadIdx.x;
    if (i >= n4) return;
    float4 v = ((const float4*)in)[i];
    unsigned short h0 = f2bf(v.x), h1 = f2bf(v.y), h2 = f2bf(v.z), h3 = f2bf(v.w);
    unsigned short l0 = f2bf(v.x - bf2f(h0));
    unsigned short l1 = f2bf(v.y - bf2f(h1));
    unsigned short l2 = f2bf(v.z - bf2f(h2));
    unsigned short l3 = f2bf(v.w - bf2f(h3));
    uint2 hp, lp;
    hp.x = (uint32_t)h0 | ((uint32_t)h1 << 16);
    hp.y = (uint32_t)h2 | ((uint32_t)h3 << 16);
    lp.x = (uint32_t)l0 | ((uint32_t)l1 << 16);
    lp.y = (uint32_t)l2 | ((uint32_t)l3 << 16);
    *(uint2*)(hi + 4 * (size_t)i) = hp;
    *(uint2*)(lo + 4 * (size_t)i) = lp;
}

// ---------------- MFMA split-bf16 GEMM, double-buffered LDS (2-phase pipeline) ----
// out16[M,256] = A[M,256] @ W[256,256]^T. Per K-step: issue NEXT tile's
// global_load_lds BEFORE computing current tile; single __syncthreads at end
// drains vmcnt after 48 MFMAs have issued (T3-min pattern).

__global__ __launch_bounds__(256, 2) void gemm_mfma(
    const unsigned short* __restrict__ Ah, const unsigned short* __restrict__ Al,
    const unsigned short* __restrict__ Wh, const unsigned short* __restrict__ Wl,
    _Float16* __restrict__ out16, int M) {
    __shared__ unsigned short sAh[2][128][32], sAl[2][128][32], sWh[2][128][32], sWl[2][128][32];
    const int t = threadIdx.x;
    const int m0 = blockIdx.x * 128, n0 = blockIdx.y * 128;
    const int lane = t & 63, w = t >> 6;
    const int wr = w >> 1, wc = w & 1;
    const int fr = lane & 15, fg = lane >> 4;

    // staging geometry (identical to r6): unit u in [0,512), thread covers u0,u1
    const int u0 = (w * 2) * 64 + lane, u1 = (w * 2 + 1) * 64 + lane;
    const int row0 = u0 >> 2, cb0 = (u0 & 3) * 8;
    const int row1 = u1 >> 2, cb1 = (u1 & 3) * 8;
    int gra0 = m0 + row0; gra0 = gra0 < M ? gra0 : M - 1;
    int gra1 = m0 + row1; gra1 = gra1 < M ? gra1 : M - 1;
    const int grw0 = n0 + row0, grw1 = n0 + row1;

    auto stage = [&](int b, int kc) {
        __builtin_amdgcn_global_load_lds((gas_t)(Ah + (size_t)gra0 * HC + kc + cb0), (las_t)&sAh[b][row0][cb0], 16, 0, 0);
        __builtin_amdgcn_global_load_lds((gas_t)(Ah + (size_t)gra1 * HC + kc + cb1), (las_t)&sAh[b][row1][cb1], 16, 0, 0);
        __builtin_amdgcn_global_load_lds((gas_t)(Al + (size_t)gra0 * HC + kc + cb0), (las_t)&sAl[b][row0][cb0], 16, 0, 0);
        __builtin_amdgcn_global_load_lds((gas_t)(Al + (size_t)gra1 * HC + kc + cb1), (las_t)&sAl[b][row1][cb1], 16, 0, 0);
        __builtin_amdgcn_global_load_lds((gas_t)(Wh + (size_t)grw0 * HC + kc + cb0), (las_t)&sWh[b][row0][cb0], 16, 0, 0);
        __builtin_amdgcn_global_load_lds((gas_t)(Wh + (size_t)grw1 * HC + kc + cb1), (las_t)&sWh[b][row1][cb1], 16, 0, 0);
        __builtin_amdgcn_global_load_lds((gas_t)(Wl + (size_t)grw0 * HC + kc + cb0), (las_t)&sWl[b][row0][cb0], 16, 0, 0);
        __builtin_amdgcn_global_load_lds((gas_t)(Wl + (size_t)grw1 * HC + kc + cb1), (las_t)&sWl[b][row1][cb1], 16, 0, 0);
    };

    f32x4 acc[4][4];
#pragma unroll
    for (int mi = 0; mi < 4; mi++)
#pragma unroll
        for (int ni = 0; ni < 4; ni++) acc[mi][ni] = (f32x4){0.f, 0.f, 0.f, 0.f};

    auto compute = [&](int b) {
        short8v ah[4], al[4], bh[4], bl[4];
#pragma unroll
        for (int i = 0; i < 4; i++) {
            ah[i] = *(const short8v*)&sAh[b][wr * 64 + i * 16 + fr][fg * 8];
            al[i] = *(const short8v*)&sAl[b][wr * 64 + i * 16 + fr][fg * 8];
            bh[i] = *(const short8v*)&sWh[b][wc * 64 + i * 16 + fr][fg * 8];
            bl[i] = *(const short8v*)&sWl[b][wc * 64 + i * 16 + fr][fg * 8];
        }
#pragma unroll
        for (int mi = 0; mi < 4; mi++)
#pragma unroll
            for (int ni = 0; ni < 4; ni++) {
                acc[mi][ni] = __builtin_amdgcn_mfma_f32_16x16x32_bf16(ah[mi], bh[ni], acc[mi][ni], 0, 0, 0);
                acc[mi][ni] = __builtin_amdgcn_mfma_f32_16x16x32_bf16(ah[mi], bl[ni], acc[mi][ni], 0, 0, 0);
                acc[mi][ni] = __builtin_amdgcn_mfma_f32_16x16x32_bf16(al[mi], bh[ni], acc[mi][ni], 0, 0, 0);
            }
    };

    stage(0, 0);
    __syncthreads();                      // drains vmcnt: buf0 ready
#pragma unroll
    for (int kt = 0; kt < 7; kt++) {
        stage((kt + 1) & 1, (kt + 1) * 32);   // prefetch next tile
        compute(kt & 1);                      // MFMA on current (hides load latency)
        __syncthreads();                      // drains vmcnt+lgkm: next ready, cur consumed
    }
    compute(1);                               // kt=7, buffer 1

#pragma unroll
    for (int mi = 0; mi < 4; mi++) {
#pragma unroll
        for (int r = 0; r < 4; r++) {
            int gr = m0 + wr * 64 + mi * 16 + fg * 4 + r;
            if (gr < M) {
#pragma unroll
                for (int ni = 0; ni < 4; ni++) {
                    out16[(size_t)gr * HC + n0 + wc * 64 + ni * 16 + fr] = (_Float16)acc[mi][ni][r];
                }
            }
        }
    }
}

// ---------------- per-(node,head) attention logits (wave-per-row, 8B loads) -----

__global__ void alpha_hc(const _Float16* __restrict__ h16, const float* __restrict__ a_s,
                         const float* __restrict__ a_d, float* __restrict__ asrc,
                         float* __restrict__ adst) {
    int n = blockIdx.x * 4 + (threadIdx.x >> 6);
    int lane = threadIdx.x & 63;
    uint2 raw = *(const uint2*)(h16 + (size_t)n * HC + lane * 4);
    __half2 p0 = *(__half2*)&raw.x;
    __half2 p1 = *(__half2*)&raw.y;
    float h0 = __low2float(p0), h1 = __high2float(p0);
    float h2 = __low2float(p1), h3 = __high2float(p1);
    float4 s4 = *(const float4*)(a_s + lane * 4);
    float4 d4 = *(const float4*)(a_d + lane * 4);
    float ps = h0 * s4.x + h1 * s4.y + h2 * s4.z + h3 * s4.w;
    float pd = h0 * d4.x + h1 * d4.y + h2 * d4.z + h3 * d4.w;
    // reduce within 16-lane groups (one head per group: channels 64h..64h+63)
#pragma unroll
    for (int o = 1; o < 16; o <<= 1) {
        ps += __shfl_xor(ps, o);
        pd += __shfl_xor(pd, o);
    }
    if ((lane & 15) == 0) {
        int hh = lane >> 4;
        asrc[n * 4 + hh] = ps;
        adst[n * 4 + hh] = pd;
    }
}

// ---------------- fused segment softmax + aggregation (layers 1,2) ----------------

#define CHUNK 512

__global__ void aggregate_hc(const _Float16* __restrict__ h16, const float* __restrict__ asrc,
                             const float* __restrict__ adst, const int* __restrict__ rp,
                             const int* __restrict__ csr, const float* __restrict__ bias,
                             float* __restrict__ y, unsigned short* __restrict__ yh,
                             unsigned short* __restrict__ yl, int flags) {
    __shared__ int   sIdx[CHUNK];
    __shared__ float sE4[CHUNK][4];
    __shared__ float sM[4][4], sS[4][4];
    __shared__ float sRed[4][32][9];
    int n = blockIdx.x;
    int t = threadIdx.x;
    int r0 = rp[n], deg = rp[n + 1] - r0;

    if (deg <= CHUNK) {
        for (int j = t; j < deg; j += 256) sIdx[j] = csr[r0 + j];
        __syncthreads();

        int hA = t & 3, jj = t >> 2;
        float adh = adst[n * 4 + hA];
        float pm = -1e30f;
        for (int j = jj; j < deg; j += 64) {
            int s = sIdx[j];
            float e = asrc[s * 4 + hA] + adh;
            e = e > 0.f ? e : 0.2f * e;
            sE4[j][hA] = e;
            pm = fmaxf(pm, e);
        }
#pragma unroll
        for (int o = 4; o <= 32; o <<= 1) pm = fmaxf(pm, __shfl_xor(pm, o));
        if ((t & 63) < 4) sM[t >> 6][t & 3] = pm;
        __syncthreads();

        float mh = fmaxf(fmaxf(sM[0][hA], sM[1][hA]), fmaxf(sM[2][hA], sM[3][hA]));
        float ps = 0.f;
        for (int j = jj; j < deg; j += 64) {
            float ex = __expf(sE4[j][hA] - mh);
            sE4[j][hA] = ex;
            ps += ex;
        }
#pragma unroll
        for (int o = 4; o <= 32; o <<= 1) ps += __shfl_xor(ps, o);
        if ((t & 63) < 4) sS[t >> 6][t & 3] = ps;
        __syncthreads();

        int G = t >> 5, q = t & 31, hh = q >> 3;
        float a[8];
#pragma unroll
        for (int i = 0; i < 8; i++) a[i] = 0.f;
#pragma unroll 2
        for (int j = G; j < deg; j += 8) {
            int s = sIdx[j];
            float aw = sE4[j][hh];
            uint4 raw = *(const uint4*)(h16 + (size_t)s * HC + 8 * q);
            const _Float16* hv = reinterpret_cast<const _Float16*>(&raw);
#pragma unroll
            for (int i = 0; i < 8; i++) a[i] = fmaf((float)hv[i], aw, a[i]);
        }
#pragma unroll
        for (int i = 0; i < 8; i++) a[i] += __shfl_xor(a[i], 32);
        int wv = t >> 6, l = t & 63;
        if (l < 32) {
#pragma unroll
            for (int i = 0; i < 8; i++) sRed[wv][l][i] = a[i];
        }
        __syncthreads();

        int c = t;
        float val = sRed[0][c >> 3][c & 7] + sRed[1][c >> 3][c & 7]
                  + sRed[2][c >> 3][c & 7] + sRed[3][c >> 3][c & 7];
        int ch = c >> 6;
        float ssum = sS[0][ch] + sS[1][ch] + sS[2][ch] + sS[3][ch];
        float outv = val / ssum + bias[c];
        outv = outv > 0.f ? outv : expm1f(outv);
        size_t off = (size_t)n * HC + c;
        if (flags & 1) y[off] = outv;
        if (flags & 2) {
            unsigned short hi = f2bf(outv);
            yh[off] = hi;
            yl[off] = f2bf(outv - bf2f(hi));
        }
    } else {
        int w = t >> 6, l = t & 63;
        float ad = adst[n * 4 + w];
        int hoff = (w << 6) + l;
        const _Float16* hp = h16 + hoff;
        float m = -1e30f;
        for (int j = l; j < deg; j += 64) {
            int s = csr[r0 + j];
            float e = asrc[s * 4 + w] + ad;
            e = e > 0.f ? e : 0.2f * e;
            m = fmaxf(m, e);
        }
#pragma unroll
        for (int o = 32; o > 0; o >>= 1) m = fmaxf(m, __shfl_xor(m, o));
        float acc = 0.f, ssum = 0.f;
        for (int j = 0; j < deg; j++) {
            int s = csr[r0 + j];
            float e = asrc[s * 4 + w] + ad;
            e = e > 0.f ? e : 0.2f * e;
            float aa = __expf(e - m);
            ssum += aa;
            acc = fmaf(aa, (float)hp[(size_t)s * HC], acc);
        }
        float outv = acc / ssum + bias[hoff];
        outv = outv > 0.f ? outv : expm1f(outv);
        size_t off = (size_t)n * HC + hoff;
        if (flags & 1) y[off] = outv;
        if (flags & 2) {
            unsigned short hi = f2bf(outv);
            yh[off] = hi;
            yl[off] = f2bf(outv - bf2f(hi));
        }
    }
}

// ---------------- layer 3 ----------------

__global__ void gemm_small(const float* __restrict__ Y, const float* __restrict__ W3,
                           float* __restrict__ h3) {
    int idx = blockIdx.x * 256 + threadIdx.x;
    if (idx >= NNODES * 12) return;
    int n = idx / 12, o = idx - n * 12;
    const float4* xr = (const float4*)(Y + (size_t)n * HC);
    const float4* wr = (const float4*)(W3 + o * HC);
    float acc = 0.f;
#pragma unroll 8
    for (int k = 0; k < 64; k++) {
        float4 a = xr[k], b = wr[k];
        acc += a.x * b.x + a.y * b.y + a.z * b.z + a.w * b.w;
    }
    h3[idx] = acc;
}

__global__ void alpha3(const float* __restrict__ h3, const float* __restrict__ a_s,
                       const float* __restrict__ a_d, float* __restrict__ asrc,
                       float* __restrict__ adst) {
    int n = blockIdx.x * 256 + threadIdx.x;
    if (n >= NNODES) return;
    const float* hr = h3 + (size_t)n * 12;
    float s[4], d[4];
#pragma unroll
    for (int hh = 0; hh < 4; hh++) {
        s[hh] = hr[hh * 3] * a_s[hh * 3] + hr[hh * 3 + 1] * a_s[hh * 3 + 1] + hr[hh * 3 + 2] * a_s[hh * 3 + 2];
        d[hh] = hr[hh * 3] * a_d[hh * 3] + hr[hh * 3 + 1] * a_d[hh * 3 + 1] + hr[hh * 3 + 2] * a_d[hh * 3 + 2];
    }
    *(float4*)(asrc + n * 4) = make_float4(s[0], s[1], s[2], s[3]);
    *(float4*)(adst + n * 4) = make_float4(d[0], d[1], d[2], d[3]);
}

__global__ void aggregate3(const float* __restrict__ h3, const float* __restrict__ asrc,
                           const float* __restrict__ adst, const int* __restrict__ rp,
                           const int* __restrict__ csr, const float* __restrict__ b3,
                           float* __restrict__ out) {
    int n = blockIdx.x * 4 + (threadIdx.x >> 6);
    int l = threadIdx.x & 63;
    if (n >= NNODES) return;
    int r0 = rp[n], deg = rp[n + 1] - r0;
    float4 ad = *(const float4*)(adst + n * 4);

    float m0 = -1e30f, m1 = -1e30f, m2 = -1e30f, m3 = -1e30f;
    for (int j = l; j < deg; j += 64) {
        int s = csr[r0 + j];
        float4 a4 = *(const float4*)(asrc + s * 4);
        float e0 = a4.x + ad.x, e1 = a4.y + ad.y, e2 = a4.z + ad.z, e3 = a4.w + ad.w;
        e0 = e0 > 0.f ? e0 : 0.2f * e0;
        e1 = e1 > 0.f ? e1 : 0.2f * e1;
        e2 = e2 > 0.f ? e2 : 0.2f * e2;
        e3 = e3 > 0.f ? e3 : 0.2f * e3;
        m0 = fmaxf(m0, e0); m1 = fmaxf(m1, e1); m2 = fmaxf(m2, e2); m3 = fmaxf(m3, e3);
    }
    for (int o = 32; o > 0; o >>= 1) {
        m0 = fmaxf(m0, __shfl_xor(m0, o));
        m1 = fmaxf(m1, __shfl_xor(m1, o));
        m2 = fmaxf(m2, __shfl_xor(m2, o));
        m3 = fmaxf(m3, __shfl_xor(m3, o));
    }

    float acc[12];
#pragma unroll
    for (int k = 0; k < 12; k++) acc[k] = 0.f;
    float s0 = 0.f, s1 = 0.f, s2 = 0.f, s3 = 0.f;
    for (int j = l; j < deg; j += 64) {
        int s = csr[r0 + j];
        float4 a4 = *(const float4*)(asrc + s * 4);
        float e0 = a4.x + ad.x, e1 = a4.y + ad.y, e2 = a4.z + ad.z, e3 = a4.w + ad.w;
        e0 = e0 > 0.f ? e0 : 0.2f * e0;
        e1 = e1 > 0.f ? e1 : 0.2f * e1;
        e2 = e2 > 0.f ? e2 : 0.2f * e2;
        e3 = e3 > 0.f ? e3 : 0.2f * e3;
        float w0 = __expf(e0 - m0), w1 = __expf(e1 - m1), w2 = __expf(e2 - m2), w3 = __expf(e3 - m3);
        s0 += w0; s1 += w1; s2 += w2; s3 += w3;
        const float* hr = h3 + (size_t)s * 12;
#pragma unroll
        for (int c = 0; c < 3; c++) {
            acc[c]     += w0 * hr[c];
            acc[3 + c] += w1 * hr[3 + c];
            acc[6 + c] += w2 * hr[6 + c];
            acc[9 + c] += w3 * hr[9 + c];
        }
    }
    for (int o = 32; o > 0; o >>= 1) {
#pragma unroll
        for (int k = 0; k < 12; k++) acc[k] += __shfl_xor(acc[k], o);
        s0 += __shfl_xor(s0, o);
        s1 += __shfl_xor(s1, o);
        s2 += __shfl_xor(s2, o);
        s3 += __shfl_xor(s3, o);
    }
    if (l < 3) {
        float v = 0.25f * (acc[l] / s0 + acc[3 + l] / s1 + acc[6 + l] / s2 + acc[9 + l] / s3) + b3[l];
        v = v > 0.f ? v : expm1f(v);
        out[(size_t)n * 3 + l] = v;
    }
}

// ---------------- launch ----------------

extern "C" void kernel_launch(void* const* d_in, const int* in_sizes, int n_in,
                              void* d_out, int out_size, void* d_ws, size_t ws_size,
                              hipStream_t stream) {
    (void)in_sizes; (void)n_in; (void)out_size; (void)ws_size;
    const float* x   = (const float*)d_in[0];
    const int*   ei  = (const int*)d_in[1];
    const float* W1  = (const float*)d_in[2];
    const float* as1 = (const float*)d_in[3];
    const float* ad1 = (const float*)d_in[4];
    const float* b1  = (const float*)d_in[5];
    const float* W2  = (const float*)d_in[6];
    const float* as2 = (const float*)d_in[7];
    const float* ad2 = (const float*)d_in[8];
    const float* b2  = (const float*)d_in[9];
    const float* W3  = (const float*)d_in[10];
    const float* as3 = (const float*)d_in[11];
    const float* ad3 = (const float*)d_in[12];
    const float* b3  = (const float*)d_in[13];
    float* out = (float*)d_out;

    uint8_t* p = (uint8_t*)d_ws;
    auto alloc = [&](size_t bytes) -> void* {
        void* r = (void*)p;
        p += (bytes + 255) & ~(size_t)255;
        return r;
    };
    float* bufY = (float*)alloc((size_t)NNODES * HC * 4);
    float* h3   = (float*)alloc((size_t)NNODES * 12 * 4);
    float* asrc = (float*)alloc((size_t)NNODES * 4 * 4);
    float* adst = (float*)alloc((size_t)NNODES * 4 * 4);
    int* deg    = (int*)alloc((size_t)NNODES * 4);
    int* rp     = (int*)alloc((size_t)(NNODES + 1) * 4);
    int* cnt    = (int*)alloc((size_t)NNODES * 4);
    int* csr    = (int*)alloc((size_t)E2 * 4);
    int* bsums  = (int*)alloc(256 * 4);
    unsigned short* xh  = (unsigned short*)alloc((size_t)NNODES * HC * 2);
    unsigned short* xl  = (unsigned short*)alloc((size_t)NNODES * HC * 2);
    unsigned short* w1h = (unsigned short*)alloc((size_t)HC * HC * 2);
    unsigned short* w1l = (unsigned short*)alloc((size_t)HC * HC * 2);
    unsigned short* w2h = (unsigned short*)alloc((size_t)HC * HC * 2);
    unsigned short* w2l = (unsigned short*)alloc((size_t)HC * HC * 2);
    _Float16* h16 = (_Float16*)alloc((size_t)NNODES * HC * 2);

    const int NB_N = (NNODES + 255) / 256;
    const int NB_E = (E2 + 255) / 256;
    const int N4_A = NNODES * HC / 4;
    const int N4_W = HC * HC / 4;

    // CSR build
    zero_int<<<NB_N, 256, 0, stream>>>(deg, NNODES);
    count_deg<<<NB_E, 256, 0, stream>>>(ei, deg);
    scan1<<<NB_N, 256, 0, stream>>>(deg, rp, bsums);
    scan2<<<1, 256, 0, stream>>>(bsums, NB_N);
    scan3<<<NB_N, 256, 0, stream>>>(rp, bsums, cnt);
    fill_csr<<<NB_E, 256, 0, stream>>>(ei, cnt, csr);

    dim3 ggrid((NNODES + 127) / 128, 2);

    // Layer 1
    split_bf16<<<(N4_W + 255) / 256, 256, 0, stream>>>(W1, w1h, w1l, N4_W);
    split_bf16<<<(N4_A + 255) / 256, 256, 0, stream>>>(x, xh, xl, N4_A);
    gemm_mfma<<<ggrid, 256, 0, stream>>>(xh, xl, w1h, w1l, h16, NNODES);
    alpha_hc<<<NNODES / 4, 256, 0, stream>>>(h16, as1, ad1, asrc, adst);
    aggregate_hc<<<NNODES, 256, 0, stream>>>(h16, asrc, adst, rp, csr, b1, bufY, xh, xl, 2);

    // Layer 2
    split_bf16<<<(N4_W + 255) / 256, 256, 0, stream>>>(W2, w2h, w2l, N4_W);
    gemm_mfma<<<ggrid, 256, 0, stream>>>(xh, xl, w2h, w2l, h16, NNODES);
    alpha_hc<<<NNODES / 4, 256, 0, stream>>>(h16, as2, ad2, asrc, adst);
    aggregate_hc<<<NNODES, 256, 0, stream>>>(h16, asrc, adst, rp, csr, b2, bufY, xh, xl, 1);

    // Layer 3
    gemm_small<<<(NNODES * 12 + 255) / 256, 256, 0, stream>>>(bufY, W3, h3);
    alpha3<<<NB_N, 256, 0, stream>>>(h3, as3, ad3, asrc, adst);
    aggregate3<<<(NNODES + 3) / 4, 256, 0, stream>>>(h3, asrc, adst, rp, csr, b3, out);
}

// Round 9
// 639.993 us; speedup vs baseline: 6.9166x; 1.0003x over previous
//
#include <hip/hip_runtime.h>
#include <hip/hip_fp16.h>
#include <cstdint>
#include <cstddef>

#define NNODES 50000
#define NEDGES 800000
#define E2 (NEDGES + NNODES)
#define HC 256

typedef __attribute__((ext_vector_type(8))) short short8v;  // 8 bf16 = 4 VGPR (MFMA A/B frag)
typedef __attribute__((ext_vector_type(4))) float f32x4;    // MFMA C/D frag
typedef const __attribute__((address_space(1))) void* gas_t;
typedef __attribute__((address_space(3))) void* las_t;

// ---------------- CSR build ----------------

__global__ void zero_int(int* __restrict__ p, int n) {
    int i = blockIdx.x * 256 + threadIdx.x;
    if (i < n) p[i] = 0;
}

__global__ void count_deg(const int* __restrict__ ei, int* __restrict__ deg) {
    int i = blockIdx.x * 256 + threadIdx.x;
    if (i >= E2) return;
    int d = (i < NEDGES) ? ei[NEDGES + i] : (i - NEDGES);
    atomicAdd(&deg[d], 1);
}

__global__ void scan1(const int* __restrict__ deg, int* __restrict__ rp, int* __restrict__ bs) {
    __shared__ int s[256];
    int t = threadIdx.x, i = blockIdx.x * 256 + t;
    int v = (i < NNODES) ? deg[i] : 0;
    s[t] = v;
    __syncthreads();
    for (int o = 1; o < 256; o <<= 1) {
        int add = (t >= o) ? s[t - o] : 0;
        __syncthreads();
        s[t] += add;
        __syncthreads();
    }
    if (i < NNODES) rp[i] = s[t] - v;
    if (t == 255) bs[blockIdx.x] = s[255];
}

__global__ void scan2(int* __restrict__ bs, int nb) {
    __shared__ int s[256];
    int t = threadIdx.x;
    int v = (t < nb) ? bs[t] : 0;
    s[t] = v;
    __syncthreads();
    for (int o = 1; o < 256; o <<= 1) {
        int add = (t >= o) ? s[t - o] : 0;
        __syncthreads();
        s[t] += add;
        __syncthreads();
    }
    bs[t] = s[t] - v;
}

__global__ void scan3(int* __restrict__ rp, const int* __restrict__ bs, int* __restrict__ cnt) {
    int i = blockIdx.x * 256 + threadIdx.x;
    if (i < NNODES) {
        int v = rp[i] + bs[blockIdx.x];
        rp[i] = v;
        cnt[i] = v;
    }
    if (i == 0) rp[NNODES] = E2;
}

__global__ void fill_csr(const int* __restrict__ ei, int* __restrict__ cnt, int* __restrict__ csr) {
    int i = blockIdx.x * 256 + threadIdx.x;
    if (i >= E2) return;
    int s, d;
    if (i < NEDGES) { s = ei[i]; d = ei[NEDGES + i]; }
    else            { s = d = i - NEDGES; }
    int pos = atomicAdd(&cnt[d], 1);
    csr[pos] = s;
}

// ---------------- fp32 -> split bf16 (hi + residual-lo), RNE ----------------

__device__ __forceinline__ unsigned short f2bf(float f) {
    uint32_t u = __float_as_uint(f);
    uint32_t r = (u + 0x7FFFu + ((u >> 16) & 1u)) >> 16;
    return (unsigned short)r;
}
__device__ __forceinline__ float bf2f(unsigned short h) {
    return __uint_as_float(((uint32_t)h) << 16);
}

__global__ void split_bf16(const float* __restrict__ in, unsigned short* __restrict__ hi,
                           unsigned short* __restrict__ lo, int n4) {
    int i = blockIdx.x * 256 + threadIdx.x;
    if (i >= n4) return;
    float4 v = ((const float4*)in)[i];
    unsigned short h0 = f2bf(v.x), h1 = f2bf(v.y), h2 = f2bf(v.z), h3 = f2bf(v.w);
    unsigned short l0 = f2bf(v.x - bf2f(h0));
    unsigned short l1 = f2bf(v.y - bf2f(h1));
    unsigned short l2 = f2bf(v.z - bf2f(h2));
    unsigned short l3 = f2bf(v.w - bf2f(h3));
    uint2 hp, lp;
    hp.x = (uint32_t)h0 | ((uint32_t)h1 << 16);
    hp.y = (uint32_t)h2 | ((uint32_t)h3 << 16);
    lp.x = (uint32_t)l0 | ((uint32_t)l1 << 16);
    lp.y = (uint32_t)l2 | ((uint32_t)l3 << 16);
    *(uint2*)(hi + 4 * (size_t)i) = hp;
    *(uint2*)(lo + 4 * (size_t)i) = lp;
}

// ---------------- MFMA split-bf16 GEMM, double-buffered LDS (2-phase pipeline) ----

__global__ __launch_bounds__(256, 2) void gemm_mfma(
    const unsigned short* __restrict__ Ah, const unsigned short* __restrict__ Al,
    const unsigned short* __restrict__ Wh, const unsigned short* __restrict__ Wl,
    _Float16* __restrict__ out16, int M) {
    __shared__ unsigned short sAh[2][128][32], sAl[2][128][32], sWh[2][128][32], sWl[2][128][32];
    const int t = threadIdx.x;
    const int m0 = blockIdx.x * 128, n0 = blockIdx.y * 128;
    const int lane = t & 63, w = t >> 6;
    const int wr = w >> 1, wc = w & 1;
    const int fr = lane & 15, fg = lane >> 4;

    const int u0 = (w * 2) * 64 + lane, u1 = (w * 2 + 1) * 64 + lane;
    const int row0 = u0 >> 2, cb0 = (u0 & 3) * 8;
    const int row1 = u1 >> 2, cb1 = (u1 & 3) * 8;
    int gra0 = m0 + row0; gra0 = gra0 < M ? gra0 : M - 1;
    int gra1 = m0 + row1; gra1 = gra1 < M ? gra1 : M - 1;
    const int grw0 = n0 + row0, grw1 = n0 + row1;

    auto stage = [&](int b, int kc) {
        __builtin_amdgcn_global_load_lds((gas_t)(Ah + (size_t)gra0 * HC + kc + cb0), (las_t)&sAh[b][row0][cb0], 16, 0, 0);
        __builtin_amdgcn_global_load_lds((gas_t)(Ah + (size_t)gra1 * HC + kc + cb1), (las_t)&sAh[b][row1][cb1], 16, 0, 0);
        __builtin_amdgcn_global_load_lds((gas_t)(Al + (size_t)gra0 * HC + kc + cb0), (las_t)&sAl[b][row0][cb0], 16, 0, 0);
        __builtin_amdgcn_global_load_lds((gas_t)(Al + (size_t)gra1 * HC + kc + cb1), (las_t)&sAl[b][row1][cb1], 16, 0, 0);
        __builtin_amdgcn_global_load_lds((gas_t)(Wh + (size_t)grw0 * HC + kc + cb0), (las_t)&sWh[b][row0][cb0], 16, 0, 0);
        __builtin_amdgcn_global_load_lds((gas_t)(Wh + (size_t)grw1 * HC + kc + cb1), (las_t)&sWh[b][row1][cb1], 16, 0, 0);
        __builtin_amdgcn_global_load_lds((gas_t)(Wl + (size_t)grw0 * HC + kc + cb0), (las_t)&sWl[b][row0][cb0], 16, 0, 0);
        __builtin_amdgcn_global_load_lds((gas_t)(Wl + (size_t)grw1 * HC + kc + cb1), (las_t)&sWl[b][row1][cb1], 16, 0, 0);
    };

    f32x4 acc[4][4];
#pragma unroll
    for (int mi = 0; mi < 4; mi++)
#pragma unroll
        for (int ni = 0; ni < 4; ni++) acc[mi][ni] = (f32x4){0.f, 0.f, 0.f, 0.f};

    auto compute = [&](int b) {
        short8v ah[4], al[4], bh[4], bl[4];
#pragma unroll
        for (int i = 0; i < 4; i++) {
            ah[i] = *(const short8v*)&sAh[b][wr * 64 + i * 16 + fr][fg * 8];
            al[i] = *(const short8v*)&sAl[b][wr * 64 + i * 16 + fr][fg * 8];
            bh[i] = *(const short8v*)&sWh[b][wc * 64 + i * 16 + fr][fg * 8];
            bl[i] = *(const short8v*)&sWl[b][wc * 64 + i * 16 + fr][fg * 8];
        }
#pragma unroll
        for (int mi = 0; mi < 4; mi++)
#pragma unroll
            for (int ni = 0; ni < 4; ni++) {
                acc[mi][ni] = __builtin_amdgcn_mfma_f32_16x16x32_bf16(ah[mi], bh[ni], acc[mi][ni], 0, 0, 0);
                acc[mi][ni] = __builtin_amdgcn_mfma_f32_16x16x32_bf16(ah[mi], bl[ni], acc[mi][ni], 0, 0, 0);
                acc[mi][ni] = __builtin_amdgcn_mfma_f32_16x16x32_bf16(al[mi], bh[ni], acc[mi][ni], 0, 0, 0);
            }
    };

    stage(0, 0);
    __syncthreads();
#pragma unroll
    for (int kt = 0; kt < 7; kt++) {
        stage((kt + 1) & 1, (kt + 1) * 32);
        compute(kt & 1);
        __syncthreads();
    }
    compute(1);

#pragma unroll
    for (int mi = 0; mi < 4; mi++) {
#pragma unroll
        for (int r = 0; r < 4; r++) {
            int gr = m0 + wr * 64 + mi * 16 + fg * 4 + r;
            if (gr < M) {
#pragma unroll
                for (int ni = 0; ni < 4; ni++) {
                    out16[(size_t)gr * HC + n0 + wc * 64 + ni * 16 + fr] = (_Float16)acc[mi][ni][r];
                }
            }
        }
    }
}

// ---------------- per-(node,head) attention logits (wave-per-row, 8B loads) -----

__global__ void alpha_hc(const _Float16* __restrict__ h16, const float* __restrict__ a_s,
                         const float* __restrict__ a_d, float* __restrict__ asrc,
                         float* __restrict__ adst) {
    int n = blockIdx.x * 4 + (threadIdx.x >> 6);
    int lane = threadIdx.x & 63;
    uint2 raw = *(const uint2*)(h16 + (size_t)n * HC + lane * 4);
    __half2 p0 = *(__half2*)&raw.x;
    __half2 p1 = *(__half2*)&raw.y;
    float h0 = __low2float(p0), h1 = __high2float(p0);
    float h2 = __low2float(p1), h3 = __high2float(p1);
    float4 s4 = *(const float4*)(a_s + lane * 4);
    float4 d4 = *(const float4*)(a_d + lane * 4);
    float ps = h0 * s4.x + h1 * s4.y + h2 * s4.z + h3 * s4.w;
    float pd = h0 * d4.x + h1 * d4.y + h2 * d4.z + h3 * d4.w;
#pragma unroll
    for (int o = 1; o < 16; o <<= 1) {
        ps += __shfl_xor(ps, o);
        pd += __shfl_xor(pd, o);
    }
    if ((lane & 15) == 0) {
        int hh = lane >> 4;
        asrc[n * 4 + hh] = ps;
        adst[n * 4 + hh] = pd;
    }
}

// ---------------- fused segment softmax + aggregation (layers 1,2) ----------------
// 8 nodes per block (CSR ranges contiguous -> coalesced staging). 3 syncs total.
// Phase A/B: thread = (node t>>5, head (t&31)>>3, slot t&7); per-(node,head)
// shfl_xor reduce inside 8-lane subgroup. Gather: group i (32 lanes) == node i,
// lane q owns channels 8q..8q+7 via uint4 fp16 loads; no cross-group combine.

#define CHUNK 384
#define NPB 8

__global__ void aggregate_hc(const _Float16* __restrict__ h16, const float* __restrict__ asrc,
                             const float* __restrict__ adst, const int* __restrict__ rp,
                             const int* __restrict__ csr, const float* __restrict__ bias,
                             float* __restrict__ y, unsigned short* __restrict__ yh,
                             unsigned short* __restrict__ yl, int flags) {
    __shared__ int   sIdx[CHUNK];
    __shared__ int   sOff[NPB + 1];
    __shared__ float sE4[CHUNK][4];
    __shared__ float sM[NPB][4], sS[NPB][4];
    __shared__ float sAd[NPB][4];
    int n0 = blockIdx.x * NPB;
    int t = threadIdx.x;
    int r0 = rp[n0];
    int tot = rp[n0 + NPB] - r0;

    if (tot <= CHUNK) {
        if (t <= NPB) sOff[t] = rp[n0 + t] - r0;
        if (t >= 32 && t < 32 + NPB * 4) {
            int i = (t - 32) >> 2, hh = t & 3;
            sAd[i][hh] = adst[(n0 + i) * 4 + hh];
        }
        for (int j = t; j < tot; j += 256) sIdx[j] = csr[r0 + j];
        __syncthreads();

        int i = t >> 5, q = t & 31, hh = q >> 3, slot = q & 7;
        int js = sOff[i], je = sOff[i + 1];

        // phase A: logits + per-(node,head) max
        float adh = sAd[i][hh];
        float pm = -1e30f;
        for (int j = js + slot; j < je; j += 8) {
            int s = sIdx[j];
            float e = asrc[s * 4 + hh] + adh;
            e = e > 0.f ? e : 0.2f * e;
            sE4[j][hh] = e;
            pm = fmaxf(pm, e);
        }
#pragma unroll
        for (int o = 1; o < 8; o <<= 1) pm = fmaxf(pm, __shfl_xor(pm, o));
        if (slot == 0) sM[i][hh] = pm;
        __syncthreads();

        // phase B: exp + per-(node,head) sum
        float mh = sM[i][hh];
        float ps = 0.f;
        for (int j = js + slot; j < je; j += 8) {
            float ex = __expf(sE4[j][hh] - mh);
            sE4[j][hh] = ex;
            ps += ex;
        }
#pragma unroll
        for (int o = 1; o < 8; o <<= 1) ps += __shfl_xor(ps, o);
        if (slot == 0) sS[i][hh] = ps;
        __syncthreads();

        // gather: group i == node i; lane q -> channels 8q..8q+7
        float a[8];
#pragma unroll
        for (int k = 0; k < 8; k++) a[k] = 0.f;
        for (int j = js; j < je; j++) {
            int s = sIdx[j];
            float aw = sE4[j][hh];
            uint4 raw = *(const uint4*)(h16 + (size_t)s * HC + 8 * q);
            const _Float16* hv = reinterpret_cast<const _Float16*>(&raw);
#pragma unroll
            for (int k = 0; k < 8; k++) a[k] = fmaf((float)hv[k], aw, a[k]);
        }
        float inv = 1.f / sS[i][hh];
        size_t base = (size_t)(n0 + i) * HC + 8 * q;
#pragma unroll
        for (int k = 0; k < 8; k++) {
            float outv = a[k] * inv + bias[8 * q + k];
            outv = outv > 0.f ? outv : expm1f(outv);
            if (flags & 1) y[base + k] = outv;
            if (flags & 2) {
                unsigned short hi = f2bf(outv);
                yh[base + k] = hi;
                yl[base + k] = f2bf(outv - bf2f(hi));
            }
        }
    } else {
        // fallback: per-node, wave w == head w (unreachable for this graph size)
        for (int i = 0; i < NPB; i++) {
            int n = n0 + i;
            int rr0 = rp[n], deg = rp[n + 1] - rr0;
            int w = t >> 6, l = t & 63;
            float ad = adst[n * 4 + w];
            int hoff = (w << 6) + l;
            const _Float16* hp = h16 + hoff;
            float m = -1e30f;
            for (int j = l; j < deg; j += 64) {
                int s = csr[rr0 + j];
                float e = asrc[s * 4 + w] + ad;
                e = e > 0.f ? e : 0.2f * e;
                m = fmaxf(m, e);
            }
#pragma unroll
            for (int o = 32; o > 0; o >>= 1) m = fmaxf(m, __shfl_xor(m, o));
            float acc = 0.f, ssum = 0.f;
            for (int j = 0; j < deg; j++) {
                int s = csr[rr0 + j];
                float e = asrc[s * 4 + w] + ad;
                e = e > 0.f ? e : 0.2f * e;
                float aa = __expf(e - m);
                ssum += aa;
                acc = fmaf(aa, (float)hp[(size_t)s * HC], acc);
            }
            float outv = acc / ssum + bias[hoff];
            outv = outv > 0.f ? outv : expm1f(outv);
            size_t off = (size_t)n * HC + hoff;
            if (flags & 1) y[off] = outv;
            if (flags & 2) {
                unsigned short hi = f2bf(outv);
                yh[off] = hi;
                yl[off] = f2bf(outv - bf2f(hi));
            }
        }
    }
}

// ---------------- layer 3 ----------------

__global__ void gemm_small(const float* __restrict__ Y, const float* __restrict__ W3,
                           float* __restrict__ h3) {
    int idx = blockIdx.x * 256 + threadIdx.x;
    if (idx >= NNODES * 12) return;
    int n = idx / 12, o = idx - n * 12;
    const float4* xr = (const float4*)(Y + (size_t)n * HC);
    const float4* wr = (const float4*)(W3 + o * HC);
    float acc = 0.f;
#pragma unroll 8
    for (int k = 0; k < 64; k++) {
        float4 a = xr[k], b = wr[k];
        acc += a.x * b.x + a.y * b.y + a.z * b.z + a.w * b.w;
    }
    h3[idx] = acc;
}

__global__ void alpha3(const float* __restrict__ h3, const float* __restrict__ a_s,
                       const float* __restrict__ a_d, float* __restrict__ asrc,
                       float* __restrict__ adst) {
    int n = blockIdx.x * 256 + threadIdx.x;
    if (n >= NNODES) return;
    const float* hr = h3 + (size_t)n * 12;
    float s[4], d[4];
#pragma unroll
    for (int hh = 0; hh < 4; hh++) {
        s[hh] = hr[hh * 3] * a_s[hh * 3] + hr[hh * 3 + 1] * a_s[hh * 3 + 1] + hr[hh * 3 + 2] * a_s[hh * 3 + 2];
        d[hh] = hr[hh * 3] * a_d[hh * 3] + hr[hh * 3 + 1] * a_d[hh * 3 + 1] + hr[hh * 3 + 2] * a_d[hh * 3 + 2];
    }
    *(float4*)(asrc + n * 4) = make_float4(s[0], s[1], s[2], s[3]);
    *(float4*)(adst + n * 4) = make_float4(d[0], d[1], d[2], d[3]);
}

__global__ void aggregate3(const float* __restrict__ h3, const float* __restrict__ asrc,
                           const float* __restrict__ adst, const int* __restrict__ rp,
                           const int* __restrict__ csr, const float* __restrict__ b3,
                           float* __restrict__ out) {
    int n = blockIdx.x * 4 + (threadIdx.x >> 6);
    int l = threadIdx.x & 63;
    if (n >= NNODES) return;
    int r0 = rp[n], deg = rp[n + 1] - r0;
    float4 ad = *(const float4*)(adst + n * 4);

    float m0 = -1e30f, m1 = -1e30f, m2 = -1e30f, m3 = -1e30f;
    for (int j = l; j < deg; j += 64) {
        int s = csr[r0 + j];
        float4 a4 = *(const float4*)(asrc + s * 4);
        float e0 = a4.x + ad.x, e1 = a4.y + ad.y, e2 = a4.z + ad.z, e3 = a4.w + ad.w;
        e0 = e0 > 0.f ? e0 : 0.2f * e0;
        e1 = e1 > 0.f ? e1 : 0.2f * e1;
        e2 = e2 > 0.f ? e2 : 0.2f * e2;
        e3 = e3 > 0.f ? e3 : 0.2f * e3;
        m0 = fmaxf(m0, e0); m1 = fmaxf(m1, e1); m2 = fmaxf(m2, e2); m3 = fmaxf(m3, e3);
    }
    for (int o = 32; o > 0; o >>= 1) {
        m0 = fmaxf(m0, __shfl_xor(m0, o));
        m1 = fmaxf(m1, __shfl_xor(m1, o));
        m2 = fmaxf(m2, __shfl_xor(m2, o));
        m3 = fmaxf(m3, __shfl_xor(m3, o));
    }

    float acc[12];
#pragma unroll
    for (int k = 0; k < 12; k++) acc[k] = 0.f;
    float s0 = 0.f, s1 = 0.f, s2 = 0.f, s3 = 0.f;
    for (int j = l; j < deg; j += 64) {
        int s = csr[r0 + j];
        float4 a4 = *(const float4*)(asrc + s * 4);
        float e0 = a4.x + ad.x, e1 = a4.y + ad.y, e2 = a4.z + ad.z, e3 = a4.w + ad.w;
        e0 = e0 > 0.f ? e0 : 0.2f * e0;
        e1 = e1 > 0.f ? e1 : 0.2f * e1;
        e2 = e2 > 0.f ? e2 : 0.2f * e2;
        e3 = e3 > 0.f ? e3 : 0.2f * e3;
        float w0 = __expf(e0 - m0), w1 = __expf(e1 - m1), w2 = __expf(e2 - m2), w3 = __expf(e3 - m3);
        s0 += w0; s1 += w1; s2 += w2; s3 += w3;
        const float* hr = h3 + (size_t)s * 12;
#pragma unroll
        for (int c = 0; c < 3; c++) {
            acc[c]     += w0 * hr[c];
            acc[3 + c] += w1 * hr[3 + c];
            acc[6 + c] += w2 * hr[6 + c];
            acc[9 + c] += w3 * hr[9 + c];
        }
    }
    for (int o = 32; o > 0; o >>= 1) {
#pragma unroll
        for (int k = 0; k < 12; k++) acc[k] += __shfl_xor(acc[k], o);
        s0 += __shfl_xor(s0, o);
        s1 += __shfl_xor(s1, o);
        s2 += __shfl_xor(s2, o);
        s3 += __shfl_xor(s3, o);
    }
    if (l < 3) {
        float v = 0.25f * (acc[l] / s0 + acc[3 + l] / s1 + acc[6 + l] / s2 + acc[9 + l] / s3) + b3[l];
        v = v > 0.f ? v : expm1f(v);
        out[(size_t)n * 3 + l] = v;
    }
}

// ---------------- launch ----------------

extern "C" void kernel_launch(void* const* d_in, const int* in_sizes, int n_in,
                              void* d_out, int out_size, void* d_ws, size_t ws_size,
                              hipStream_t stream) {
    (void)in_sizes; (void)n_in; (void)out_size; (void)ws_size;
    const float* x   = (const float*)d_in[0];
    const int*   ei  = (const int*)d_in[1];
    const float* W1  = (const float*)d_in[2];
    const float* as1 = (const float*)d_in[3];
    const float* ad1 = (const float*)d_in[4];
    const float* b1  = (const float*)d_in[5];
    const float* W2  = (const float*)d_in[6];
    const float* as2 = (const float*)d_in[7];
    const float* ad2 = (const float*)d_in[8];
    const float* b2  = (const float*)d_in[9];
    const float* W3  = (const float*)d_in[10];
    const float* as3 = (const float*)d_in[11];
    const float* ad3 = (const float*)d_in[12];
    const float* b3  = (const float*)d_in[13];
    float* out = (float*)d_out;

    uint8_t* p = (uint8_t*)d_ws;
    auto alloc = [&](size_t bytes) -> void* {
        void* r = (void*)p;
        p += (bytes + 255) & ~(size_t)255;
        return r;
    };
    float* bufY = (float*)alloc((size_t)NNODES * HC * 4);
    float* h3   = (float*)alloc((size_t)NNODES * 12 * 4);
    float* asrc = (float*)alloc((size_t)NNODES * 4 * 4);
    float* adst = (float*)alloc((size_t)NNODES * 4 * 4);
    int* deg    = (int*)alloc((size_t)NNODES * 4);
    int* rp     = (int*)alloc((size_t)(NNODES + 1) * 4);
    int* cnt    = (int*)alloc((size_t)NNODES * 4);
    int* csr    = (int*)alloc((size_t)E2 * 4);
    int* bsums  = (int*)alloc(256 * 4);
    unsigned short* xh  = (unsigned short*)alloc((size_t)NNODES * HC * 2);
    unsigned short* xl  = (unsigned short*)alloc((size_t)NNODES * HC * 2);
    unsigned short* w1h = (unsigned short*)alloc((size_t)HC * HC * 2);
    unsigned short* w1l = (unsigned short*)alloc((size_t)HC * HC * 2);
    unsigned short* w2h = (unsigned short*)alloc((size_t)HC * HC * 2);
    unsigned short* w2l = (unsigned short*)alloc((size_t)HC * HC * 2);
    _Float16* h16 = (_Float16*)alloc((size_t)NNODES * HC * 2);

    const int NB_N = (NNODES + 255) / 256;
    const int NB_E = (E2 + 255) / 256;
    const int N4_A = NNODES * HC / 4;
    const int N4_W = HC * HC / 4;

    // CSR build
    zero_int<<<NB_N, 256, 0, stream>>>(deg, NNODES);
    count_deg<<<NB_E, 256, 0, stream>>>(ei, deg);
    scan1<<<NB_N, 256, 0, stream>>>(deg, rp, bsums);
    scan2<<<1, 256, 0, stream>>>(bsums, NB_N);
    scan3<<<NB_N, 256, 0, stream>>>(rp, bsums, cnt);
    fill_csr<<<NB_E, 256, 0, stream>>>(ei, cnt, csr);

    dim3 ggrid((NNODES + 127) / 128, 2);

    // Layer 1
    split_bf16<<<(N4_W + 255) / 256, 256, 0, stream>>>(W1, w1h, w1l, N4_W);
    split_bf16<<<(N4_A + 255) / 256, 256, 0, stream>>>(x, xh, xl, N4_A);
    gemm_mfma<<<ggrid, 256, 0, stream>>>(xh, xl, w1h, w1l, h16, NNODES);
    alpha_hc<<<NNODES / 4, 256, 0, stream>>>(h16, as1, ad1, asrc, adst);
    aggregate_hc<<<NNODES / NPB, 256, 0, stream>>>(h16, asrc, adst, rp, csr, b1, bufY, xh, xl, 2);

    // Layer 2
    split_bf16<<<(N4_W + 255) / 256, 256, 0, stream>>>(W2, w2h, w2l, N4_W);
    gemm_mfma<<<ggrid, 256, 0, stream>>>(xh, xl, w2h, w2l, h16, NNODES);
    alpha_hc<<<NNODES / 4, 256, 0, stream>>>(h16, as2, ad2, asrc, adst);
    aggregate_hc<<<NNODES / NPB, 256, 0, stream>>>(h16, asrc, adst, rp, csr, b2, bufY, xh, xl, 1);

    // Layer 3
    gemm_small<<<(NNODES * 12 + 255) / 256, 256, 0, stream>>>(bufY, W3, h3);
    alpha3<<<NB_N, 256, 0, stream>>>(h3, as3, ad3, asrc, adst);
    aggregate3<<<(NNODES + 3) / 4, 256, 0, stream>>>(h3, asrc, adst, rp, csr, b3, out);
}